// Round 19
// baseline (260.145 us; speedup 1.0000x reference)
//
#include <hip/hip_runtime.h>
#include <hip/hip_bf16.h>

#define A_SCALE_C 0.6454972243679028f   // (24/10)^-0.5
#define E_SCALE_C 0.3952847075210474f   // (64/10)^-0.5

typedef unsigned short u16;
typedef unsigned int u32;
typedef __attribute__((ext_vector_type(8))) short bf16x8;
typedef __attribute__((ext_vector_type(4))) float f32x4;
typedef __attribute__((ext_vector_type(4))) unsigned short u16x4;
typedef __attribute__((ext_vector_type(8))) unsigned short u16x8;

static __device__ __forceinline__ float waveSum(float v){
#pragma unroll
  for (int off = 32; off; off >>= 1) v += __shfl_xor(v, off, 64);
  return v;
}
static __device__ __forceinline__ float silu(float g){
  return g / (1.0f + __expf(-g));
}
static __device__ __forceinline__ float bf2f(u16 h){
  union { u32 u; float f; } x; x.u = ((u32)h) << 16; return x.f;
}
static __device__ __forceinline__ u16 f2bf(float f){
  __hip_bfloat16 h = __float2bfloat16(f);
  u16 r; __builtin_memcpy(&r, &h, 2); return r;
}
template<int PERM>
static __device__ __forceinline__ int cperm(int c){
  if constexpr (PERM) return (c < 512) ? (((c>>2)&63)*8 + ((c>>8)<<2) + (c&3)) : c;
  else return c;
}

// inline row rmsnorm -> bf16 A-fragments (row covered by l4-group of 4 lanes)
static __device__ __forceinline__ void row_rms_frag(
    const float* __restrict__ rowp, const float* __restrict__ normw,
    int l4, bf16x8* bfr){
  float xr[4][8];
  float ssx = 0.f;
#pragma unroll
  for (int kk=0; kk<4; kk++){
    const float* rp = rowp + kk*32 + l4*8;
    float4 a = *(const float4*)rp;
    float4 bq = *(const float4*)(rp + 4);
    xr[kk][0]=a.x; xr[kk][1]=a.y; xr[kk][2]=a.z; xr[kk][3]=a.w;
    xr[kk][4]=bq.x; xr[kk][5]=bq.y; xr[kk][6]=bq.z; xr[kk][7]=bq.w;
#pragma unroll
    for (int e=0;e<8;e++) ssx = fmaf(xr[kk][e], xr[kk][e], ssx);
  }
  ssx += __shfl_xor(ssx,16,64);
  ssx += __shfl_xor(ssx,32,64);
  const float rsx = rsqrtf(ssx*(1.0f/128.0f) + 1e-6f);
#pragma unroll
  for (int kk=0; kk<4; kk++){
    const float* wp = normw + kk*32 + l4*8;
#pragma unroll
    for (int e=0;e<8;e++) bfr[kk][e] = (short)f2bf(xr[kk][e] * rsx * wp[e]);
  }
}

// ---------------- batched weight-transpose builder ----------------
struct WtJob { const float* src; const float* scale; u16* dst;
               int src_ld, row0, c0, k0, dlog, kslog, C; };
struct WtJobs { WtJob j[23]; };

__global__ __launch_bounds__(256) void build_all_wt(WtJobs P){
  const WtJob J = P.j[blockIdx.y];
  const int ks = 1 << J.kslog;
  const int total = J.C << J.kslog;
  for (int idx = blockIdx.x*256 + threadIdx.x; idx < total; idx += gridDim.x*256){
    int c = idx >> J.kslog, k = idx & (ks-1);
    float s = J.scale ? J.scale[k] : 1.0f;
    J.dst[((size_t)(J.c0 + c) << J.dlog) + J.k0 + k] =
        f2bf(J.src[(size_t)(J.row0 + k)*J.src_ld + c] * s);
  }
}

// ---------------- merged hat rmsnorm + output init ----------------
__global__ void hat_init_kernel(const float* __restrict__ ang, u16* __restrict__ hat,
                                const float4* __restrict__ e, float4* __restrict__ oe,
                                const float4* __restrict__ n, float4* __restrict__ on){
  int bid = blockIdx.x;
  if (bid < 18432){
    int row = bid*4 + (threadIdx.x >> 6);
    int lane = threadIdx.x & 63;
    float x = ang[(size_t)row*64 + lane];
    float ss = waveSum(x*x);
    float rs = rsqrtf(ss*(1.0f/64.0f) + 1e-6f);
    hat[(size_t)row*64 + lane] = f2bf(x*rs);
  } else {
    int idx = (bid - 18432)*256 + threadIdx.x;
    if (idx < 262144) oe[idx] = e[idx];
    else if (idx < 262144 + 4096) on[idx - 262144] = n[idx - 262144];
  }
}

// compact rmsnorm + node append: enc_aug[3072][256] = [e_n bf16 | node bf16]
__global__ void rmsnorm128c_aug_kernel(const float* __restrict__ x, const float* __restrict__ w,
                                       const float* __restrict__ node, u16* __restrict__ out){
  int row = blockIdx.x*4 + (threadIdx.x >> 6);   // 0..3071
  int lane = threadIdx.x & 63;
  int loc = row/24;
  int src = loc*64 + (row - loc*24);
  float2 v = *(const float2*)(x + (size_t)src*128 + lane*2);
  float ss = waveSum(v.x*v.x + v.y*v.y);
  float rs = rsqrtf(ss*(1.0f/128.0f) + 1e-6f);
  float2 wv = *(const float2*)(w + lane*2);
  u32 pk = (u32)f2bf(v.x*rs*wv.x) | ((u32)f2bf(v.y*rs*wv.y) << 16);
  *(u32*)(out + (size_t)row*256 + lane*2) = pk;
  float2 nv = *(const float2*)(node + loc*128 + lane*2);
  u32 pn = (u32)f2bf(nv.x) | ((u32)f2bf(nv.y) << 16);
  *(u32*)(out + (size_t)row*256 + 128 + lane*2) = pn;
}

// fused node rmsnorm + table GEMM
__global__ __launch_bounds__(128) void node_gemm2_kernel(
    const float* __restrict__ node, const float* __restrict__ nw,
    const float* __restrict__ Ba, float* __restrict__ Ca,
    const float* __restrict__ Bb, float* __restrict__ Cb){
  __shared__ float ar[128];
  __shared__ float sred[2];
  const int row = blockIdx.x, t = threadIdx.x;
  float x = node[row*128 + t];
  float s = waveSum(x*x);
  if ((t & 63) == 0) sred[t>>6] = s;
  __syncthreads();
  float rs = rsqrtf((sred[0]+sred[1])*(1.0f/128.0f) + 1e-6f);
  ar[t] = x * rs * nw[t];
  __syncthreads();
  const int c = blockIdx.y;
  const float* B = (c < 8) ? Ba : Bb;
  float* C = (c < 8) ? Ca : Cb;
  const int cc = c & 7, half = cc >> 2, sub = cc & 3;
  const int brow = 128 + half*128;
  const int col = sub*128 + t;
  float acc = 0.f;
  for (int k=0;k<128;k++) acc = fmaf(ar[k], B[(size_t)(brow+k)*512 + col], acc);
  C[(size_t)row*1024 + half*512 + col] = acc;
}

// ---------------- dual MFMA GEMM ----------------
__global__ __launch_bounds__(256) void gemm2_bf16_kernel(
    const u16* __restrict__ A, int lda,
    const u16* __restrict__ Bt0, u16* __restrict__ C0, int N0, int K0, int ny0,
    const u16* __restrict__ Bt1, u16* __restrict__ C1, int N1, int K1){
  __shared__ float cl[32*128];
  const int lane = threadIdx.x & 63, wave = threadIdx.x >> 6;
  const int job1 = ((int)blockIdx.y >= ny0);
  const u16* Bt = job1 ? Bt1 : Bt0;
  u16* C = job1 ? C1 : C0;
  const int N = job1 ? N1 : N0;
  const int K = job1 ? K1 : K0;
  const int by = job1 ? ((int)blockIdx.y - ny0) : (int)blockIdx.y;
  const size_t arow = (size_t)blockIdx.x*32;
  const size_t bcol = (size_t)by*128 + wave*32;
  f32x4 acc00={0,0,0,0}, acc01={0,0,0,0}, acc10={0,0,0,0}, acc11={0,0,0,0};
  for (int k=0; k<K; k+=32){
    int ko = k + (lane>>4)*8;
    bf16x8 a0 = *(const bf16x8*)(A + (arow + (lane&15))*lda + ko);
    bf16x8 a1 = *(const bf16x8*)(A + (arow + 16 + (lane&15))*lda + ko);
    bf16x8 b0 = *(const bf16x8*)(Bt + (bcol + (lane&15))*K + ko);
    bf16x8 b1 = *(const bf16x8*)(Bt + (bcol + 16 + (lane&15))*K + ko);
    acc00 = __builtin_amdgcn_mfma_f32_16x16x32_bf16(a0, b0, acc00, 0,0,0);
    acc01 = __builtin_amdgcn_mfma_f32_16x16x32_bf16(a0, b1, acc01, 0,0,0);
    acc10 = __builtin_amdgcn_mfma_f32_16x16x32_bf16(a1, b0, acc10, 0,0,0);
    acc11 = __builtin_amdgcn_mfma_f32_16x16x32_bf16(a1, b1, acc11, 0,0,0);
  }
  const int cr = (lane>>4)*4, cc = wave*32 + (lane&15);
#pragma unroll
  for (int q=0;q<4;q++){
    cl[(cr+q)*128 + cc]      = acc00[q];
    cl[(cr+q)*128 + cc+16]   = acc01[q];
    cl[(16+cr+q)*128 + cc]    = acc10[q];
    cl[(16+cr+q)*128 + cc+16] = acc11[q];
  }
  __syncthreads();
  const int t = threadIdx.x;
#pragma unroll
  for (int i=0;i<16;i++){
    int idx = i*256 + t; int r = idx>>7, c = idx&127;
    int gcol = by*128 + c;
    C[(arow + r)*(size_t)N + cperm<1>(gcol)] = f2bf(cl[idx]);
  }
}

// ---------------- fused angle kernel v11 ----------------
template<bool IS_BLK1>
__global__ __launch_bounds__(512, 4) void angle11_kernel(
    const u16* __restrict__ hat, const u16* __restrict__ preE, const u16* __restrict__ preK,
    const u16* __restrict__ wangT, const u16* __restrict__ woT,
    const float* __restrict__ angle,
    const float* __restrict__ rbf, const float* __restrict__ envW,
    const float* __restrict__ a_sw,
    const u16* __restrict__ aprojTb, const float* __restrict__ eproj,
    float* __restrict__ edge_out, float* __restrict__ angle_out)
{
  constexpr int HW = IS_BLK1 ? 640 : 512;
  constexpr int VGN_B  = 48*264*2;
  constexpr int GATE_O = VGN_B;
  constexpr int SS_O   = GATE_O + (IS_BLK1 ? 48*132*2 : 0);
  constexpr int RS_O   = SS_O + 8*48*4;
  constexpr int SEG_O  = RS_O + 192;
  constexpr int RBF_O  = SEG_O + (IS_BLK1 ? 0 : 1024);
  constexpr int LDS_B  = RBF_O + (IS_BLK1 ? 0 : 1152);
  __shared__ __align__(16) char ldsRaw[LDS_B];
  u16*   vgn    = (u16*)ldsRaw;
  u16*   gateLb = (u16*)(ldsRaw + GATE_O);
  float* ssL    = (float*)(ldsRaw + SS_O);
  float* rsL    = (float*)(ldsRaw + RS_O);
  float* segL   = (float*)(ldsRaw + SEG_O);
  float* rbfL   = (float*)(ldsRaw + RBF_O);
  float* msgL   = (float*)ldsRaw;

  const int t = threadIdx.x, lane = t & 63, w = t >> 6;
  const int l15 = lane & 15, l4 = lane >> 4;
  const int b = blockIdx.x;
  const int xcd = b & 7, idx = b >> 3;
  const int loc = xcd*16 + idx/12;
  const int j0 = (idx - (idx/12)*12)*2;
  const int s0 = loc*24 + j0;
  const int hbase = s0*24;
  const int oc = 16*w + l15;

  if constexpr (!IS_BLK1){
    if (t < 288) rbfL[t] = rbf[(size_t)(loc*64)*12 + t];
  }

  u16x8 pk[3][2], pe[3][2];
  u16x4 pkg[3], peg[3];
#pragma unroll
  for (int nt=0; nt<3; nt++){
    const int r = nt*16 + l15;
    const int hi = (r >= 24);
    const int rr = r - 24*hi;
    const u16* pK = preK + (size_t)(loc*24 + rr)*HW;
    const u16* pE = preE + (size_t)(s0 + hi)*HW;
#pragma unroll
    for (int i=0;i<2;i++){
      const int a = (2*w + i)*4 + l4;
      pk[nt][i] = *(const u16x8*)(pK + a*8);
      pe[nt][i] = *(const u16x8*)(pE + a*8);
    }
    if constexpr (IS_BLK1){
      const int cg = 512 + w*16 + l4*4;
      pkg[nt] = *(const u16x4*)(pK + cg);
      peg[nt] = *(const u16x4*)(pE + cg);
    }
  }

  f32x4 accv[3][2], accg[3][2], accgate[3];
#pragma unroll
  for (int nt=0;nt<3;nt++){
    accv[nt][0]=(f32x4){0,0,0,0}; accv[nt][1]=(f32x4){0,0,0,0};
    accg[nt][0]=(f32x4){0,0,0,0}; accg[nt][1]=(f32x4){0,0,0,0};
    accgate[nt]=(f32x4){0,0,0,0};
  }
#pragma unroll
  for (int kk=0; kk<2; kk++){
    const int ko = kk*32 + l4*8;
    bf16x8 bb[3];
#pragma unroll
    for (int nt=0;nt<3;nt++)
      bb[nt] = *(const bf16x8*)(hat + (size_t)(hbase + nt*16 + l15)*64 + ko);
#pragma unroll
    for (int i=0;i<2;i++){
      const int chv = (2*w + i)*16 + l15;
      bf16x8 av = *(const bf16x8*)(wangT + (size_t)chv*64 + ko);
      bf16x8 ag = *(const bf16x8*)(wangT + (size_t)(256 + chv)*64 + ko);
#pragma unroll
      for (int nt=0;nt<3;nt++){
        accv[nt][i] = __builtin_amdgcn_mfma_f32_16x16x32_bf16(av, bb[nt], accv[nt][i], 0,0,0);
        accg[nt][i] = __builtin_amdgcn_mfma_f32_16x16x32_bf16(ag, bb[nt], accg[nt][i], 0,0,0);
      }
    }
    if constexpr (IS_BLK1){
      bf16x8 aga = *(const bf16x8*)(wangT + (size_t)(512 + w*16 + l15)*64 + ko);
#pragma unroll
      for (int nt=0;nt<3;nt++)
        accgate[nt] = __builtin_amdgcn_mfma_f32_16x16x32_bf16(aga, bb[nt], accgate[nt], 0,0,0);
    }
  }

  float ssr[3] = {0.f, 0.f, 0.f};
#pragma unroll
  for (int nt=0; nt<3; nt++){
    const int r = nt*16 + l15;
#pragma unroll
    for (int i=0;i<2;i++){
      const int cb = (2*w + i)*16 + l4*4;
      u16x4 xs;
#pragma unroll
      for (int q=0;q<4;q++){
        float v = accv[nt][i][q] + bf2f(pk[nt][i][q])   + bf2f(pe[nt][i][q]);
        float g = accg[nt][i][q] + bf2f(pk[nt][i][4+q]) + bf2f(pe[nt][i][4+q]);
        float x = v * silu(g);
        ssr[nt] += x*x;
        xs[q] = f2bf(x);
      }
      *(u16x4*)&vgn[r*264 + cb] = xs;
    }
    if constexpr (IS_BLK1){
      u16x4 gs;
#pragma unroll
      for (int q=0;q<4;q++)
        gs[q] = f2bf((accgate[nt][q] + bf2f(pkg[nt][q]) + bf2f(peg[nt][q])) * A_SCALE_C);
      *(u16x4*)&gateLb[r*132 + w*16 + l4*4] = gs;
    }
  }
#pragma unroll
  for (int nt=0;nt<3;nt++){
    float s = ssr[nt];
    s += __shfl_xor(s,16,64); s += __shfl_xor(s,32,64);
    if (l4 == 0) ssL[w*48 + nt*16 + l15] = s;
  }
  bf16x8 bwp[8];
#pragma unroll
  for (int kk=0; kk<8; kk++)
    bwp[kk] = *(const bf16x8*)(woT + (size_t)oc*256 + kk*32 + l4*8);
  __syncthreads();                    // sync1
  if (t < 48){
    float s_ = 0.f;
#pragma unroll
    for (int k=0;k<8;k++) s_ += ssL[k*48 + t];
    rsL[t] = rsqrtf(s_*(1.0f/256.0f) + 1e-6f);
  }

  f32x4 mac[3];
#pragma unroll
  for (int m=0;m<3;m++) mac[m] = (f32x4){0,0,0,0};
#pragma unroll
  for (int kk=0; kk<8; kk++){
#pragma unroll
    for (int m=0;m<3;m++){
      bf16x8 aw = *(const bf16x8*)&vgn[(m*16 + l15)*264 + kk*32 + l4*8];
      mac[m] = __builtin_amdgcn_mfma_f32_16x16x32_bf16(aw, bwp[kk], mac[m], 0,0,0);
    }
  }
  __syncthreads();                    // sync2
  float rsv[3][4];
#pragma unroll
  for (int m=0;m<3;m++)
#pragma unroll
    for (int q=0;q<4;q++) rsv[m][q] = rsL[m*16 + l4*4 + q];
#pragma unroll
  for (int m=0;m<3;m++)
#pragma unroll
    for (int q=0;q<4;q++)
      msgL[(m*16 + l4*4 + q)*132 + 16*w + l15] = mac[m][q] * rsv[m][q];
  __syncthreads();                    // sync3

  if constexpr (IS_BLK1){
    if (t < 256){
      int s = t>>7, c = t&127;
      float ex[24]; float mx = -1e30f;
#pragma unroll
      for (int k=0;k<24;k++){ ex[k] = bf2f(gateLb[(s*24+k)*132 + c]); mx = fmaxf(mx, ex[k]); }
      float S = 0.f;
#pragma unroll
      for (int k=0;k<24;k++){ ex[k] = __expf(ex[k] - mx); S += ex[k]; }
      float inv = 1.f/(S + 1e-12f);
      float delta = 0.f;
#pragma unroll
      for (int k=0;k<24;k++) delta += msgL[(s*24+k)*132 + c] * ex[k];
      edge_out[(size_t)(loc*64 + j0 + s)*128 + c] += delta * inv;
    }
  } else {
    if (t < 256){
      int s = t>>7, c = t&127;
      float envR[12];
#pragma unroll
      for (int j=0;j<12;j++) envR[j] = envW[j*128 + c];
      float sg_ = 0.f;
#pragma unroll
      for (int k=0;k<24;k++){
        float envC = 0.f;
#pragma unroll
        for (int j=0;j<12;j++) envC = fmaf(rbfL[k*12 + j], envR[j], envC);
        sg_ += msgL[(s*24+k)*132 + c] * envC * a_sw[(size_t)(s0+s)*24 + k];
      }
      segL[s*128 + c] = sg_;
    }
    for (int p = w; p < 12; p += 8){
      const int mt = p >> 2, ntc = p & 3;
      f32x4 am = (f32x4){0,0,0,0};
#pragma unroll
      for (int kk=0; kk<4; kk++){
        const float* mrow = &msgL[(mt*16 + l15)*132 + kk*32 + l4*8];
        bf16x8 a;
#pragma unroll
        for (int e=0;e<8;e++) a[e] = (short)f2bf(mrow[e]);
        bf16x8 bb = *(const bf16x8*)(aprojTb + (size_t)(ntc*16 + l15)*128 + kk*32 + l4*8);
        am = __builtin_amdgcn_mfma_f32_16x16x32_bf16(a, bb, am, 0,0,0);
      }
#pragma unroll
      for (int q=0;q<4;q++){
        int row = mt*16 + l4*4 + q;
        size_t a_ = (size_t)hbase + row;
        int col = ntc*16 + l15;
        angle_out[a_*64 + col] = angle[a_*64 + col] + am[q] * a_sw[a_];
      }
    }
    __syncthreads();
    if (t < 256){
      int s = t>>7, c = t&127;
      float acc2 = 0.f;
      for (int dd=0; dd<128; dd++) acc2 = fmaf(segL[s*128 + dd], eproj[dd*128 + c], acc2);
      edge_out[(size_t)(loc*64 + j0 + s)*128 + c] += acc2 * A_SCALE_C;
    }
  }
}

// ---------------- scores v3: inline rmsnorm + MFMA gate + softmax ----------------
__global__ __launch_bounds__(256) void scores3_kernel(const float* __restrict__ edge_src,
                                                      const float* __restrict__ norm_e,
                                                      const u16* __restrict__ gateT,
                                                      float* __restrict__ scores){
  __shared__ float s[64*132];
  const int t = threadIdx.x, lane = t & 63, w = t >> 6;
  const int l15 = lane & 15, l4 = lane >> 4;
  const int n = blockIdx.x;
  const int row = n*64 + w*16 + l15;
  bf16x8 bfr[4];
  row_rms_frag(edge_src + (size_t)row*128, norm_e, l4, bfr);
  f32x4 acc[8];
#pragma unroll
  for (int j=0;j<8;j++) acc[j] = (f32x4){0,0,0,0};
#pragma unroll
  for (int kk=0; kk<4; kk++){
    const int ko = kk*32 + l4*8;
#pragma unroll
    for (int j=0;j<8;j++){
      bf16x8 b = *(const bf16x8*)(gateT + (size_t)(j*16 + l15)*128 + ko);
      acc[j] = __builtin_amdgcn_mfma_f32_16x16x32_bf16(bfr[kk], b, acc[j], 0,0,0);
    }
  }
#pragma unroll
  for (int j=0;j<8;j++)
#pragma unroll
    for (int q=0;q<4;q++)
      s[(w*16 + l4*4 + q)*132 + j*16 + l15] = acc[j][q] * E_SCALE_C;
  __syncthreads();
  if (t < 128){
    float m = -1e30f;
    for (int r=0;r<64;r++) m = fmaxf(m, s[r*132 + t]);
    float S = 0.f;
    for (int r=0;r<64;r++) S += __expf(s[r*132 + t] - m);
    float inv = 1.f/(S + 1e-12f);
    for (int r=0;r<64;r++)
      scores[(size_t)(n*64 + r)*128 + t] = __expf(s[r*132 + t] - m) * inv;
  }
}

// ---------------- combined blk2 edge kernel (inline rmsnorm) ----------------
__global__ __launch_bounds__(256) void edge_fused01_kernel(
    const float* __restrict__ edge_src,
    const float* __restrict__ norm_e,
    const float* __restrict__ NPa, const float* __restrict__ NPe,
    const int* __restrict__ next2e,
    const u16* __restrict__ aaWT, const u16* __restrict__ aeWT,
    const u16* __restrict__ woaaT, const u16* __restrict__ woaeT,
    const float* __restrict__ scores,
    float* __restrict__ edge_out, float* __restrict__ partial){
  __shared__ __align__(16) char lds[13184];
  u16*   vgn  = (u16*)lds;
  float* msgF = (float*)lds;
  float* ssP  = (float*)(lds + 12800);
  float* rsL  = (float*)(lds + 13056);
  const int t = threadIdx.x, lane = t & 63, w = t >> 6;
  const int l15 = lane & 15, l4 = lane >> 4;
  const int g = blockIdx.x, e0 = g*16, n = e0 >> 6;
  const int nx = next2e[e0 + l15];

  bf16x8 bfr[4];
  row_rms_frag(edge_src + (size_t)(e0 + l15)*128, norm_e, l4, bfr);

#pragma unroll
  for (int path=0; path<2; path++){
    const u16* wT  = path ? aeWT : aaWT;
    const u16* woT = path ? woaeT : woaaT;
    const float* NPt = path ? NPe : NPa;

    f32x4 av4[4], ag4[4];
#pragma unroll
    for (int i=0;i<4;i++){ av4[i]=(f32x4){0,0,0,0}; ag4[i]=(f32x4){0,0,0,0}; }
#pragma unroll
    for (int kk=0; kk<4; kk++){
      const int ko = kk*32 + l4*8;
#pragma unroll
      for (int i=0;i<4;i++){
        const int chr = w*64 + i*16 + l15;
        bf16x8 wv = *(const bf16x8*)(wT + (size_t)chr*128 + ko);
        bf16x8 wg = *(const bf16x8*)(wT + (size_t)(256 + chr)*128 + ko);
        av4[i] = __builtin_amdgcn_mfma_f32_16x16x32_bf16(wv, bfr[kk], av4[i], 0,0,0);
        ag4[i] = __builtin_amdgcn_mfma_f32_16x16x32_bf16(wg, bfr[kk], ag4[i], 0,0,0);
      }
    }

    float ssr = 0.f;
#pragma unroll
    for (int i=0;i<4;i++){
      const int cb = w*64 + i*16 + l4*4;
      float4 sv = *(const float4*)(NPt + n*1024 + cb);
      float4 sg = *(const float4*)(NPt + n*1024 + 256 + cb);
      float4 nv = *(const float4*)(NPt + (size_t)nx*1024 + 512 + cb);
      float4 ng = *(const float4*)(NPt + (size_t)nx*1024 + 768 + cb);
      u16x4 xs;
#pragma unroll
      for (int q=0;q<4;q++){
        float v  = av4[i][q] + ((const float*)&sv)[q] + ((const float*)&nv)[q];
        float gg = ag4[i][q] + ((const float*)&sg)[q] + ((const float*)&ng)[q];
        float x = v * silu(gg);
        ssr += x*x;
        xs[q] = f2bf(x);
      }
      *(u16x4*)&vgn[l15*264 + cb] = xs;
    }
    {
      float s = ssr;
      s += __shfl_xor(s,16,64); s += __shfl_xor(s,32,64);
      if (l4 == 0) ssP[l15*4 + w] = s;
    }
    __syncthreads();
    if (t < 16)
      rsL[t] = rsqrtf((ssP[t*4]+ssP[t*4+1]+ssP[t*4+2]+ssP[t*4+3])*(1.0f/256.0f) + 1e-6f);
    __syncthreads();
    f32x4 mac[2] = {(f32x4){0,0,0,0}, (f32x4){0,0,0,0}};
#pragma unroll
    for (int kk=0; kk<8; kk++){
      bf16x8 a = *(const bf16x8*)&vgn[l15*264 + kk*32 + l4*8];
#pragma unroll
      for (int nt=0; nt<2; nt++){
        bf16x8 bw = *(const bf16x8*)(woT + (size_t)(32*w + nt*16 + l15)*256 + kk*32 + l4*8);
        mac[nt] = __builtin_amdgcn_mfma_f32_16x16x32_bf16(a, bw, mac[nt], 0,0,0);
      }
    }
    float rsv[4];
#pragma unroll
    for (int q=0;q<4;q++) rsv[q] = rsL[l4*4 + q];
    __syncthreads();
#pragma unroll
    for (int nt=0; nt<2; nt++)
#pragma unroll
      for (int q=0;q<4;q++)
        msgF[(l4*4 + q)*132 + 32*w + nt*16 + l15] = mac[nt][q] * rsv[q];
    __syncthreads();

    if (path == 0){
      if (t < 128){
        float p = 0.f;
#pragma unroll
        for (int r=0;r<16;r++) p += msgF[r*132 + t] * scores[(size_t)(e0+r)*128 + t];
        partial[g*128 + t] = p;
      }
    } else {
      const int d = t & 127, rg = (t >> 7) * 8;
#pragma unroll
      for (int i=0;i<8;i++)
        edge_out[(size_t)(e0+rg+i)*128 + d] += msgF[(rg+i)*132 + d];
    }
    __syncthreads();
  }
}

// ---------------- blk4 edge kernel: MODE2 with fused rmsnorm ----------------
__global__ __launch_bounds__(256) void edge_fused2m2_kernel(
    const float* __restrict__ edge_src,
    const float* __restrict__ norm_e,
    const float* __restrict__ NPt,
    const int* __restrict__ next2e,
    const u16* __restrict__ wT,
    const u16* __restrict__ woT,
    const float* __restrict__ rbf, const float* __restrict__ envW,
    const float* __restrict__ sw, const u16* __restrict__ eprojT,
    float* __restrict__ edge_out, float* __restrict__ partial){
  __shared__ __align__(16) char lds[20096];
  u16*   vgn  = (u16*)lds;
  float* msgF = (float*)lds;
  u16*   msgB = (u16*)(lds + 8448);
  float* ssP  = (float*)(lds + 12800);
  float* rsL  = (float*)(lds + 13056);
  float* envWL= (float*)(lds + 13184);
  float* rbfL = (float*)(lds + 19328);
  const int t = threadIdx.x, lane = t & 63, w = t >> 6;
  const int l15 = lane & 15, l4 = lane >> 4;
  const int g = blockIdx.x, e0 = g*16, n = e0 >> 6;
  const int nx = next2e[e0 + l15];
  for (int i=t; i<12*128; i+=256) envWL[i] = envW[i];
  if (t < 192) rbfL[t] = rbf[(size_t)e0*12 + t];

  bf16x8 bfr[4];
  row_rms_frag(edge_src + (size_t)(e0 + l15)*128, norm_e, l4, bfr);

  float4 sv[4], sg[4], nv[4], ng[4];
#pragma unroll
  for (int i=0;i<4;i++){
    const int cb = w*64 + i*16 + l4*4;
    sv[i] = *(const float4*)(NPt + n*1024 + cb);
    sg[i] = *(const float4*)(NPt + n*1024 + 256 + cb);
    nv[i] = *(const float4*)(NPt + (size_t)nx*1024 + 512 + cb);
    ng[i] = *(const float4*)(NPt + (size_t)nx*1024 + 768 + cb);
  }

  f32x4 av4[4], ag4[4];
#pragma unroll
  for (int i=0;i<4;i++){ av4[i]=(f32x4){0,0,0,0}; ag4[i]=(f32x4){0,0,0,0}; }
#pragma unroll
  for (int kk=0; kk<4; kk++){
    const int ko = kk*32 + l4*8;
#pragma unroll
    for (int i=0;i<4;i++){
      const int chr = w*64 + i*16 + l15;
      bf16x8 wv = *(const bf16x8*)(wT + (size_t)chr*128 + ko);
      bf16x8 wg = *(const bf16x8*)(wT + (size_t)(256 + chr)*128 + ko);
      av4[i] = __builtin_amdgcn_mfma_f32_16x16x32_bf16(wv, bfr[kk], av4[i], 0,0,0);
      ag4[i] = __builtin_amdgcn_mfma_f32_16x16x32_bf16(wg, bfr[kk], ag4[i], 0,0,0);
    }
  }

  float ssr = 0.f;
#pragma unroll
  for (int i=0;i<4;i++){
    const int cb = w*64 + i*16 + l4*4;
    u16x4 xs;
#pragma unroll
    for (int q=0;q<4;q++){
      float v = av4[i][q] + ((const float*)&sv[i])[q] + ((const float*)&nv[i])[q];
      float gg = ag4[i][q] + ((const float*)&sg[i])[q] + ((const float*)&ng[i])[q];
      float x = v * silu(gg);
      ssr += x*x;
      xs[q] = f2bf(x);
    }
    *(u16x4*)&vgn[l15*264 + cb] = xs;
  }
  {
    float s = ssr;
    s += __shfl_xor(s,16,64); s += __shfl_xor(s,32,64);
    if (l4 == 0) ssP[l15*4 + w] = s;
  }
  __syncthreads();
  if (t < 16)
    rsL[t] = rsqrtf((ssP[t*4]+ssP[t*4+1]+ssP[t*4+2]+ssP[t*4+3])*(1.0f/256.0f) + 1e-6f);
  __syncthreads();
  f32x4 mac[2] = {(f32x4){0,0,0,0}, (f32x4){0,0,0,0}};
#pragma unroll
  for (int kk=0; kk<8; kk++){
    bf16x8 a = *(const bf16x8*)&vgn[l15*264 + kk*32 + l4*8];
#pragma unroll
    for (int nt=0; nt<2; nt++){
      bf16x8 bw = *(const bf16x8*)(woT + (size_t)(32*w + nt*16 + l15)*256 + kk*32 + l4*8);
      mac[nt] = __builtin_amdgcn_mfma_f32_16x16x32_bf16(a, bw, mac[nt], 0,0,0);
    }
  }
  float rsv[4];
#pragma unroll
  for (int q=0;q<4;q++) rsv[q] = rsL[l4*4 + q];
  __syncthreads();
#pragma unroll
  for (int nt=0; nt<2; nt++)
#pragma unroll
    for (int q=0;q<4;q++){
      float val = mac[nt][q] * rsv[q];
      int row = l4*4 + q, col = 32*w + nt*16 + l15;
      msgF[row*132 + col] = val;
      msgB[row*136 + col] = f2bf(val);
    }
  __syncthreads();

  f32x4 em[2] = {(f32x4){0,0,0,0}, (f32x4){0,0,0,0}};
#pragma unroll
  for (int kk=0; kk<4; kk++){
    bf16x8 a = *(const bf16x8*)&msgB[l15*136 + kk*32 + l4*8];
#pragma unroll
    for (int nt=0; nt<2; nt++){
      bf16x8 bw = *(const bf16x8*)(eprojT + (size_t)(32*w + nt*16 + l15)*128 + kk*32 + l4*8);
      em[nt] = __builtin_amdgcn_mfma_f32_16x16x32_bf16(a, bw, em[nt], 0,0,0);
    }
  }
#pragma unroll
  for (int nt=0; nt<2; nt++)
#pragma unroll
    for (int q=0;q<4;q++)
      edge_out[(size_t)(e0 + l4*4 + q)*128 + 32*w + nt*16 + l15] += em[nt][q];
  if (t < 128){
    float p = 0.f;
#pragma unroll
    for (int r=0;r<16;r++){
      float envC = 0.f;
#pragma unroll
      for (int j=0;j<12;j++) envC = fmaf(rbfL[r*12 + j], envWL[j*128 + t], envC);
      p += msgF[r*132 + t] * envC * sw[e0 + r];
    }
    partial[g*128 + t] = p;
  }
}

__global__ void node_add4_kernel(const float* __restrict__ partial, float* __restrict__ node_out){
  int n = blockIdx.x, t = threadIdx.x;
  node_out[n*128 + t] += partial[(4*n)*128+t] + partial[(4*n+1)*128+t]
                       + partial[(4*n+2)*128+t] + partial[(4*n+3)*128+t];
}

__global__ void node_final4_kernel(const float* __restrict__ partial,
                                   const float* __restrict__ nproj,
                                   float* __restrict__ node_out){
  __shared__ float seg[128];
  int n = blockIdx.x, t = threadIdx.x;
  seg[t] = partial[(4*n)*128+t] + partial[(4*n+1)*128+t]
         + partial[(4*n+2)*128+t] + partial[(4*n+3)*128+t];
  __syncthreads();
  float acc = 0.f;
  for (int dd=0; dd<128; dd++) acc = fmaf(seg[dd], nproj[dd*128 + t], acc);
  node_out[n*128 + t] += acc * E_SCALE_C;
}

// ---------------- launch ----------------
extern "C" void kernel_launch(void* const* d_in, const int* in_sizes, int n_in,
                              void* d_out, int out_size, void* d_ws, size_t ws_size,
                              hipStream_t stream){
  const float* node_in  = (const float*)d_in[0];
  const float* edge_in  = (const float*)d_in[1];
  const float* angle_in = (const float*)d_in[2];
  const float* sw       = (const float*)d_in[3];
  const float* a_sw     = (const float*)d_in[4];
  const float* rbf      = (const float*)d_in[5];
  const int*   edge_index = (const int*)d_in[6];
  const float* la_norm_e = (const float*)d_in[8];
  const float* la_norm_a = (const float*)d_in[9];
  const float* la_win    = (const float*)d_in[10];
  const float* la_nw     = (const float*)d_in[11];
  const float* la_wout   = (const float*)d_in[12];
  const float* la_gate   = (const float*)d_in[13];
  const float* aa_norm_n = (const float*)d_in[14];
  const float* aa_norm_e = (const float*)d_in[15];
  const float* aa_win    = (const float*)d_in[16];
  const float* aa_nw     = (const float*)d_in[17];
  const float* aa_wout   = (const float*)d_in[18];
  const float* aa_src_gate = (const float*)d_in[19];
  const float* ae_win    = (const float*)d_in[20];
  const float* ae_nw     = (const float*)d_in[21];
  const float* ae_wout   = (const float*)d_in[22];
  const float* lr_norm_e = (const float*)d_in[23];
  const float* lr_norm_a = (const float*)d_in[24];
  const float* lr_win    = (const float*)d_in[25];
  const float* lr_nw     = (const float*)d_in[26];
  const float* lr_wout   = (const float*)d_in[27];
  const float* lr_env    = (const float*)d_in[28];
  const float* lr_eproj  = (const float*)d_in[29];
  const float* lr_aproj  = (const float*)d_in[30];
  const float* ar_norm_n = (const float*)d_in[31];
  const float* ar_norm_e = (const float*)d_in[32];
  const float* ar_win    = (const float*)d_in[33];
  const float* ar_nw     = (const float*)d_in[34];
  const float* ar_wout   = (const float*)d_in[35];
  const float* ar_env    = (const float*)d_in[36];
  const float* ar_nproj  = (const float*)d_in[37];
  const float* ar_eproj  = (const float*)d_in[38];

  float* out_node  = (float*)d_out;
  float* out_edge  = out_node + 128*128;
  float* out_angle = out_edge + (size_t)8192*128;

  float* p = (float*)d_ws;
  float* hat_f   = p; p += 2359296;
  float* enca_f  = p; p += 393216;
  float* preE_f  = p; p += 983040;
  float* preK_f  = p; p += 983040;
  float* wang1_f = p; p += 20480;
  float* wang3_f = p; p += 16384;
  float* wij1_f  = p; p += 40960;
  float* wij3_f  = p; p += 32768;
  float* wik1_f  = p; p += 81920;
  float* wik3_f  = p; p += 65536;
  float* wo1T_f  = p; p += 16384;
  float* wo3T_f  = p; p += 16384;
  float* whe2_f  = p; p += 73728;
  float* whe4_f  = p; p += 32768;
  float* woaaT_f = p; p += 16384;
  float* woaeT_f = p; p += 16384;
  float* woarT_f = p; p += 16384;
  float* eprjT_f = p; p += 8192;
  float* aprjT_f = p; p += 4096;
  float* npa     = p; p += 131072;
  float* npe     = p; p += 131072;
  float* npr     = p; p += 131072;
  float* scores2 = p; p += 1048576;
  float* partial = p; p += 65536;

  u16* hat  = (u16*)hat_f;
  u16* enca = (u16*)enca_f;
  u16* preE = (u16*)preE_f;
  u16* preK = (u16*)preK_f;
  u16* wang1= (u16*)wang1_f;
  u16* wang3= (u16*)wang3_f;
  u16* wij1 = (u16*)wij1_f;
  u16* wij3 = (u16*)wij3_f;
  u16* wik1 = (u16*)wik1_f;
  u16* wik3 = (u16*)wik3_f;
  u16* wo1T = (u16*)wo1T_f;
  u16* wo3T = (u16*)wo3T_f;
  u16* whe2 = (u16*)whe2_f;
  u16* whe4 = (u16*)whe4_f;
  u16* woaaT= (u16*)woaaT_f;
  u16* woaeT= (u16*)woaeT_f;
  u16* woarT= (u16*)woarT_f;
  u16* eprjT= (u16*)eprjT_f;
  u16* aprjT= (u16*)aprjT_f;
  u16* aaWT = whe2;
  u16* aeWT = whe2 + 512*128;
  u16* gateT= whe2 + 1024*128;
  u16* arWT = whe4;

  dim3 b512(512), b256(256), b128(128);
  const int* next2e = edge_index + 8192;

  WtJobs jobs;
  int nj = 0;
  auto add = [&](const float* src, const float* scale, u16* dst,
                 int ld, int row0, int c0, int k0, int dlog, int kslog, int C){
    jobs.j[nj++] = WtJob{src, scale, dst, ld, row0, c0, k0, dlog, kslog, C};
  };
  add(la_win, la_norm_a, wang1, 512, 0,   0,   0,   6, 6, 512);
  add(la_gate,la_norm_a, wang1, 128, 0,   512, 0,   6, 6, 128);
  add(la_win, nullptr,   wij1,  512, 192, 0,   0,   7, 7, 512);
  add(la_gate,nullptr,   wij1,  128, 192, 512, 0,   7, 7, 128);
  add(la_win, nullptr,   wik1,  512, 320, 0,   0,   8, 7, 512);
  add(la_gate,nullptr,   wik1,  128, 320, 512, 0,   8, 7, 128);
  add(la_win, nullptr,   wik1,  512, 64,  0,   128, 8, 7, 512);
  add(la_gate,nullptr,   wik1,  128, 64,  512, 128, 8, 7, 128);
  add(la_wout,la_nw,     wo1T,  128, 0,   0,   0,   8, 8, 128);
  add(lr_win, lr_norm_a, wang3, 512, 0,   0,   0,   6, 6, 512);
  add(lr_win, nullptr,   wij3,  512, 192, 0,   0,   7, 7, 512);
  add(lr_win, nullptr,   wik3,  512, 320, 0,   0,   8, 7, 512);
  add(lr_win, nullptr,   wik3,  512, 64,  0,   128, 8, 7, 512);
  add(lr_wout,lr_nw,     wo3T,  128, 0,   0,   0,   8, 8, 128);
  add(aa_win, nullptr,   whe2,  512, 0,   0,   0,   7, 7, 512);
  add(ae_win, nullptr,   whe2,  512, 0,   512, 0,   7, 7, 512);
  add(aa_src_gate,nullptr,whe2, 128, 0,   1024,0,   7, 7, 128);
  add(ar_win, nullptr,   whe4,  512, 0,   0,   0,   7, 7, 512);
  add(aa_wout, aa_nw,    woaaT, 128, 0,   0,   0,   8, 8, 128);
  add(ae_wout, ae_nw,    woaeT, 128, 0,   0,   0,   8, 8, 128);
  add(ar_wout, ar_nw,    woarT, 128, 0,   0,   0,   8, 8, 128);
  add(ar_eproj,nullptr,  eprjT, 128, 0,   0,   0,   7, 7, 128);
  add(lr_aproj,nullptr,  aprjT, 64,  0,   0,   0,   7, 7, 64);
  build_all_wt<<<dim3(64, 23), b256, 0, stream>>>(jobs);

  hat_init_kernel<<<18432 + 1040, b256, 0, stream>>>(angle_in, hat,
      (const float4*)edge_in, (float4*)out_edge, (const float4*)node_in, (float4*)out_node);

  // ---- block 1 ----
  rmsnorm128c_aug_kernel<<<768, b256, 0, stream>>>(edge_in, la_norm_e, node_in, enca);
  gemm2_bf16_kernel<<<dim3(96,10), b256, 0, stream>>>(enca, 256,
      wij1, preE, 640, 128, 5, wik1, preK, 640, 256);
  angle11_kernel<true><<<1536, b512, 0, stream>>>(hat, preE, preK, wang1, wo1T,
      angle_in, nullptr, nullptr, nullptr, nullptr, nullptr, out_edge, nullptr);

  // ---- block 2 (edge rmsnorm fused into scores3 + edge_fused01) ----
  node_gemm2_kernel<<<dim3(128,16), b128, 0, stream>>>(node_in, aa_norm_n,
      aa_win, npa, ae_win, npe);
  scores3_kernel<<<128, b256, 0, stream>>>(out_edge, aa_norm_e, gateT, scores2);
  edge_fused01_kernel<<<512, b256, 0, stream>>>(out_edge, aa_norm_e, npa, npe, next2e,
      aaWT, aeWT, woaaT, woaeT, scores2, out_edge, partial);
  node_add4_kernel<<<128, b128, 0, stream>>>(partial, out_node);

  // ---- block 3 ----
  rmsnorm128c_aug_kernel<<<768, b256, 0, stream>>>(out_edge, lr_norm_e, out_node, enca);
  gemm2_bf16_kernel<<<dim3(96,8), b256, 0, stream>>>(enca, 256,
      wij3, preE, 512, 128, 4, wik3, preK, 512, 256);
  angle11_kernel<false><<<1536, b512, 0, stream>>>(hat, preE, preK, wang3, wo3T,
      angle_in, rbf, lr_env, a_sw, aprjT, lr_eproj, out_edge, out_angle);

  // ---- block 4 (rmsnorm fused into edge kernel) ----
  node_gemm2_kernel<<<dim3(128,8), b128, 0, stream>>>(out_node, ar_norm_n,
      ar_win, npr, nullptr, nullptr);
  edge_fused2m2_kernel<<<512, b256, 0, stream>>>(out_edge, ar_norm_e, npr, next2e,
      arWT, woarT, rbf, ar_env, sw, eprjT, out_edge, partial);
  node_final4_kernel<<<128, b128, 0, stream>>>(partial, ar_nproj, out_node);

  (void)in_sizes; (void)n_in; (void)out_size; (void)ws_size;
}

// Round 20
// 259.187 us; speedup vs baseline: 1.0037x; 1.0037x over previous
//
#include <hip/hip_runtime.h>
#include <hip/hip_bf16.h>

#define A_SCALE_C 0.6454972243679028f   // (24/10)^-0.5
#define E_SCALE_C 0.3952847075210474f   // (64/10)^-0.5

typedef unsigned short u16;
typedef unsigned int u32;
typedef __attribute__((ext_vector_type(8))) short bf16x8;
typedef __attribute__((ext_vector_type(4))) float f32x4;
typedef __attribute__((ext_vector_type(4))) unsigned short u16x4;
typedef __attribute__((ext_vector_type(8))) unsigned short u16x8;

static __device__ __forceinline__ float waveSum(float v){
#pragma unroll
  for (int off = 32; off; off >>= 1) v += __shfl_xor(v, off, 64);
  return v;
}
static __device__ __forceinline__ float silu(float g){
  return g / (1.0f + __expf(-g));
}
static __device__ __forceinline__ float bf2f(u16 h){
  union { u32 u; float f; } x; x.u = ((u32)h) << 16; return x.f;
}
static __device__ __forceinline__ u16 f2bf(float f){
  __hip_bfloat16 h = __float2bfloat16(f);
  u16 r; __builtin_memcpy(&r, &h, 2); return r;
}
template<int PERM>
static __device__ __forceinline__ int cperm(int c){
  if constexpr (PERM) return (c < 512) ? (((c>>2)&63)*8 + ((c>>8)<<2) + (c&3)) : c;
  else return c;
}

// inline row rmsnorm -> bf16 A-fragments (row covered by l4-group of 4 lanes)
static __device__ __forceinline__ void row_rms_frag(
    const float* __restrict__ rowp, const float* __restrict__ normw,
    int l4, bf16x8* bfr){
  float xr[4][8];
  float ssx = 0.f;
#pragma unroll
  for (int kk=0; kk<4; kk++){
    const float* rp = rowp + kk*32 + l4*8;
    float4 a = *(const float4*)rp;
    float4 bq = *(const float4*)(rp + 4);
    xr[kk][0]=a.x; xr[kk][1]=a.y; xr[kk][2]=a.z; xr[kk][3]=a.w;
    xr[kk][4]=bq.x; xr[kk][5]=bq.y; xr[kk][6]=bq.z; xr[kk][7]=bq.w;
#pragma unroll
    for (int e=0;e<8;e++) ssx = fmaf(xr[kk][e], xr[kk][e], ssx);
  }
  ssx += __shfl_xor(ssx,16,64);
  ssx += __shfl_xor(ssx,32,64);
  const float rsx = rsqrtf(ssx*(1.0f/128.0f) + 1e-6f);
#pragma unroll
  for (int kk=0; kk<4; kk++){
    const float* wp = normw + kk*32 + l4*8;
#pragma unroll
    for (int e=0;e<8;e++) bfr[kk][e] = (short)f2bf(xr[kk][e] * rsx * wp[e]);
  }
}

// ---------------- batched weight-transpose builder ----------------
struct WtJob { const float* src; const float* scale; u16* dst;
               int src_ld, row0, c0, k0, dlog, kslog, C; };
struct WtJobs { WtJob j[23]; };

__global__ __launch_bounds__(256) void build_all_wt(WtJobs P){
  const WtJob J = P.j[blockIdx.y];
  const int ks = 1 << J.kslog;
  const int total = J.C << J.kslog;
  for (int idx = blockIdx.x*256 + threadIdx.x; idx < total; idx += gridDim.x*256){
    int c = idx >> J.kslog, k = idx & (ks-1);
    float s = J.scale ? J.scale[k] : 1.0f;
    J.dst[((size_t)(J.c0 + c) << J.dlog) + J.k0 + k] =
        f2bf(J.src[(size_t)(J.row0 + k)*J.src_ld + c] * s);
  }
}

// ---------------- merged prologue: hat rmsnorm + output init + blk2 node tables ----------------
// bid < 18432: hat; next 1040: copy-init; next 2048: npa/npe node-table GEMM (input-only dep)
__global__ void hat_init_kernel(const float* __restrict__ ang, u16* __restrict__ hat,
                                const float4* __restrict__ e, float4* __restrict__ oe,
                                const float4* __restrict__ n, float4* __restrict__ on,
                                const float* __restrict__ node, const float* __restrict__ nw,
                                const float* __restrict__ Ba, float* __restrict__ Ca,
                                const float* __restrict__ Bb, float* __restrict__ Cb){
  int bid = blockIdx.x;
  const int t = threadIdx.x;
  if (bid < 18432){
    int row = bid*4 + (t >> 6);
    int lane = t & 63;
    float x = ang[(size_t)row*64 + lane];
    float ss = waveSum(x*x);
    float rs = rsqrtf(ss*(1.0f/64.0f) + 1e-6f);
    hat[(size_t)row*64 + lane] = f2bf(x*rs);
  } else if (bid < 18432 + 1040){
    int idx = (bid - 18432)*256 + t;
    if (idx < 262144) oe[idx] = e[idx];
    else if (idx < 262144 + 4096) on[idx - 262144] = n[idx - 262144];
  } else {
    __shared__ float ar[128];
    __shared__ float sred[2];
    const int c2 = bid - (18432 + 1040);     // 0..2047
    const int row = c2 >> 4;                 // 0..127
    const int c = c2 & 15;                   // chunk
    float x = 0.f;
    if (t < 128) x = node[row*128 + t];
    float s = waveSum(x*x);
    if (t < 128 && (t & 63) == 0) sred[t>>6] = s;
    __syncthreads();
    float rs = rsqrtf((sred[0]+sred[1])*(1.0f/128.0f) + 1e-6f);
    if (t < 128) ar[t] = x * rs * nw[t];
    __syncthreads();
    if (t < 128){
      const float* B = (c < 8) ? Ba : Bb;
      float* C = (c < 8) ? Ca : Cb;
      const int cc = c & 7, half = cc >> 2, sub = cc & 3;
      const int brow = 128 + half*128;
      const int col = sub*128 + t;
      float acc = 0.f;
      for (int k=0;k<128;k++) acc = fmaf(ar[k], B[(size_t)(brow+k)*512 + col], acc);
      C[(size_t)row*1024 + half*512 + col] = acc;
    }
  }
}

// compact rmsnorm + node append: enc_aug[3072][256] = [e_n bf16 | node bf16]
__global__ void rmsnorm128c_aug_kernel(const float* __restrict__ x, const float* __restrict__ w,
                                       const float* __restrict__ node, u16* __restrict__ out){
  int row = blockIdx.x*4 + (threadIdx.x >> 6);   // 0..3071
  int lane = threadIdx.x & 63;
  int loc = row/24;
  int src = loc*64 + (row - loc*24);
  float2 v = *(const float2*)(x + (size_t)src*128 + lane*2);
  float ss = waveSum(v.x*v.x + v.y*v.y);
  float rs = rsqrtf(ss*(1.0f/128.0f) + 1e-6f);
  float2 wv = *(const float2*)(w + lane*2);
  u32 pk = (u32)f2bf(v.x*rs*wv.x) | ((u32)f2bf(v.y*rs*wv.y) << 16);
  *(u32*)(out + (size_t)row*256 + lane*2) = pk;
  float2 nv = *(const float2*)(node + loc*128 + lane*2);
  u32 pn = (u32)f2bf(nv.x) | ((u32)f2bf(nv.y) << 16);
  *(u32*)(out + (size_t)row*256 + 128 + lane*2) = pn;
}

// fused node rmsnorm + table GEMM (used for blk4 npr)
__global__ __launch_bounds__(128) void node_gemm2_kernel(
    const float* __restrict__ node, const float* __restrict__ nw,
    const float* __restrict__ Ba, float* __restrict__ Ca,
    const float* __restrict__ Bb, float* __restrict__ Cb){
  __shared__ float ar[128];
  __shared__ float sred[2];
  const int row = blockIdx.x, t = threadIdx.x;
  float x = node[row*128 + t];
  float s = waveSum(x*x);
  if ((t & 63) == 0) sred[t>>6] = s;
  __syncthreads();
  float rs = rsqrtf((sred[0]+sred[1])*(1.0f/128.0f) + 1e-6f);
  ar[t] = x * rs * nw[t];
  __syncthreads();
  const int c = blockIdx.y;
  const float* B = (c < 8) ? Ba : Bb;
  float* C = (c < 8) ? Ca : Cb;
  const int cc = c & 7, half = cc >> 2, sub = cc & 3;
  const int brow = 128 + half*128;
  const int col = sub*128 + t;
  float acc = 0.f;
  for (int k=0;k<128;k++) acc = fmaf(ar[k], B[(size_t)(brow+k)*512 + col], acc);
  C[(size_t)row*1024 + half*512 + col] = acc;
}

// ---------------- dual MFMA GEMM ----------------
__global__ __launch_bounds__(256) void gemm2_bf16_kernel(
    const u16* __restrict__ A, int lda,
    const u16* __restrict__ Bt0, u16* __restrict__ C0, int N0, int K0, int ny0,
    const u16* __restrict__ Bt1, u16* __restrict__ C1, int N1, int K1){
  __shared__ float cl[32*128];
  const int lane = threadIdx.x & 63, wave = threadIdx.x >> 6;
  const int job1 = ((int)blockIdx.y >= ny0);
  const u16* Bt = job1 ? Bt1 : Bt0;
  u16* C = job1 ? C1 : C0;
  const int N = job1 ? N1 : N0;
  const int K = job1 ? K1 : K0;
  const int by = job1 ? ((int)blockIdx.y - ny0) : (int)blockIdx.y;
  const size_t arow = (size_t)blockIdx.x*32;
  const size_t bcol = (size_t)by*128 + wave*32;
  f32x4 acc00={0,0,0,0}, acc01={0,0,0,0}, acc10={0,0,0,0}, acc11={0,0,0,0};
  for (int k=0; k<K; k+=32){
    int ko = k + (lane>>4)*8;
    bf16x8 a0 = *(const bf16x8*)(A + (arow + (lane&15))*lda + ko);
    bf16x8 a1 = *(const bf16x8*)(A + (arow + 16 + (lane&15))*lda + ko);
    bf16x8 b0 = *(const bf16x8*)(Bt + (bcol + (lane&15))*K + ko);
    bf16x8 b1 = *(const bf16x8*)(Bt + (bcol + 16 + (lane&15))*K + ko);
    acc00 = __builtin_amdgcn_mfma_f32_16x16x32_bf16(a0, b0, acc00, 0,0,0);
    acc01 = __builtin_amdgcn_mfma_f32_16x16x32_bf16(a0, b1, acc01, 0,0,0);
    acc10 = __builtin_amdgcn_mfma_f32_16x16x32_bf16(a1, b0, acc10, 0,0,0);
    acc11 = __builtin_amdgcn_mfma_f32_16x16x32_bf16(a1, b1, acc11, 0,0,0);
  }
  const int cr = (lane>>4)*4, cc = wave*32 + (lane&15);
#pragma unroll
  for (int q=0;q<4;q++){
    cl[(cr+q)*128 + cc]      = acc00[q];
    cl[(cr+q)*128 + cc+16]   = acc01[q];
    cl[(16+cr+q)*128 + cc]    = acc10[q];
    cl[(16+cr+q)*128 + cc+16] = acc11[q];
  }
  __syncthreads();
  const int t = threadIdx.x;
#pragma unroll
  for (int i=0;i<16;i++){
    int idx = i*256 + t; int r = idx>>7, c = idx&127;
    int gcol = by*128 + c;
    C[(arow + r)*(size_t)N + cperm<1>(gcol)] = f2bf(cl[idx]);
  }
}

// ---------------- fused angle kernel v11 ----------------
template<bool IS_BLK1>
__global__ __launch_bounds__(512, 4) void angle11_kernel(
    const u16* __restrict__ hat, const u16* __restrict__ preE, const u16* __restrict__ preK,
    const u16* __restrict__ wangT, const u16* __restrict__ woT,
    const float* __restrict__ angle,
    const float* __restrict__ rbf, const float* __restrict__ envW,
    const float* __restrict__ a_sw,
    const u16* __restrict__ aprojTb, const float* __restrict__ eproj,
    float* __restrict__ edge_out, float* __restrict__ angle_out)
{
  constexpr int HW = IS_BLK1 ? 640 : 512;
  constexpr int VGN_B  = 48*264*2;
  constexpr int GATE_O = VGN_B;
  constexpr int SS_O   = GATE_O + (IS_BLK1 ? 48*132*2 : 0);
  constexpr int RS_O   = SS_O + 8*48*4;
  constexpr int SEG_O  = RS_O + 192;
  constexpr int RBF_O  = SEG_O + (IS_BLK1 ? 0 : 1024);
  constexpr int LDS_B  = RBF_O + (IS_BLK1 ? 0 : 1152);
  __shared__ __align__(16) char ldsRaw[LDS_B];
  u16*   vgn    = (u16*)ldsRaw;
  u16*   gateLb = (u16*)(ldsRaw + GATE_O);
  float* ssL    = (float*)(ldsRaw + SS_O);
  float* rsL    = (float*)(ldsRaw + RS_O);
  float* segL   = (float*)(ldsRaw + SEG_O);
  float* rbfL   = (float*)(ldsRaw + RBF_O);
  float* msgL   = (float*)ldsRaw;

  const int t = threadIdx.x, lane = t & 63, w = t >> 6;
  const int l15 = lane & 15, l4 = lane >> 4;
  const int b = blockIdx.x;
  const int xcd = b & 7, idx = b >> 3;
  const int loc = xcd*16 + idx/12;
  const int j0 = (idx - (idx/12)*12)*2;
  const int s0 = loc*24 + j0;
  const int hbase = s0*24;
  const int oc = 16*w + l15;

  if constexpr (!IS_BLK1){
    if (t < 288) rbfL[t] = rbf[(size_t)(loc*64)*12 + t];
  }

  u16x8 pk[3][2], pe[3][2];
  u16x4 pkg[3], peg[3];
#pragma unroll
  for (int nt=0; nt<3; nt++){
    const int r = nt*16 + l15;
    const int hi = (r >= 24);
    const int rr = r - 24*hi;
    const u16* pK = preK + (size_t)(loc*24 + rr)*HW;
    const u16* pE = preE + (size_t)(s0 + hi)*HW;
#pragma unroll
    for (int i=0;i<2;i++){
      const int a = (2*w + i)*4 + l4;
      pk[nt][i] = *(const u16x8*)(pK + a*8);
      pe[nt][i] = *(const u16x8*)(pE + a*8);
    }
    if constexpr (IS_BLK1){
      const int cg = 512 + w*16 + l4*4;
      pkg[nt] = *(const u16x4*)(pK + cg);
      peg[nt] = *(const u16x4*)(pE + cg);
    }
  }

  f32x4 accv[3][2], accg[3][2], accgate[3];
#pragma unroll
  for (int nt=0;nt<3;nt++){
    accv[nt][0]=(f32x4){0,0,0,0}; accv[nt][1]=(f32x4){0,0,0,0};
    accg[nt][0]=(f32x4){0,0,0,0}; accg[nt][1]=(f32x4){0,0,0,0};
    accgate[nt]=(f32x4){0,0,0,0};
  }
#pragma unroll
  for (int kk=0; kk<2; kk++){
    const int ko = kk*32 + l4*8;
    bf16x8 bb[3];
#pragma unroll
    for (int nt=0;nt<3;nt++)
      bb[nt] = *(const bf16x8*)(hat + (size_t)(hbase + nt*16 + l15)*64 + ko);
#pragma unroll
    for (int i=0;i<2;i++){
      const int chv = (2*w + i)*16 + l15;
      bf16x8 av = *(const bf16x8*)(wangT + (size_t)chv*64 + ko);
      bf16x8 ag = *(const bf16x8*)(wangT + (size_t)(256 + chv)*64 + ko);
#pragma unroll
      for (int nt=0;nt<3;nt++){
        accv[nt][i] = __builtin_amdgcn_mfma_f32_16x16x32_bf16(av, bb[nt], accv[nt][i], 0,0,0);
        accg[nt][i] = __builtin_amdgcn_mfma_f32_16x16x32_bf16(ag, bb[nt], accg[nt][i], 0,0,0);
      }
    }
    if constexpr (IS_BLK1){
      bf16x8 aga = *(const bf16x8*)(wangT + (size_t)(512 + w*16 + l15)*64 + ko);
#pragma unroll
      for (int nt=0;nt<3;nt++)
        accgate[nt] = __builtin_amdgcn_mfma_f32_16x16x32_bf16(aga, bb[nt], accgate[nt], 0,0,0);
    }
  }

  float ssr[3] = {0.f, 0.f, 0.f};
#pragma unroll
  for (int nt=0; nt<3; nt++){
    const int r = nt*16 + l15;
#pragma unroll
    for (int i=0;i<2;i++){
      const int cb = (2*w + i)*16 + l4*4;
      u16x4 xs;
#pragma unroll
      for (int q=0;q<4;q++){
        float v = accv[nt][i][q] + bf2f(pk[nt][i][q])   + bf2f(pe[nt][i][q]);
        float g = accg[nt][i][q] + bf2f(pk[nt][i][4+q]) + bf2f(pe[nt][i][4+q]);
        float x = v * silu(g);
        ssr[nt] += x*x;
        xs[q] = f2bf(x);
      }
      *(u16x4*)&vgn[r*264 + cb] = xs;
    }
    if constexpr (IS_BLK1){
      u16x4 gs;
#pragma unroll
      for (int q=0;q<4;q++)
        gs[q] = f2bf((accgate[nt][q] + bf2f(pkg[nt][q]) + bf2f(peg[nt][q])) * A_SCALE_C);
      *(u16x4*)&gateLb[r*132 + w*16 + l4*4] = gs;
    }
  }
#pragma unroll
  for (int nt=0;nt<3;nt++){
    float s = ssr[nt];
    s += __shfl_xor(s,16,64); s += __shfl_xor(s,32,64);
    if (l4 == 0) ssL[w*48 + nt*16 + l15] = s;
  }
  bf16x8 bwp[8];
#pragma unroll
  for (int kk=0; kk<8; kk++)
    bwp[kk] = *(const bf16x8*)(woT + (size_t)oc*256 + kk*32 + l4*8);
  __syncthreads();                    // sync1
  if (t < 48){
    float s_ = 0.f;
#pragma unroll
    for (int k=0;k<8;k++) s_ += ssL[k*48 + t];
    rsL[t] = rsqrtf(s_*(1.0f/256.0f) + 1e-6f);
  }

  f32x4 mac[3];
#pragma unroll
  for (int m=0;m<3;m++) mac[m] = (f32x4){0,0,0,0};
#pragma unroll
  for (int kk=0; kk<8; kk++){
#pragma unroll
    for (int m=0;m<3;m++){
      bf16x8 aw = *(const bf16x8*)&vgn[(m*16 + l15)*264 + kk*32 + l4*8];
      mac[m] = __builtin_amdgcn_mfma_f32_16x16x32_bf16(aw, bwp[kk], mac[m], 0,0,0);
    }
  }
  __syncthreads();                    // sync2
  float rsv[3][4];
#pragma unroll
  for (int m=0;m<3;m++)
#pragma unroll
    for (int q=0;q<4;q++) rsv[m][q] = rsL[m*16 + l4*4 + q];
#pragma unroll
  for (int m=0;m<3;m++)
#pragma unroll
    for (int q=0;q<4;q++)
      msgL[(m*16 + l4*4 + q)*132 + 16*w + l15] = mac[m][q] * rsv[m][q];
  __syncthreads();                    // sync3

  if constexpr (IS_BLK1){
    if (t < 256){
      int s = t>>7, c = t&127;
      float ex[24]; float mx = -1e30f;
#pragma unroll
      for (int k=0;k<24;k++){ ex[k] = bf2f(gateLb[(s*24+k)*132 + c]); mx = fmaxf(mx, ex[k]); }
      float S = 0.f;
#pragma unroll
      for (int k=0;k<24;k++){ ex[k] = __expf(ex[k] - mx); S += ex[k]; }
      float inv = 1.f/(S + 1e-12f);
      float delta = 0.f;
#pragma unroll
      for (int k=0;k<24;k++) delta += msgL[(s*24+k)*132 + c] * ex[k];
      edge_out[(size_t)(loc*64 + j0 + s)*128 + c] += delta * inv;
    }
  } else {
    if (t < 256){
      int s = t>>7, c = t&127;
      float envR[12];
#pragma unroll
      for (int j=0;j<12;j++) envR[j] = envW[j*128 + c];
      float sg_ = 0.f;
#pragma unroll
      for (int k=0;k<24;k++){
        float envC = 0.f;
#pragma unroll
        for (int j=0;j<12;j++) envC = fmaf(rbfL[k*12 + j], envR[j], envC);
        sg_ += msgL[(s*24+k)*132 + c] * envC * a_sw[(size_t)(s0+s)*24 + k];
      }
      segL[s*128 + c] = sg_;
    }
    for (int p = w; p < 12; p += 8){
      const int mt = p >> 2, ntc = p & 3;
      f32x4 am = (f32x4){0,0,0,0};
#pragma unroll
      for (int kk=0; kk<4; kk++){
        const float* mrow = &msgL[(mt*16 + l15)*132 + kk*32 + l4*8];
        bf16x8 a;
#pragma unroll
        for (int e=0;e<8;e++) a[e] = (short)f2bf(mrow[e]);
        bf16x8 bb = *(const bf16x8*)(aprojTb + (size_t)(ntc*16 + l15)*128 + kk*32 + l4*8);
        am = __builtin_amdgcn_mfma_f32_16x16x32_bf16(a, bb, am, 0,0,0);
      }
#pragma unroll
      for (int q=0;q<4;q++){
        int row = mt*16 + l4*4 + q;
        size_t a_ = (size_t)hbase + row;
        int col = ntc*16 + l15;
        angle_out[a_*64 + col] = angle[a_*64 + col] + am[q] * a_sw[a_];
      }
    }
    __syncthreads();
    if (t < 256){
      int s = t>>7, c = t&127;
      float acc2 = 0.f;
      for (int dd=0; dd<128; dd++) acc2 = fmaf(segL[s*128 + dd], eproj[dd*128 + c], acc2);
      edge_out[(size_t)(loc*64 + j0 + s)*128 + c] += acc2 * A_SCALE_C;
    }
  }
}

// ---------------- scores v3: inline rmsnorm + MFMA gate + softmax ----------------
__global__ __launch_bounds__(256) void scores3_kernel(const float* __restrict__ edge_src,
                                                      const float* __restrict__ norm_e,
                                                      const u16* __restrict__ gateT,
                                                      float* __restrict__ scores){
  __shared__ float s[64*132];
  const int t = threadIdx.x, lane = t & 63, w = t >> 6;
  const int l15 = lane & 15, l4 = lane >> 4;
  const int n = blockIdx.x;
  const int row = n*64 + w*16 + l15;
  bf16x8 bfr[4];
  row_rms_frag(edge_src + (size_t)row*128, norm_e, l4, bfr);
  f32x4 acc[8];
#pragma unroll
  for (int j=0;j<8;j++) acc[j] = (f32x4){0,0,0,0};
#pragma unroll
  for (int kk=0; kk<4; kk++){
    const int ko = kk*32 + l4*8;
#pragma unroll
    for (int j=0;j<8;j++){
      bf16x8 b = *(const bf16x8*)(gateT + (size_t)(j*16 + l15)*128 + ko);
      acc[j] = __builtin_amdgcn_mfma_f32_16x16x32_bf16(bfr[kk], b, acc[j], 0,0,0);
    }
  }
#pragma unroll
  for (int j=0;j<8;j++)
#pragma unroll
    for (int q=0;q<4;q++)
      s[(w*16 + l4*4 + q)*132 + j*16 + l15] = acc[j][q] * E_SCALE_C;
  __syncthreads();
  if (t < 128){
    float m = -1e30f;
    for (int r=0;r<64;r++) m = fmaxf(m, s[r*132 + t]);
    float S = 0.f;
    for (int r=0;r<64;r++) S += __expf(s[r*132 + t] - m);
    float inv = 1.f/(S + 1e-12f);
    for (int r=0;r<64;r++)
      scores[(size_t)(n*64 + r)*128 + t] = __expf(s[r*132 + t] - m) * inv;
  }
}

// ---------------- combined blk2 edge kernel (inline rmsnorm) ----------------
__global__ __launch_bounds__(256) void edge_fused01_kernel(
    const float* __restrict__ edge_src,
    const float* __restrict__ norm_e,
    const float* __restrict__ NPa, const float* __restrict__ NPe,
    const int* __restrict__ next2e,
    const u16* __restrict__ aaWT, const u16* __restrict__ aeWT,
    const u16* __restrict__ woaaT, const u16* __restrict__ woaeT,
    const float* __restrict__ scores,
    float* __restrict__ edge_out, float* __restrict__ partial){
  __shared__ __align__(16) char lds[13184];
  u16*   vgn  = (u16*)lds;
  float* msgF = (float*)lds;
  float* ssP  = (float*)(lds + 12800);
  float* rsL  = (float*)(lds + 13056);
  const int t = threadIdx.x, lane = t & 63, w = t >> 6;
  const int l15 = lane & 15, l4 = lane >> 4;
  const int g = blockIdx.x, e0 = g*16, n = e0 >> 6;
  const int nx = next2e[e0 + l15];

  bf16x8 bfr[4];
  row_rms_frag(edge_src + (size_t)(e0 + l15)*128, norm_e, l4, bfr);

#pragma unroll
  for (int path=0; path<2; path++){
    const u16* wT  = path ? aeWT : aaWT;
    const u16* woT = path ? woaeT : woaaT;
    const float* NPt = path ? NPe : NPa;

    f32x4 av4[4], ag4[4];
#pragma unroll
    for (int i=0;i<4;i++){ av4[i]=(f32x4){0,0,0,0}; ag4[i]=(f32x4){0,0,0,0}; }
#pragma unroll
    for (int kk=0; kk<4; kk++){
      const int ko = kk*32 + l4*8;
#pragma unroll
      for (int i=0;i<4;i++){
        const int chr = w*64 + i*16 + l15;
        bf16x8 wv = *(const bf16x8*)(wT + (size_t)chr*128 + ko);
        bf16x8 wg = *(const bf16x8*)(wT + (size_t)(256 + chr)*128 + ko);
        av4[i] = __builtin_amdgcn_mfma_f32_16x16x32_bf16(wv, bfr[kk], av4[i], 0,0,0);
        ag4[i] = __builtin_amdgcn_mfma_f32_16x16x32_bf16(wg, bfr[kk], ag4[i], 0,0,0);
      }
    }

    float ssr = 0.f;
#pragma unroll
    for (int i=0;i<4;i++){
      const int cb = w*64 + i*16 + l4*4;
      float4 sv = *(const float4*)(NPt + n*1024 + cb);
      float4 sg = *(const float4*)(NPt + n*1024 + 256 + cb);
      float4 nv = *(const float4*)(NPt + (size_t)nx*1024 + 512 + cb);
      float4 ng = *(const float4*)(NPt + (size_t)nx*1024 + 768 + cb);
      u16x4 xs;
#pragma unroll
      for (int q=0;q<4;q++){
        float v  = av4[i][q] + ((const float*)&sv)[q] + ((const float*)&nv)[q];
        float gg = ag4[i][q] + ((const float*)&sg)[q] + ((const float*)&ng)[q];
        float x = v * silu(gg);
        ssr += x*x;
        xs[q] = f2bf(x);
      }
      *(u16x4*)&vgn[l15*264 + cb] = xs;
    }
    {
      float s = ssr;
      s += __shfl_xor(s,16,64); s += __shfl_xor(s,32,64);
      if (l4 == 0) ssP[l15*4 + w] = s;
    }
    __syncthreads();
    if (t < 16)
      rsL[t] = rsqrtf((ssP[t*4]+ssP[t*4+1]+ssP[t*4+2]+ssP[t*4+3])*(1.0f/256.0f) + 1e-6f);
    __syncthreads();
    f32x4 mac[2] = {(f32x4){0,0,0,0}, (f32x4){0,0,0,0}};
#pragma unroll
    for (int kk=0; kk<8; kk++){
      bf16x8 a = *(const bf16x8*)&vgn[l15*264 + kk*32 + l4*8];
#pragma unroll
      for (int nt=0; nt<2; nt++){
        bf16x8 bw = *(const bf16x8*)(woT + (size_t)(32*w + nt*16 + l15)*256 + kk*32 + l4*8);
        mac[nt] = __builtin_amdgcn_mfma_f32_16x16x32_bf16(a, bw, mac[nt], 0,0,0);
      }
    }
    float rsv[4];
#pragma unroll
    for (int q=0;q<4;q++) rsv[q] = rsL[l4*4 + q];
    __syncthreads();
#pragma unroll
    for (int nt=0; nt<2; nt++)
#pragma unroll
      for (int q=0;q<4;q++)
        msgF[(l4*4 + q)*132 + 32*w + nt*16 + l15] = mac[nt][q] * rsv[q];
    __syncthreads();

    if (path == 0){
      if (t < 128){
        float p = 0.f;
#pragma unroll
        for (int r=0;r<16;r++) p += msgF[r*132 + t] * scores[(size_t)(e0+r)*128 + t];
        partial[g*128 + t] = p;
      }
    } else {
      const int d = t & 127, rg = (t >> 7) * 8;
#pragma unroll
      for (int i=0;i<8;i++)
        edge_out[(size_t)(e0+rg+i)*128 + d] += msgF[(rg+i)*132 + d];
    }
    __syncthreads();
  }
}

// ---------------- blk4 edge kernel: MODE2 with fused rmsnorm ----------------
__global__ __launch_bounds__(256) void edge_fused2m2_kernel(
    const float* __restrict__ edge_src,
    const float* __restrict__ norm_e,
    const float* __restrict__ NPt,
    const int* __restrict__ next2e,
    const u16* __restrict__ wT,
    const u16* __restrict__ woT,
    const float* __restrict__ rbf, const float* __restrict__ envW,
    const float* __restrict__ sw, const u16* __restrict__ eprojT,
    float* __restrict__ edge_out, float* __restrict__ partial){
  __shared__ __align__(16) char lds[20096];
  u16*   vgn  = (u16*)lds;
  float* msgF = (float*)lds;
  u16*   msgB = (u16*)(lds + 8448);
  float* ssP  = (float*)(lds + 12800);
  float* rsL  = (float*)(lds + 13056);
  float* envWL= (float*)(lds + 13184);
  float* rbfL = (float*)(lds + 19328);
  const int t = threadIdx.x, lane = t & 63, w = t >> 6;
  const int l15 = lane & 15, l4 = lane >> 4;
  const int g = blockIdx.x, e0 = g*16, n = e0 >> 6;
  const int nx = next2e[e0 + l15];
  for (int i=t; i<12*128; i+=256) envWL[i] = envW[i];
  if (t < 192) rbfL[t] = rbf[(size_t)e0*12 + t];

  bf16x8 bfr[4];
  row_rms_frag(edge_src + (size_t)(e0 + l15)*128, norm_e, l4, bfr);

  float4 sv[4], sg[4], nv[4], ng[4];
#pragma unroll
  for (int i=0;i<4;i++){
    const int cb = w*64 + i*16 + l4*4;
    sv[i] = *(const float4*)(NPt + n*1024 + cb);
    sg[i] = *(const float4*)(NPt + n*1024 + 256 + cb);
    nv[i] = *(const float4*)(NPt + (size_t)nx*1024 + 512 + cb);
    ng[i] = *(const float4*)(NPt + (size_t)nx*1024 + 768 + cb);
  }

  f32x4 av4[4], ag4[4];
#pragma unroll
  for (int i=0;i<4;i++){ av4[i]=(f32x4){0,0,0,0}; ag4[i]=(f32x4){0,0,0,0}; }
#pragma unroll
  for (int kk=0; kk<4; kk++){
    const int ko = kk*32 + l4*8;
#pragma unroll
    for (int i=0;i<4;i++){
      const int chr = w*64 + i*16 + l15;
      bf16x8 wv = *(const bf16x8*)(wT + (size_t)chr*128 + ko);
      bf16x8 wg = *(const bf16x8*)(wT + (size_t)(256 + chr)*128 + ko);
      av4[i] = __builtin_amdgcn_mfma_f32_16x16x32_bf16(wv, bfr[kk], av4[i], 0,0,0);
      ag4[i] = __builtin_amdgcn_mfma_f32_16x16x32_bf16(wg, bfr[kk], ag4[i], 0,0,0);
    }
  }

  float ssr = 0.f;
#pragma unroll
  for (int i=0;i<4;i++){
    const int cb = w*64 + i*16 + l4*4;
    u16x4 xs;
#pragma unroll
    for (int q=0;q<4;q++){
      float v = av4[i][q] + ((const float*)&sv[i])[q] + ((const float*)&nv[i])[q];
      float gg = ag4[i][q] + ((const float*)&sg[i])[q] + ((const float*)&ng[i])[q];
      float x = v * silu(gg);
      ssr += x*x;
      xs[q] = f2bf(x);
    }
    *(u16x4*)&vgn[l15*264 + cb] = xs;
  }
  {
    float s = ssr;
    s += __shfl_xor(s,16,64); s += __shfl_xor(s,32,64);
    if (l4 == 0) ssP[l15*4 + w] = s;
  }
  __syncthreads();
  if (t < 16)
    rsL[t] = rsqrtf((ssP[t*4]+ssP[t*4+1]+ssP[t*4+2]+ssP[t*4+3])*(1.0f/256.0f) + 1e-6f);
  __syncthreads();
  f32x4 mac[2] = {(f32x4){0,0,0,0}, (f32x4){0,0,0,0}};
#pragma unroll
  for (int kk=0; kk<8; kk++){
    bf16x8 a = *(const bf16x8*)&vgn[l15*264 + kk*32 + l4*8];
#pragma unroll
    for (int nt=0; nt<2; nt++){
      bf16x8 bw = *(const bf16x8*)(woT + (size_t)(32*w + nt*16 + l15)*256 + kk*32 + l4*8);
      mac[nt] = __builtin_amdgcn_mfma_f32_16x16x32_bf16(a, bw, mac[nt], 0,0,0);
    }
  }
  float rsv[4];
#pragma unroll
  for (int q=0;q<4;q++) rsv[q] = rsL[l4*4 + q];
  __syncthreads();
#pragma unroll
  for (int nt=0; nt<2; nt++)
#pragma unroll
    for (int q=0;q<4;q++){
      float val = mac[nt][q] * rsv[q];
      int row = l4*4 + q, col = 32*w + nt*16 + l15;
      msgF[row*132 + col] = val;
      msgB[row*136 + col] = f2bf(val);
    }
  __syncthreads();

  f32x4 em[2] = {(f32x4){0,0,0,0}, (f32x4){0,0,0,0}};
#pragma unroll
  for (int kk=0; kk<4; kk++){
    bf16x8 a = *(const bf16x8*)&msgB[l15*136 + kk*32 + l4*8];
#pragma unroll
    for (int nt=0; nt<2; nt++){
      bf16x8 bw = *(const bf16x8*)(eprojT + (size_t)(32*w + nt*16 + l15)*128 + kk*32 + l4*8);
      em[nt] = __builtin_amdgcn_mfma_f32_16x16x32_bf16(a, bw, em[nt], 0,0,0);
    }
  }
#pragma unroll
  for (int nt=0; nt<2; nt++)
#pragma unroll
    for (int q=0;q<4;q++)
      edge_out[(size_t)(e0 + l4*4 + q)*128 + 32*w + nt*16 + l15] += em[nt][q];
  if (t < 128){
    float p = 0.f;
#pragma unroll
    for (int r=0;r<16;r++){
      float envC = 0.f;
#pragma unroll
      for (int j=0;j<12;j++) envC = fmaf(rbfL[r*12 + j], envWL[j*128 + t], envC);
      p += msgF[r*132 + t] * envC * sw[e0 + r];
    }
    partial[g*128 + t] = p;
  }
}

__global__ void node_add4_kernel(const float* __restrict__ partial, float* __restrict__ node_out){
  int n = blockIdx.x, t = threadIdx.x;
  node_out[n*128 + t] += partial[(4*n)*128+t] + partial[(4*n+1)*128+t]
                       + partial[(4*n+2)*128+t] + partial[(4*n+3)*128+t];
}

__global__ void node_final4_kernel(const float* __restrict__ partial,
                                   const float* __restrict__ nproj,
                                   float* __restrict__ node_out){
  __shared__ float seg[128];
  int n = blockIdx.x, t = threadIdx.x;
  seg[t] = partial[(4*n)*128+t] + partial[(4*n+1)*128+t]
         + partial[(4*n+2)*128+t] + partial[(4*n+3)*128+t];
  __syncthreads();
  float acc = 0.f;
  for (int dd=0; dd<128; dd++) acc = fmaf(seg[dd], nproj[dd*128 + t], acc);
  node_out[n*128 + t] += acc * E_SCALE_C;
}

// ---------------- launch ----------------
extern "C" void kernel_launch(void* const* d_in, const int* in_sizes, int n_in,
                              void* d_out, int out_size, void* d_ws, size_t ws_size,
                              hipStream_t stream){
  const float* node_in  = (const float*)d_in[0];
  const float* edge_in  = (const float*)d_in[1];
  const float* angle_in = (const float*)d_in[2];
  const float* sw       = (const float*)d_in[3];
  const float* a_sw     = (const float*)d_in[4];
  const float* rbf      = (const float*)d_in[5];
  const int*   edge_index = (const int*)d_in[6];
  const float* la_norm_e = (const float*)d_in[8];
  const float* la_norm_a = (const float*)d_in[9];
  const float* la_win    = (const float*)d_in[10];
  const float* la_nw     = (const float*)d_in[11];
  const float* la_wout   = (const float*)d_in[12];
  const float* la_gate   = (const float*)d_in[13];
  const float* aa_norm_n = (const float*)d_in[14];
  const float* aa_norm_e = (const float*)d_in[15];
  const float* aa_win    = (const float*)d_in[16];
  const float* aa_nw     = (const float*)d_in[17];
  const float* aa_wout   = (const float*)d_in[18];
  const float* aa_src_gate = (const float*)d_in[19];
  const float* ae_win    = (const float*)d_in[20];
  const float* ae_nw     = (const float*)d_in[21];
  const float* ae_wout   = (const float*)d_in[22];
  const float* lr_norm_e = (const float*)d_in[23];
  const float* lr_norm_a = (const float*)d_in[24];
  const float* lr_win    = (const float*)d_in[25];
  const float* lr_nw     = (const float*)d_in[26];
  const float* lr_wout   = (const float*)d_in[27];
  const float* lr_env    = (const float*)d_in[28];
  const float* lr_eproj  = (const float*)d_in[29];
  const float* lr_aproj  = (const float*)d_in[30];
  const float* ar_norm_n = (const float*)d_in[31];
  const float* ar_norm_e = (const float*)d_in[32];
  const float* ar_win    = (const float*)d_in[33];
  const float* ar_nw     = (const float*)d_in[34];
  const float* ar_wout   = (const float*)d_in[35];
  const float* ar_env    = (const float*)d_in[36];
  const float* ar_nproj  = (const float*)d_in[37];
  const float* ar_eproj  = (const float*)d_in[38];

  float* out_node  = (float*)d_out;
  float* out_edge  = out_node + 128*128;
  float* out_angle = out_edge + (size_t)8192*128;

  float* p = (float*)d_ws;
  float* hat_f   = p; p += 2359296;
  float* enca_f  = p; p += 393216;
  float* preE_f  = p; p += 983040;
  float* preK_f  = p; p += 983040;
  float* wang1_f = p; p += 20480;
  float* wang3_f = p; p += 16384;
  float* wij1_f  = p; p += 40960;
  float* wij3_f  = p; p += 32768;
  float* wik1_f  = p; p += 81920;
  float* wik3_f  = p; p += 65536;
  float* wo1T_f  = p; p += 16384;
  float* wo3T_f  = p; p += 16384;
  float* whe2_f  = p; p += 73728;
  float* whe4_f  = p; p += 32768;
  float* woaaT_f = p; p += 16384;
  float* woaeT_f = p; p += 16384;
  float* woarT_f = p; p += 16384;
  float* eprjT_f = p; p += 8192;
  float* aprjT_f = p; p += 4096;
  float* npa     = p; p += 131072;
  float* npe     = p; p += 131072;
  float* npr     = p; p += 131072;
  float* scores2 = p; p += 1048576;
  float* partial = p; p += 65536;

  u16* hat  = (u16*)hat_f;
  u16* enca = (u16*)enca_f;
  u16* preE = (u16*)preE_f;
  u16* preK = (u16*)preK_f;
  u16* wang1= (u16*)wang1_f;
  u16* wang3= (u16*)wang3_f;
  u16* wij1 = (u16*)wij1_f;
  u16* wij3 = (u16*)wij3_f;
  u16* wik1 = (u16*)wik1_f;
  u16* wik3 = (u16*)wik3_f;
  u16* wo1T = (u16*)wo1T_f;
  u16* wo3T = (u16*)wo3T_f;
  u16* whe2 = (u16*)whe2_f;
  u16* whe4 = (u16*)whe4_f;
  u16* woaaT= (u16*)woaaT_f;
  u16* woaeT= (u16*)woaeT_f;
  u16* woarT= (u16*)woarT_f;
  u16* eprjT= (u16*)eprjT_f;
  u16* aprjT= (u16*)aprjT_f;
  u16* aaWT = whe2;
  u16* aeWT = whe2 + 512*128;
  u16* gateT= whe2 + 1024*128;
  u16* arWT = whe4;

  dim3 b512(512), b256(256), b128(128);
  const int* next2e = edge_index + 8192;

  WtJobs jobs;
  int nj = 0;
  auto add = [&](const float* src, const float* scale, u16* dst,
                 int ld, int row0, int c0, int k0, int dlog, int kslog, int C){
    jobs.j[nj++] = WtJob{src, scale, dst, ld, row0, c0, k0, dlog, kslog, C};
  };
  add(la_win, la_norm_a, wang1, 512, 0,   0,   0,   6, 6, 512);
  add(la_gate,la_norm_a, wang1, 128, 0,   512, 0,   6, 6, 128);
  add(la_win, nullptr,   wij1,  512, 192, 0,   0,   7, 7, 512);
  add(la_gate,nullptr,   wij1,  128, 192, 512, 0,   7, 7, 128);
  add(la_win, nullptr,   wik1,  512, 320, 0,   0,   8, 7, 512);
  add(la_gate,nullptr,   wik1,  128, 320, 512, 0,   8, 7, 128);
  add(la_win, nullptr,   wik1,  512, 64,  0,   128, 8, 7, 512);
  add(la_gate,nullptr,   wik1,  128, 64,  512, 128, 8, 7, 128);
  add(la_wout,la_nw,     wo1T,  128, 0,   0,   0,   8, 8, 128);
  add(lr_win, lr_norm_a, wang3, 512, 0,   0,   0,   6, 6, 512);
  add(lr_win, nullptr,   wij3,  512, 192, 0,   0,   7, 7, 512);
  add(lr_win, nullptr,   wik3,  512, 320, 0,   0,   8, 7, 512);
  add(lr_win, nullptr,   wik3,  512, 64,  0,   128, 8, 7, 512);
  add(lr_wout,lr_nw,     wo3T,  128, 0,   0,   0,   8, 8, 128);
  add(aa_win, nullptr,   whe2,  512, 0,   0,   0,   7, 7, 512);
  add(ae_win, nullptr,   whe2,  512, 0,   512, 0,   7, 7, 512);
  add(aa_src_gate,nullptr,whe2, 128, 0,   1024,0,   7, 7, 128);
  add(ar_win, nullptr,   whe4,  512, 0,   0,   0,   7, 7, 512);
  add(aa_wout, aa_nw,    woaaT, 128, 0,   0,   0,   8, 8, 128);
  add(ae_wout, ae_nw,    woaeT, 128, 0,   0,   0,   8, 8, 128);
  add(ar_wout, ar_nw,    woarT, 128, 0,   0,   0,   8, 8, 128);
  add(ar_eproj,nullptr,  eprjT, 128, 0,   0,   0,   7, 7, 128);
  add(lr_aproj,nullptr,  aprjT, 64,  0,   0,   0,   7, 7, 64);
  build_all_wt<<<dim3(64, 23), b256, 0, stream>>>(jobs);

  // prologue: hat + init + blk2 node tables (input-only deps) in one launch
  hat_init_kernel<<<18432 + 1040 + 2048, b256, 0, stream>>>(angle_in, hat,
      (const float4*)edge_in, (float4*)out_edge, (const float4*)node_in, (float4*)out_node,
      node_in, aa_norm_n, aa_win, npa, ae_win, npe);

  // ---- block 1 ----
  rmsnorm128c_aug_kernel<<<768, b256, 0, stream>>>(edge_in, la_norm_e, node_in, enca);
  gemm2_bf16_kernel<<<dim3(96,10), b256, 0, stream>>>(enca, 256,
      wij1, preE, 640, 128, 5, wik1, preK, 640, 256);
  angle11_kernel<true><<<1536, b512, 0, stream>>>(hat, preE, preK, wang1, wo1T,
      angle_in, nullptr, nullptr, nullptr, nullptr, nullptr, out_edge, nullptr);

  // ---- block 2 (edge rmsnorm fused into scores3 + edge_fused01) ----
  scores3_kernel<<<128, b256, 0, stream>>>(out_edge, aa_norm_e, gateT, scores2);
  edge_fused01_kernel<<<512, b256, 0, stream>>>(out_edge, aa_norm_e, npa, npe, next2e,
      aaWT, aeWT, woaaT, woaeT, scores2, out_edge, partial);
  node_add4_kernel<<<128, b128, 0, stream>>>(partial, out_node);

  // ---- block 3 ----
  rmsnorm128c_aug_kernel<<<768, b256, 0, stream>>>(out_edge, lr_norm_e, out_node, enca);
  gemm2_bf16_kernel<<<dim3(96,8), b256, 0, stream>>>(enca, 256,
      wij3, preE, 512, 128, 4, wik3, preK, 512, 256);
  angle11_kernel<false><<<1536, b512, 0, stream>>>(hat, preE, preK, wang3, wo3T,
      angle_in, rbf, lr_env, a_sw, aprjT, lr_eproj, out_edge, out_angle);

  // ---- block 4 (rmsnorm fused into edge kernel) ----
  node_gemm2_kernel<<<dim3(128,8), b128, 0, stream>>>(out_node, ar_norm_n,
      ar_win, npr, nullptr, nullptr);
  edge_fused2m2_kernel<<<512, b256, 0, stream>>>(out_edge, ar_norm_e, npr, next2e,
      arWT, woarT, rbf, ar_env, sw, eprjT, out_edge, partial);
  node_final4_kernel<<<128, b128, 0, stream>>>(partial, ar_nproj, out_node);

  (void)in_sizes; (void)n_in; (void)out_size; (void)ws_size;
}

// Round 21
// 257.563 us; speedup vs baseline: 1.0100x; 1.0063x over previous
//
#include <hip/hip_runtime.h>
#include <hip/hip_bf16.h>

#define A_SCALE_C 0.6454972243679028f   // (24/10)^-0.5
#define E_SCALE_C 0.3952847075210474f   // (64/10)^-0.5

typedef unsigned short u16;
typedef unsigned int u32;
typedef __attribute__((ext_vector_type(8))) short bf16x8;
typedef __attribute__((ext_vector_type(4))) float f32x4;
typedef __attribute__((ext_vector_type(4))) unsigned short u16x4;
typedef __attribute__((ext_vector_type(8))) unsigned short u16x8;

// XOR swizzle for vgn LDS rows (u16 units; 16B granularity)
#define SWZ(r, c) ((c) ^ (((r)&7)<<3))

static __device__ __forceinline__ float waveSum(float v){
#pragma unroll
  for (int off = 32; off; off >>= 1) v += __shfl_xor(v, off, 64);
  return v;
}
static __device__ __forceinline__ float silu(float g){
  return g / (1.0f + __expf(-g));
}
static __device__ __forceinline__ float bf2f(u16 h){
  union { u32 u; float f; } x; x.u = ((u32)h) << 16; return x.f;
}
static __device__ __forceinline__ u16 f2bf(float f){
  __hip_bfloat16 h = __float2bfloat16(f);
  u16 r; __builtin_memcpy(&r, &h, 2); return r;
}
template<int PERM>
static __device__ __forceinline__ int cperm(int c){
  if constexpr (PERM) return (c < 512) ? (((c>>2)&63)*8 + ((c>>8)<<2) + (c&3)) : c;
  else return c;
}

// inline row rmsnorm -> bf16 A-fragments (row covered by l4-group of 4 lanes)
static __device__ __forceinline__ void row_rms_frag(
    const float* __restrict__ rowp, const float* __restrict__ normw,
    int l4, bf16x8* bfr){
  float xr[4][8];
  float ssx = 0.f;
#pragma unroll
  for (int kk=0; kk<4; kk++){
    const float* rp = rowp + kk*32 + l4*8;
    float4 a = *(const float4*)rp;
    float4 bq = *(const float4*)(rp + 4);
    xr[kk][0]=a.x; xr[kk][1]=a.y; xr[kk][2]=a.z; xr[kk][3]=a.w;
    xr[kk][4]=bq.x; xr[kk][5]=bq.y; xr[kk][6]=bq.z; xr[kk][7]=bq.w;
#pragma unroll
    for (int e=0;e<8;e++) ssx = fmaf(xr[kk][e], xr[kk][e], ssx);
  }
  ssx += __shfl_xor(ssx,16,64);
  ssx += __shfl_xor(ssx,32,64);
  const float rsx = rsqrtf(ssx*(1.0f/128.0f) + 1e-6f);
#pragma unroll
  for (int kk=0; kk<4; kk++){
    const float* wp = normw + kk*32 + l4*8;
#pragma unroll
    for (int e=0;e<8;e++) bfr[kk][e] = (short)f2bf(xr[kk][e] * rsx * wp[e]);
  }
}

// ---------------- batched weight-transpose builder ----------------
struct WtJob { const float* src; const float* scale; u16* dst;
               int src_ld, row0, c0, k0, dlog, kslog, C; };
struct WtJobs { WtJob j[23]; };

__global__ __launch_bounds__(256) void build_all_wt(WtJobs P){
  const WtJob J = P.j[blockIdx.y];
  const int ks = 1 << J.kslog;
  const int total = J.C << J.kslog;
  for (int idx = blockIdx.x*256 + threadIdx.x; idx < total; idx += gridDim.x*256){
    int c = idx >> J.kslog, k = idx & (ks-1);
    float s = J.scale ? J.scale[k] : 1.0f;
    J.dst[((size_t)(J.c0 + c) << J.dlog) + J.k0 + k] =
        f2bf(J.src[(size_t)(J.row0 + k)*J.src_ld + c] * s);
  }
}

// ---------------- merged prologue: hat rmsnorm + output init + blk2 node tables ----------------
__global__ void hat_init_kernel(const float* __restrict__ ang, u16* __restrict__ hat,
                                const float4* __restrict__ e, float4* __restrict__ oe,
                                const float4* __restrict__ n, float4* __restrict__ on,
                                const float* __restrict__ node, const float* __restrict__ nw,
                                const float* __restrict__ Ba, float* __restrict__ Ca,
                                const float* __restrict__ Bb, float* __restrict__ Cb){
  int bid = blockIdx.x;
  const int t = threadIdx.x;
  if (bid < 18432){
    int row = bid*4 + (t >> 6);
    int lane = t & 63;
    float x = ang[(size_t)row*64 + lane];
    float ss = waveSum(x*x);
    float rs = rsqrtf(ss*(1.0f/64.0f) + 1e-6f);
    hat[(size_t)row*64 + lane] = f2bf(x*rs);
  } else if (bid < 18432 + 1040){
    int idx = (bid - 18432)*256 + t;
    if (idx < 262144) oe[idx] = e[idx];
    else if (idx < 262144 + 4096) on[idx - 262144] = n[idx - 262144];
  } else {
    __shared__ float ar[128];
    __shared__ float sred[2];
    const int c2 = bid - (18432 + 1040);     // 0..2047
    const int row = c2 >> 4;                 // 0..127
    const int c = c2 & 15;                   // chunk
    float x = 0.f;
    if (t < 128) x = node[row*128 + t];
    float s = waveSum(x*x);
    if (t < 128 && (t & 63) == 0) sred[t>>6] = s;
    __syncthreads();
    float rs = rsqrtf((sred[0]+sred[1])*(1.0f/128.0f) + 1e-6f);
    if (t < 128) ar[t] = x * rs * nw[t];
    __syncthreads();
    if (t < 128){
      const float* B = (c < 8) ? Ba : Bb;
      float* C = (c < 8) ? Ca : Cb;
      const int cc = c & 7, half = cc >> 2, sub = cc & 3;
      const int brow = 128 + half*128;
      const int col = sub*128 + t;
      float acc = 0.f;
      for (int k=0;k<128;k++) acc = fmaf(ar[k], B[(size_t)(brow+k)*512 + col], acc);
      C[(size_t)row*1024 + half*512 + col] = acc;
    }
  }
}

// compact rmsnorm + node append: enc_aug[3072][256] = [e_n bf16 | node bf16]
__global__ void rmsnorm128c_aug_kernel(const float* __restrict__ x, const float* __restrict__ w,
                                       const float* __restrict__ node, u16* __restrict__ out){
  int row = blockIdx.x*4 + (threadIdx.x >> 6);   // 0..3071
  int lane = threadIdx.x & 63;
  int loc = row/24;
  int src = loc*64 + (row - loc*24);
  float2 v = *(const float2*)(x + (size_t)src*128 + lane*2);
  float ss = waveSum(v.x*v.x + v.y*v.y);
  float rs = rsqrtf(ss*(1.0f/128.0f) + 1e-6f);
  float2 wv = *(const float2*)(w + lane*2);
  u32 pk = (u32)f2bf(v.x*rs*wv.x) | ((u32)f2bf(v.y*rs*wv.y) << 16);
  *(u32*)(out + (size_t)row*256 + lane*2) = pk;
  float2 nv = *(const float2*)(node + loc*128 + lane*2);
  u32 pn = (u32)f2bf(nv.x) | ((u32)f2bf(nv.y) << 16);
  *(u32*)(out + (size_t)row*256 + 128 + lane*2) = pn;
}

// fused node rmsnorm + table GEMM (blk4 npr)
__global__ __launch_bounds__(128) void node_gemm2_kernel(
    const float* __restrict__ node, const float* __restrict__ nw,
    const float* __restrict__ Ba, float* __restrict__ Ca,
    const float* __restrict__ Bb, float* __restrict__ Cb){
  __shared__ float ar[128];
  __shared__ float sred[2];
  const int row = blockIdx.x, t = threadIdx.x;
  float x = node[row*128 + t];
  float s = waveSum(x*x);
  if ((t & 63) == 0) sred[t>>6] = s;
  __syncthreads();
  float rs = rsqrtf((sred[0]+sred[1])*(1.0f/128.0f) + 1e-6f);
  ar[t] = x * rs * nw[t];
  __syncthreads();
  const int c = blockIdx.y;
  const float* B = (c < 8) ? Ba : Bb;
  float* C = (c < 8) ? Ca : Cb;
  const int cc = c & 7, half = cc >> 2, sub = cc & 3;
  const int brow = 128 + half*128;
  const int col = sub*128 + t;
  float acc = 0.f;
  for (int k=0;k<128;k++) acc = fmaf(ar[k], B[(size_t)(brow+k)*512 + col], acc);
  C[(size_t)row*1024 + half*512 + col] = acc;
}

// ---------------- dual MFMA GEMM ----------------
__global__ __launch_bounds__(256) void gemm2_bf16_kernel(
    const u16* __restrict__ A, int lda,
    const u16* __restrict__ Bt0, u16* __restrict__ C0, int N0, int K0, int ny0,
    const u16* __restrict__ Bt1, u16* __restrict__ C1, int N1, int K1){
  __shared__ float cl[32*128];
  const int lane = threadIdx.x & 63, wave = threadIdx.x >> 6;
  const int job1 = ((int)blockIdx.y >= ny0);
  const u16* Bt = job1 ? Bt1 : Bt0;
  u16* C = job1 ? C1 : C0;
  const int N = job1 ? N1 : N0;
  const int K = job1 ? K1 : K0;
  const int by = job1 ? ((int)blockIdx.y - ny0) : (int)blockIdx.y;
  const size_t arow = (size_t)blockIdx.x*32;
  const size_t bcol = (size_t)by*128 + wave*32;
  f32x4 acc00={0,0,0,0}, acc01={0,0,0,0}, acc10={0,0,0,0}, acc11={0,0,0,0};
  for (int k=0; k<K; k+=32){
    int ko = k + (lane>>4)*8;
    bf16x8 a0 = *(const bf16x8*)(A + (arow + (lane&15))*lda + ko);
    bf16x8 a1 = *(const bf16x8*)(A + (arow + 16 + (lane&15))*lda + ko);
    bf16x8 b0 = *(const bf16x8*)(Bt + (bcol + (lane&15))*K + ko);
    bf16x8 b1 = *(const bf16x8*)(Bt + (bcol + 16 + (lane&15))*K + ko);
    acc00 = __builtin_amdgcn_mfma_f32_16x16x32_bf16(a0, b0, acc00, 0,0,0);
    acc01 = __builtin_amdgcn_mfma_f32_16x16x32_bf16(a0, b1, acc01, 0,0,0);
    acc10 = __builtin_amdgcn_mfma_f32_16x16x32_bf16(a1, b0, acc10, 0,0,0);
    acc11 = __builtin_amdgcn_mfma_f32_16x16x32_bf16(a1, b1, acc11, 0,0,0);
  }
  const int cr = (lane>>4)*4, cc = wave*32 + (lane&15);
#pragma unroll
  for (int q=0;q<4;q++){
    cl[(cr+q)*128 + cc]      = acc00[q];
    cl[(cr+q)*128 + cc+16]   = acc01[q];
    cl[(16+cr+q)*128 + cc]    = acc10[q];
    cl[(16+cr+q)*128 + cc+16] = acc11[q];
  }
  __syncthreads();
  const int t = threadIdx.x;
#pragma unroll
  for (int i=0;i<16;i++){
    int idx = i*256 + t; int r = idx>>7, c = idx&127;
    int gcol = by*128 + c;
    C[(arow + r)*(size_t)N + cperm<1>(gcol)] = f2bf(cl[idx]);
  }
}

// ---------------- fused angle kernel v12: XOR-swizzled vgn ----------------
template<bool IS_BLK1>
__global__ __launch_bounds__(512, 4) void angle12_kernel(
    const u16* __restrict__ hat, const u16* __restrict__ preE, const u16* __restrict__ preK,
    const u16* __restrict__ wangT, const u16* __restrict__ woT,
    const float* __restrict__ angle,
    const float* __restrict__ rbf, const float* __restrict__ envW,
    const float* __restrict__ a_sw,
    const u16* __restrict__ aprojTb, const float* __restrict__ eproj,
    float* __restrict__ edge_out, float* __restrict__ angle_out)
{
  constexpr int HW = IS_BLK1 ? 640 : 512;
  constexpr int VGN_B  = 48*264*2;   // region size kept (msgL f32 alias needs 25344)
  constexpr int GATE_O = VGN_B;
  constexpr int SS_O   = GATE_O + (IS_BLK1 ? 48*132*2 : 0);
  constexpr int RS_O   = SS_O + 8*48*4;
  constexpr int SEG_O  = RS_O + 192;
  constexpr int RBF_O  = SEG_O + (IS_BLK1 ? 0 : 1024);
  constexpr int LDS_B  = RBF_O + (IS_BLK1 ? 0 : 1152);
  __shared__ __align__(16) char ldsRaw[LDS_B];
  u16*   vgn    = (u16*)ldsRaw;                 // [48][256] u16, XOR-swizzled cols
  u16*   gateLb = (u16*)(ldsRaw + GATE_O);
  float* ssL    = (float*)(ldsRaw + SS_O);
  float* rsL    = (float*)(ldsRaw + RS_O);
  float* segL   = (float*)(ldsRaw + SEG_O);
  float* rbfL   = (float*)(ldsRaw + RBF_O);
  float* msgL   = (float*)ldsRaw;               // [48][132] f32, aliases after sync2

  const int t = threadIdx.x, lane = t & 63, w = t >> 6;
  const int l15 = lane & 15, l4 = lane >> 4;
  const int b = blockIdx.x;
  const int xcd = b & 7, idx = b >> 3;
  const int loc = xcd*16 + idx/12;
  const int j0 = (idx - (idx/12)*12)*2;
  const int s0 = loc*24 + j0;
  const int hbase = s0*24;
  const int oc = 16*w + l15;

  if constexpr (!IS_BLK1){
    if (t < 288) rbfL[t] = rbf[(size_t)(loc*64)*12 + t];
  }

  u16x8 pk[3][2], pe[3][2];
  u16x4 pkg[3], peg[3];
#pragma unroll
  for (int nt=0; nt<3; nt++){
    const int r = nt*16 + l15;
    const int hi = (r >= 24);
    const int rr = r - 24*hi;
    const u16* pK = preK + (size_t)(loc*24 + rr)*HW;
    const u16* pE = preE + (size_t)(s0 + hi)*HW;
#pragma unroll
    for (int i=0;i<2;i++){
      const int a = (2*w + i)*4 + l4;
      pk[nt][i] = *(const u16x8*)(pK + a*8);
      pe[nt][i] = *(const u16x8*)(pE + a*8);
    }
    if constexpr (IS_BLK1){
      const int cg = 512 + w*16 + l4*4;
      pkg[nt] = *(const u16x4*)(pK + cg);
      peg[nt] = *(const u16x4*)(pE + cg);
    }
  }

  f32x4 accv[3][2], accg[3][2], accgate[3];
#pragma unroll
  for (int nt=0;nt<3;nt++){
    accv[nt][0]=(f32x4){0,0,0,0}; accv[nt][1]=(f32x4){0,0,0,0};
    accg[nt][0]=(f32x4){0,0,0,0}; accg[nt][1]=(f32x4){0,0,0,0};
    accgate[nt]=(f32x4){0,0,0,0};
  }
#pragma unroll
  for (int kk=0; kk<2; kk++){
    const int ko = kk*32 + l4*8;
    bf16x8 bb[3];
#pragma unroll
    for (int nt=0;nt<3;nt++)
      bb[nt] = *(const bf16x8*)(hat + (size_t)(hbase + nt*16 + l15)*64 + ko);
#pragma unroll
    for (int i=0;i<2;i++){
      const int chv = (2*w + i)*16 + l15;
      bf16x8 av = *(const bf16x8*)(wangT + (size_t)chv*64 + ko);
      bf16x8 ag = *(const bf16x8*)(wangT + (size_t)(256 + chv)*64 + ko);
#pragma unroll
      for (int nt=0;nt<3;nt++){
        accv[nt][i] = __builtin_amdgcn_mfma_f32_16x16x32_bf16(av, bb[nt], accv[nt][i], 0,0,0);
        accg[nt][i] = __builtin_amdgcn_mfma_f32_16x16x32_bf16(ag, bb[nt], accg[nt][i], 0,0,0);
      }
    }
    if constexpr (IS_BLK1){
      bf16x8 aga = *(const bf16x8*)(wangT + (size_t)(512 + w*16 + l15)*64 + ko);
#pragma unroll
      for (int nt=0;nt<3;nt++)
        accgate[nt] = __builtin_amdgcn_mfma_f32_16x16x32_bf16(aga, bb[nt], accgate[nt], 0,0,0);
    }
  }

  float ssr[3] = {0.f, 0.f, 0.f};
#pragma unroll
  for (int nt=0; nt<3; nt++){
    const int r = nt*16 + l15;
#pragma unroll
    for (int i=0;i<2;i++){
      const int cb = (2*w + i)*16 + l4*4;
      u16x4 xs;
#pragma unroll
      for (int q=0;q<4;q++){
        float v = accv[nt][i][q] + bf2f(pk[nt][i][q])   + bf2f(pe[nt][i][q]);
        float g = accg[nt][i][q] + bf2f(pk[nt][i][4+q]) + bf2f(pe[nt][i][4+q]);
        float x = v * silu(g);
        ssr[nt] += x*x;
        xs[q] = f2bf(x);
      }
      *(u16x4*)&vgn[r*256 + SWZ(r, cb)] = xs;
    }
    if constexpr (IS_BLK1){
      u16x4 gs;
#pragma unroll
      for (int q=0;q<4;q++)
        gs[q] = f2bf((accgate[nt][q] + bf2f(pkg[nt][q]) + bf2f(peg[nt][q])) * A_SCALE_C);
      *(u16x4*)&gateLb[r*132 + w*16 + l4*4] = gs;
    }
  }
#pragma unroll
  for (int nt=0;nt<3;nt++){
    float s = ssr[nt];
    s += __shfl_xor(s,16,64); s += __shfl_xor(s,32,64);
    if (l4 == 0) ssL[w*48 + nt*16 + l15] = s;
  }
  bf16x8 bwp[8];
#pragma unroll
  for (int kk=0; kk<8; kk++)
    bwp[kk] = *(const bf16x8*)(woT + (size_t)oc*256 + kk*32 + l4*8);
  __syncthreads();                    // sync1
  if (t < 48){
    float s_ = 0.f;
#pragma unroll
    for (int k=0;k<8;k++) s_ += ssL[k*48 + t];
    rsL[t] = rsqrtf(s_*(1.0f/256.0f) + 1e-6f);
  }

  f32x4 mac[3];
#pragma unroll
  for (int m=0;m<3;m++) mac[m] = (f32x4){0,0,0,0};
#pragma unroll
  for (int kk=0; kk<8; kk++){
#pragma unroll
    for (int m=0;m<3;m++){
      const int rr2 = m*16 + l15;
      bf16x8 aw = *(const bf16x8*)&vgn[rr2*256 + SWZ(rr2, kk*32 + l4*8)];
      mac[m] = __builtin_amdgcn_mfma_f32_16x16x32_bf16(aw, bwp[kk], mac[m], 0,0,0);
    }
  }
  __syncthreads();                    // sync2
  float rsv[3][4];
#pragma unroll
  for (int m=0;m<3;m++)
#pragma unroll
    for (int q=0;q<4;q++) rsv[m][q] = rsL[m*16 + l4*4 + q];
#pragma unroll
  for (int m=0;m<3;m++)
#pragma unroll
    for (int q=0;q<4;q++)
      msgL[(m*16 + l4*4 + q)*132 + 16*w + l15] = mac[m][q] * rsv[m][q];
  __syncthreads();                    // sync3

  if constexpr (IS_BLK1){
    if (t < 256){
      int s = t>>7, c = t&127;
      float ex[24]; float mx = -1e30f;
#pragma unroll
      for (int k=0;k<24;k++){ ex[k] = bf2f(gateLb[(s*24+k)*132 + c]); mx = fmaxf(mx, ex[k]); }
      float S = 0.f;
#pragma unroll
      for (int k=0;k<24;k++){ ex[k] = __expf(ex[k] - mx); S += ex[k]; }
      float inv = 1.f/(S + 1e-12f);
      float delta = 0.f;
#pragma unroll
      for (int k=0;k<24;k++) delta += msgL[(s*24+k)*132 + c] * ex[k];
      edge_out[(size_t)(loc*64 + j0 + s)*128 + c] += delta * inv;
    }
  } else {
    if (t < 256){
      int s = t>>7, c = t&127;
      float envR[12];
#pragma unroll
      for (int j=0;j<12;j++) envR[j] = envW[j*128 + c];
      float sg_ = 0.f;
#pragma unroll
      for (int k=0;k<24;k++){
        float envC = 0.f;
#pragma unroll
        for (int j=0;j<12;j++) envC = fmaf(rbfL[k*12 + j], envR[j], envC);
        sg_ += msgL[(s*24+k)*132 + c] * envC * a_sw[(size_t)(s0+s)*24 + k];
      }
      segL[s*128 + c] = sg_;
    }
    for (int p = w; p < 12; p += 8){
      const int mt = p >> 2, ntc = p & 3;
      f32x4 am = (f32x4){0,0,0,0};
#pragma unroll
      for (int kk=0; kk<4; kk++){
        const float* mrow = &msgL[(mt*16 + l15)*132 + kk*32 + l4*8];
        bf16x8 a;
#pragma unroll
        for (int e=0;e<8;e++) a[e] = (short)f2bf(mrow[e]);
        bf16x8 bb = *(const bf16x8*)(aprojTb + (size_t)(ntc*16 + l15)*128 + kk*32 + l4*8);
        am = __builtin_amdgcn_mfma_f32_16x16x32_bf16(a, bb, am, 0,0,0);
      }
#pragma unroll
      for (int q=0;q<4;q++){
        int row = mt*16 + l4*4 + q;
        size_t a_ = (size_t)hbase + row;
        int col = ntc*16 + l15;
        angle_out[a_*64 + col] = angle[a_*64 + col] + am[q] * a_sw[a_];
      }
    }
    __syncthreads();
    if (t < 256){
      int s = t>>7, c = t&127;
      float acc2 = 0.f;
      for (int dd=0; dd<128; dd++) acc2 = fmaf(segL[s*128 + dd], eproj[dd*128 + c], acc2);
      edge_out[(size_t)(loc*64 + j0 + s)*128 + c] += acc2 * A_SCALE_C;
    }
  }
}

// ---------------- scores v3: inline rmsnorm + MFMA gate + softmax ----------------
__global__ __launch_bounds__(256) void scores3_kernel(const float* __restrict__ edge_src,
                                                      const float* __restrict__ norm_e,
                                                      const u16* __restrict__ gateT,
                                                      float* __restrict__ scores){
  __shared__ float s[64*132];
  const int t = threadIdx.x, lane = t & 63, w = t >> 6;
  const int l15 = lane & 15, l4 = lane >> 4;
  const int n = blockIdx.x;
  const int row = n*64 + w*16 + l15;
  bf16x8 bfr[4];
  row_rms_frag(edge_src + (size_t)row*128, norm_e, l4, bfr);
  f32x4 acc[8];
#pragma unroll
  for (int j=0;j<8;j++) acc[j] = (f32x4){0,0,0,0};
#pragma unroll
  for (int kk=0; kk<4; kk++){
    const int ko = kk*32 + l4*8;
#pragma unroll
    for (int j=0;j<8;j++){
      bf16x8 b = *(const bf16x8*)(gateT + (size_t)(j*16 + l15)*128 + ko);
      acc[j] = __builtin_amdgcn_mfma_f32_16x16x32_bf16(bfr[kk], b, acc[j], 0,0,0);
    }
  }
#pragma unroll
  for (int j=0;j<8;j++)
#pragma unroll
    for (int q=0;q<4;q++)
      s[(w*16 + l4*4 + q)*132 + j*16 + l15] = acc[j][q] * E_SCALE_C;
  __syncthreads();
  if (t < 128){
    float m = -1e30f;
    for (int r=0;r<64;r++) m = fmaxf(m, s[r*132 + t]);
    float S = 0.f;
    for (int r=0;r<64;r++) S += __expf(s[r*132 + t] - m);
    float inv = 1.f/(S + 1e-12f);
    for (int r=0;r<64;r++)
      scores[(size_t)(n*64 + r)*128 + t] = __expf(s[r*132 + t] - m) * inv;
  }
}

// ---------------- combined blk2 edge kernel (inline rmsnorm) ----------------
__global__ __launch_bounds__(256) void edge_fused01_kernel(
    const float* __restrict__ edge_src,
    const float* __restrict__ norm_e,
    const float* __restrict__ NPa, const float* __restrict__ NPe,
    const int* __restrict__ next2e,
    const u16* __restrict__ aaWT, const u16* __restrict__ aeWT,
    const u16* __restrict__ woaaT, const u16* __restrict__ woaeT,
    const float* __restrict__ scores,
    float* __restrict__ edge_out, float* __restrict__ partial){
  __shared__ __align__(16) char lds[13184];
  u16*   vgn  = (u16*)lds;
  float* msgF = (float*)lds;
  float* ssP  = (float*)(lds + 12800);
  float* rsL  = (float*)(lds + 13056);
  const int t = threadIdx.x, lane = t & 63, w = t >> 6;
  const int l15 = lane & 15, l4 = lane >> 4;
  const int g = blockIdx.x, e0 = g*16, n = e0 >> 6;
  const int nx = next2e[e0 + l15];

  bf16x8 bfr[4];
  row_rms_frag(edge_src + (size_t)(e0 + l15)*128, norm_e, l4, bfr);

#pragma unroll
  for (int path=0; path<2; path++){
    const u16* wT  = path ? aeWT : aaWT;
    const u16* woT = path ? woaeT : woaaT;
    const float* NPt = path ? NPe : NPa;

    f32x4 av4[4], ag4[4];
#pragma unroll
    for (int i=0;i<4;i++){ av4[i]=(f32x4){0,0,0,0}; ag4[i]=(f32x4){0,0,0,0}; }
#pragma unroll
    for (int kk=0; kk<4; kk++){
      const int ko = kk*32 + l4*8;
#pragma unroll
      for (int i=0;i<4;i++){
        const int chr = w*64 + i*16 + l15;
        bf16x8 wv = *(const bf16x8*)(wT + (size_t)chr*128 + ko);
        bf16x8 wg = *(const bf16x8*)(wT + (size_t)(256 + chr)*128 + ko);
        av4[i] = __builtin_amdgcn_mfma_f32_16x16x32_bf16(wv, bfr[kk], av4[i], 0,0,0);
        ag4[i] = __builtin_amdgcn_mfma_f32_16x16x32_bf16(wg, bfr[kk], ag4[i], 0,0,0);
      }
    }

    float ssr = 0.f;
#pragma unroll
    for (int i=0;i<4;i++){
      const int cb = w*64 + i*16 + l4*4;
      float4 sv = *(const float4*)(NPt + n*1024 + cb);
      float4 sg = *(const float4*)(NPt + n*1024 + 256 + cb);
      float4 nv = *(const float4*)(NPt + (size_t)nx*1024 + 512 + cb);
      float4 ng = *(const float4*)(NPt + (size_t)nx*1024 + 768 + cb);
      u16x4 xs;
#pragma unroll
      for (int q=0;q<4;q++){
        float v  = av4[i][q] + ((const float*)&sv)[q] + ((const float*)&nv)[q];
        float gg = ag4[i][q] + ((const float*)&sg)[q] + ((const float*)&ng)[q];
        float x = v * silu(gg);
        ssr += x*x;
        xs[q] = f2bf(x);
      }
      *(u16x4*)&vgn[l15*264 + cb] = xs;
    }
    {
      float s = ssr;
      s += __shfl_xor(s,16,64); s += __shfl_xor(s,32,64);
      if (l4 == 0) ssP[l15*4 + w] = s;
    }
    __syncthreads();
    if (t < 16)
      rsL[t] = rsqrtf((ssP[t*4]+ssP[t*4+1]+ssP[t*4+2]+ssP[t*4+3])*(1.0f/256.0f) + 1e-6f);
    __syncthreads();
    f32x4 mac[2] = {(f32x4){0,0,0,0}, (f32x4){0,0,0,0}};
#pragma unroll
    for (int kk=0; kk<8; kk++){
      bf16x8 a = *(const bf16x8*)&vgn[l15*264 + kk*32 + l4*8];
#pragma unroll
      for (int nt=0; nt<2; nt++){
        bf16x8 bw = *(const bf16x8*)(woT + (size_t)(32*w + nt*16 + l15)*256 + kk*32 + l4*8);
        mac[nt] = __builtin_amdgcn_mfma_f32_16x16x32_bf16(a, bw, mac[nt], 0,0,0);
      }
    }
    float rsv[4];
#pragma unroll
    for (int q=0;q<4;q++) rsv[q] = rsL[l4*4 + q];
    __syncthreads();
#pragma unroll
    for (int nt=0; nt<2; nt++)
#pragma unroll
      for (int q=0;q<4;q++)
        msgF[(l4*4 + q)*132 + 32*w + nt*16 + l15] = mac[nt][q] * rsv[q];
    __syncthreads();

    if (path == 0){
      if (t < 128){
        float p = 0.f;
#pragma unroll
        for (int r=0;r<16;r++) p += msgF[r*132 + t] * scores[(size_t)(e0+r)*128 + t];
        partial[g*128 + t] = p;
      }
    } else {
      const int d = t & 127, rg = (t >> 7) * 8;
#pragma unroll
      for (int i=0;i<8;i++)
        edge_out[(size_t)(e0+rg+i)*128 + d] += msgF[(rg+i)*132 + d];
    }
    __syncthreads();
  }
}

// ---------------- blk4 edge kernel: MODE2 with fused rmsnorm ----------------
__global__ __launch_bounds__(256) void edge_fused2m2_kernel(
    const float* __restrict__ edge_src,
    const float* __restrict__ norm_e,
    const float* __restrict__ NPt,
    const int* __restrict__ next2e,
    const u16* __restrict__ wT,
    const u16* __restrict__ woT,
    const float* __restrict__ rbf, const float* __restrict__ envW,
    const float* __restrict__ sw, const u16* __restrict__ eprojT,
    float* __restrict__ edge_out, float* __restrict__ partial){
  __shared__ __align__(16) char lds[20096];
  u16*   vgn  = (u16*)lds;
  float* msgF = (float*)lds;
  u16*   msgB = (u16*)(lds + 8448);
  float* ssP  = (float*)(lds + 12800);
  float* rsL  = (float*)(lds + 13056);
  float* envWL= (float*)(lds + 13184);
  float* rbfL = (float*)(lds + 19328);
  const int t = threadIdx.x, lane = t & 63, w = t >> 6;
  const int l15 = lane & 15, l4 = lane >> 4;
  const int g = blockIdx.x, e0 = g*16, n = e0 >> 6;
  const int nx = next2e[e0 + l15];
  for (int i=t; i<12*128; i+=256) envWL[i] = envW[i];
  if (t < 192) rbfL[t] = rbf[(size_t)e0*12 + t];

  bf16x8 bfr[4];
  row_rms_frag(edge_src + (size_t)(e0 + l15)*128, norm_e, l4, bfr);

  float4 sv[4], sg[4], nv[4], ng[4];
#pragma unroll
  for (int i=0;i<4;i++){
    const int cb = w*64 + i*16 + l4*4;
    sv[i] = *(const float4*)(NPt + n*1024 + cb);
    sg[i] = *(const float4*)(NPt + n*1024 + 256 + cb);
    nv[i] = *(const float4*)(NPt + (size_t)nx*1024 + 512 + cb);
    ng[i] = *(const float4*)(NPt + (size_t)nx*1024 + 768 + cb);
  }

  f32x4 av4[4], ag4[4];
#pragma unroll
  for (int i=0;i<4;i++){ av4[i]=(f32x4){0,0,0,0}; ag4[i]=(f32x4){0,0,0,0}; }
#pragma unroll
  for (int kk=0; kk<4; kk++){
    const int ko = kk*32 + l4*8;
#pragma unroll
    for (int i=0;i<4;i++){
      const int chr = w*64 + i*16 + l15;
      bf16x8 wv = *(const bf16x8*)(wT + (size_t)chr*128 + ko);
      bf16x8 wg = *(const bf16x8*)(wT + (size_t)(256 + chr)*128 + ko);
      av4[i] = __builtin_amdgcn_mfma_f32_16x16x32_bf16(wv, bfr[kk], av4[i], 0,0,0);
      ag4[i] = __builtin_amdgcn_mfma_f32_16x16x32_bf16(wg, bfr[kk], ag4[i], 0,0,0);
    }
  }

  float ssr = 0.f;
#pragma unroll
  for (int i=0;i<4;i++){
    const int cb = w*64 + i*16 + l4*4;
    u16x4 xs;
#pragma unroll
    for (int q=0;q<4;q++){
      float v = av4[i][q] + ((const float*)&sv[i])[q] + ((const float*)&nv[i])[q];
      float gg = ag4[i][q] + ((const float*)&sg[i])[q] + ((const float*)&ng[i])[q];
      float x = v * silu(gg);
      ssr += x*x;
      xs[q] = f2bf(x);
    }
    *(u16x4*)&vgn[l15*264 + cb] = xs;
  }
  {
    float s = ssr;
    s += __shfl_xor(s,16,64); s += __shfl_xor(s,32,64);
    if (l4 == 0) ssP[l15*4 + w] = s;
  }
  __syncthreads();
  if (t < 16)
    rsL[t] = rsqrtf((ssP[t*4]+ssP[t*4+1]+ssP[t*4+2]+ssP[t*4+3])*(1.0f/256.0f) + 1e-6f);
  __syncthreads();
  f32x4 mac[2] = {(f32x4){0,0,0,0}, (f32x4){0,0,0,0}};
#pragma unroll
  for (int kk=0; kk<8; kk++){
    bf16x8 a = *(const bf16x8*)&vgn[l15*264 + kk*32 + l4*8];
#pragma unroll
    for (int nt=0; nt<2; nt++){
      bf16x8 bw = *(const bf16x8*)(woT + (size_t)(32*w + nt*16 + l15)*256 + kk*32 + l4*8);
      mac[nt] = __builtin_amdgcn_mfma_f32_16x16x32_bf16(a, bw, mac[nt], 0,0,0);
    }
  }
  float rsv[4];
#pragma unroll
  for (int q=0;q<4;q++) rsv[q] = rsL[l4*4 + q];
  __syncthreads();
#pragma unroll
  for (int nt=0; nt<2; nt++)
#pragma unroll
    for (int q=0;q<4;q++){
      float val = mac[nt][q] * rsv[q];
      int row = l4*4 + q, col = 32*w + nt*16 + l15;
      msgF[row*132 + col] = val;
      msgB[row*136 + col] = f2bf(val);
    }
  __syncthreads();

  f32x4 em[2] = {(f32x4){0,0,0,0}, (f32x4){0,0,0,0}};
#pragma unroll
  for (int kk=0; kk<4; kk++){
    bf16x8 a = *(const bf16x8*)&msgB[l15*136 + kk*32 + l4*8];
#pragma unroll
    for (int nt=0; nt<2; nt++){
      bf16x8 bw = *(const bf16x8*)(eprojT + (size_t)(32*w + nt*16 + l15)*128 + kk*32 + l4*8);
      em[nt] = __builtin_amdgcn_mfma_f32_16x16x32_bf16(a, bw, em[nt], 0,0,0);
    }
  }
#pragma unroll
  for (int nt=0; nt<2; nt++)
#pragma unroll
    for (int q=0;q<4;q++)
      edge_out[(size_t)(e0 + l4*4 + q)*128 + 32*w + nt*16 + l15] += em[nt][q];
  if (t < 128){
    float p = 0.f;
#pragma unroll
    for (int r=0;r<16;r++){
      float envC = 0.f;
#pragma unroll
      for (int j=0;j<12;j++) envC = fmaf(rbfL[r*12 + j], envWL[j*128 + t], envC);
      p += msgF[r*132 + t] * envC * sw[e0 + r];
    }
    partial[g*128 + t] = p;
  }
}

__global__ void node_add4_kernel(const float* __restrict__ partial, float* __restrict__ node_out){
  int n = blockIdx.x, t = threadIdx.x;
  node_out[n*128 + t] += partial[(4*n)*128+t] + partial[(4*n+1)*128+t]
                       + partial[(4*n+2)*128+t] + partial[(4*n+3)*128+t];
}

__global__ void node_final4_kernel(const float* __restrict__ partial,
                                   const float* __restrict__ nproj,
                                   float* __restrict__ node_out){
  __shared__ float seg[128];
  int n = blockIdx.x, t = threadIdx.x;
  seg[t] = partial[(4*n)*128+t] + partial[(4*n+1)*128+t]
         + partial[(4*n+2)*128+t] + partial[(4*n+3)*128+t];
  __syncthreads();
  float acc = 0.f;
  for (int dd=0; dd<128; dd++) acc = fmaf(seg[dd], nproj[dd*128 + t], acc);
  node_out[n*128 + t] += acc * E_SCALE_C;
}

// ---------------- launch ----------------
extern "C" void kernel_launch(void* const* d_in, const int* in_sizes, int n_in,
                              void* d_out, int out_size, void* d_ws, size_t ws_size,
                              hipStream_t stream){
  const float* node_in  = (const float*)d_in[0];
  const float* edge_in  = (const float*)d_in[1];
  const float* angle_in = (const float*)d_in[2];
  const float* sw       = (const float*)d_in[3];
  const float* a_sw     = (const float*)d_in[4];
  const float* rbf      = (const float*)d_in[5];
  const int*   edge_index = (const int*)d_in[6];
  const float* la_norm_e = (const float*)d_in[8];
  const float* la_norm_a = (const float*)d_in[9];
  const float* la_win    = (const float*)d_in[10];
  const float* la_nw     = (const float*)d_in[11];
  const float* la_wout   = (const float*)d_in[12];
  const float* la_gate   = (const float*)d_in[13];
  const float* aa_norm_n = (const float*)d_in[14];
  const float* aa_norm_e = (const float*)d_in[15];
  const float* aa_win    = (const float*)d_in[16];
  const float* aa_nw     = (const float*)d_in[17];
  const float* aa_wout   = (const float*)d_in[18];
  const float* aa_src_gate = (const float*)d_in[19];
  const float* ae_win    = (const float*)d_in[20];
  const float* ae_nw     = (const float*)d_in[21];
  const float* ae_wout   = (const float*)d_in[22];
  const float* lr_norm_e = (const float*)d_in[23];
  const float* lr_norm_a = (const float*)d_in[24];
  const float* lr_win    = (const float*)d_in[25];
  const float* lr_nw     = (const float*)d_in[26];
  const float* lr_wout   = (const float*)d_in[27];
  const float* lr_env    = (const float*)d_in[28];
  const float* lr_eproj  = (const float*)d_in[29];
  const float* lr_aproj  = (const float*)d_in[30];
  const float* ar_norm_n = (const float*)d_in[31];
  const float* ar_norm_e = (const float*)d_in[32];
  const float* ar_win    = (const float*)d_in[33];
  const float* ar_nw     = (const float*)d_in[34];
  const float* ar_wout   = (const float*)d_in[35];
  const float* ar_env    = (const float*)d_in[36];
  const float* ar_nproj  = (const float*)d_in[37];
  const float* ar_eproj  = (const float*)d_in[38];

  float* out_node  = (float*)d_out;
  float* out_edge  = out_node + 128*128;
  float* out_angle = out_edge + (size_t)8192*128;

  float* p = (float*)d_ws;
  float* hat_f   = p; p += 2359296;
  float* enca_f  = p; p += 393216;
  float* preE_f  = p; p += 983040;
  float* preK_f  = p; p += 983040;
  float* wang1_f = p; p += 20480;
  float* wang3_f = p; p += 16384;
  float* wij1_f  = p; p += 40960;
  float* wij3_f  = p; p += 32768;
  float* wik1_f  = p; p += 81920;
  float* wik3_f  = p; p += 65536;
  float* wo1T_f  = p; p += 16384;
  float* wo3T_f  = p; p += 16384;
  float* whe2_f  = p; p += 73728;
  float* whe4_f  = p; p += 32768;
  float* woaaT_f = p; p += 16384;
  float* woaeT_f = p; p += 16384;
  float* woarT_f = p; p += 16384;
  float* eprjT_f = p; p += 8192;
  float* aprjT_f = p; p += 4096;
  float* npa     = p; p += 131072;
  float* npe     = p; p += 131072;
  float* npr     = p; p += 131072;
  float* scores2 = p; p += 1048576;
  float* partial = p; p += 65536;

  u16* hat  = (u16*)hat_f;
  u16* enca = (u16*)enca_f;
  u16* preE = (u16*)preE_f;
  u16* preK = (u16*)preK_f;
  u16* wang1= (u16*)wang1_f;
  u16* wang3= (u16*)wang3_f;
  u16* wij1 = (u16*)wij1_f;
  u16* wij3 = (u16*)wij3_f;
  u16* wik1 = (u16*)wik1_f;
  u16* wik3 = (u16*)wik3_f;
  u16* wo1T = (u16*)wo1T_f;
  u16* wo3T = (u16*)wo3T_f;
  u16* whe2 = (u16*)whe2_f;
  u16* whe4 = (u16*)whe4_f;
  u16* woaaT= (u16*)woaaT_f;
  u16* woaeT= (u16*)woaeT_f;
  u16* woarT= (u16*)woarT_f;
  u16* eprjT= (u16*)eprjT_f;
  u16* aprjT= (u16*)aprjT_f;
  u16* aaWT = whe2;
  u16* aeWT = whe2 + 512*128;
  u16* gateT= whe2 + 1024*128;
  u16* arWT = whe4;

  dim3 b512(512), b256(256), b128(128);
  const int* next2e = edge_index + 8192;

  WtJobs jobs;
  int nj = 0;
  auto add = [&](const float* src, const float* scale, u16* dst,
                 int ld, int row0, int c0, int k0, int dlog, int kslog, int C){
    jobs.j[nj++] = WtJob{src, scale, dst, ld, row0, c0, k0, dlog, kslog, C};
  };
  add(la_win, la_norm_a, wang1, 512, 0,   0,   0,   6, 6, 512);
  add(la_gate,la_norm_a, wang1, 128, 0,   512, 0,   6, 6, 128);
  add(la_win, nullptr,   wij1,  512, 192, 0,   0,   7, 7, 512);
  add(la_gate,nullptr,   wij1,  128, 192, 512, 0,   7, 7, 128);
  add(la_win, nullptr,   wik1,  512, 320, 0,   0,   8, 7, 512);
  add(la_gate,nullptr,   wik1,  128, 320, 512, 0,   8, 7, 128);
  add(la_win, nullptr,   wik1,  512, 64,  0,   128, 8, 7, 512);
  add(la_gate,nullptr,   wik1,  128, 64,  512, 128, 8, 7, 128);
  add(la_wout,la_nw,     wo1T,  128, 0,   0,   0,   8, 8, 128);
  add(lr_win, lr_norm_a, wang3, 512, 0,   0,   0,   6, 6, 512);
  add(lr_win, nullptr,   wij3,  512, 192, 0,   0,   7, 7, 512);
  add(lr_win, nullptr,   wik3,  512, 320, 0,   0,   8, 7, 512);
  add(lr_win, nullptr,   wik3,  512, 64,  0,   128, 8, 7, 512);
  add(lr_wout,lr_nw,     wo3T,  128, 0,   0,   0,   8, 8, 128);
  add(aa_win, nullptr,   whe2,  512, 0,   0,   0,   7, 7, 512);
  add(ae_win, nullptr,   whe2,  512, 0,   512, 0,   7, 7, 512);
  add(aa_src_gate,nullptr,whe2, 128, 0,   1024,0,   7, 7, 128);
  add(ar_win, nullptr,   whe4,  512, 0,   0,   0,   7, 7, 512);
  add(aa_wout, aa_nw,    woaaT, 128, 0,   0,   0,   8, 8, 128);
  add(ae_wout, ae_nw,    woaeT, 128, 0,   0,   0,   8, 8, 128);
  add(ar_wout, ar_nw,    woarT, 128, 0,   0,   0,   8, 8, 128);
  add(ar_eproj,nullptr,  eprjT, 128, 0,   0,   0,   7, 7, 128);
  add(lr_aproj,nullptr,  aprjT, 64,  0,   0,   0,   7, 7, 64);
  build_all_wt<<<dim3(64, 23), b256, 0, stream>>>(jobs);

  hat_init_kernel<<<18432 + 1040 + 2048, b256, 0, stream>>>(angle_in, hat,
      (const float4*)edge_in, (float4*)out_edge, (const float4*)node_in, (float4*)out_node,
      node_in, aa_norm_n, aa_win, npa, ae_win, npe);

  // ---- block 1 ----
  rmsnorm128c_aug_kernel<<<768, b256, 0, stream>>>(edge_in, la_norm_e, node_in, enca);
  gemm2_bf16_kernel<<<dim3(96,10), b256, 0, stream>>>(enca, 256,
      wij1, preE, 640, 128, 5, wik1, preK, 640, 256);
  angle12_kernel<true><<<1536, b512, 0, stream>>>(hat, preE, preK, wang1, wo1T,
      angle_in, nullptr, nullptr, nullptr, nullptr, nullptr, out_edge, nullptr);

  // ---- block 2 ----
  scores3_kernel<<<128, b256, 0, stream>>>(out_edge, aa_norm_e, gateT, scores2);
  edge_fused01_kernel<<<512, b256, 0, stream>>>(out_edge, aa_norm_e, npa, npe, next2e,
      aaWT, aeWT, woaaT, woaeT, scores2, out_edge, partial);
  node_add4_kernel<<<128, b128, 0, stream>>>(partial, out_node);

  // ---- block 3 ----
  rmsnorm128c_aug_kernel<<<768, b256, 0, stream>>>(out_edge, lr_norm_e, out_node, enca);
  gemm2_bf16_kernel<<<dim3(96,8), b256, 0, stream>>>(enca, 256,
      wij3, preE, 512, 128, 4, wik3, preK, 512, 256);
  angle12_kernel<false><<<1536, b512, 0, stream>>>(hat, preE, preK, wang3, wo3T,
      angle_in, rbf, lr_env, a_sw, aprjT, lr_eproj, out_edge, out_angle);

  // ---- block 4 ----
  node_gemm2_kernel<<<dim3(128,8), b128, 0, stream>>>(out_node, ar_norm_n,
      ar_win, npr, nullptr, nullptr);
  edge_fused2m2_kernel<<<512, b256, 0, stream>>>(out_edge, ar_norm_e, npr, next2e,
      arWT, woarT, rbf, ar_env, sw, eprjT, out_edge, partial);
  node_final4_kernel<<<128, b128, 0, stream>>>(partial, ar_nproj, out_node);

  (void)in_sizes; (void)n_in; (void)out_size; (void)ws_size;
}

// Round 22
// 255.129 us; speedup vs baseline: 1.0197x; 1.0095x over previous
//
#include <hip/hip_runtime.h>
#include <hip/hip_bf16.h>

#define A_SCALE_C 0.6454972243679028f   // (24/10)^-0.5
#define E_SCALE_C 0.3952847075210474f   // (64/10)^-0.5

typedef unsigned short u16;
typedef unsigned int u32;
typedef __attribute__((ext_vector_type(8))) short bf16x8;
typedef __attribute__((ext_vector_type(4))) float f32x4;
typedef __attribute__((ext_vector_type(4))) unsigned short u16x4;
typedef __attribute__((ext_vector_type(8))) unsigned short u16x8;

static __device__ __forceinline__ float waveSum(float v){
#pragma unroll
  for (int off = 32; off; off >>= 1) v += __shfl_xor(v, off, 64);
  return v;
}
static __device__ __forceinline__ float silu(float g){
  return g / (1.0f + __expf(-g));
}
static __device__ __forceinline__ float bf2f(u16 h){
  union { u32 u; float f; } x; x.u = ((u32)h) << 16; return x.f;
}
static __device__ __forceinline__ u16 f2bf(float f){
  __hip_bfloat16 h = __float2bfloat16(f);
  u16 r; __builtin_memcpy(&r, &h, 2); return r;
}
template<int PERM>
static __device__ __forceinline__ int cperm(int c){
  if constexpr (PERM) return (c < 512) ? (((c>>2)&63)*8 + ((c>>8)<<2) + (c&3)) : c;
  else return c;
}

// inline row rmsnorm -> bf16 A-fragments (row covered by l4-group of 4 lanes)
static __device__ __forceinline__ void row_rms_frag(
    const float* __restrict__ rowp, const float* __restrict__ normw,
    int l4, bf16x8* bfr){
  float xr[4][8];
  float ssx = 0.f;
#pragma unroll
  for (int kk=0; kk<4; kk++){
    const float* rp = rowp + kk*32 + l4*8;
    float4 a = *(const float4*)rp;
    float4 bq = *(const float4*)(rp + 4);
    xr[kk][0]=a.x; xr[kk][1]=a.y; xr[kk][2]=a.z; xr[kk][3]=a.w;
    xr[kk][4]=bq.x; xr[kk][5]=bq.y; xr[kk][6]=bq.z; xr[kk][7]=bq.w;
#pragma unroll
    for (int e=0;e<8;e++) ssx = fmaf(xr[kk][e], xr[kk][e], ssx);
  }
  ssx += __shfl_xor(ssx,16,64);
  ssx += __shfl_xor(ssx,32,64);
  const float rsx = rsqrtf(ssx*(1.0f/128.0f) + 1e-6f);
#pragma unroll
  for (int kk=0; kk<4; kk++){
    const float* wp = normw + kk*32 + l4*8;
#pragma unroll
    for (int e=0;e<8;e++) bfr[kk][e] = (short)f2bf(xr[kk][e] * rsx * wp[e]);
  }
}

// ---------------- batched weight-transpose builder ----------------
struct WtJob { const float* src; const float* scale; u16* dst;
               int src_ld, row0, c0, k0, dlog, kslog, C; };
struct WtJobs { WtJob j[23]; };

__global__ __launch_bounds__(256) void build_all_wt(WtJobs P){
  const WtJob J = P.j[blockIdx.y];
  const int ks = 1 << J.kslog;
  const int total = J.C << J.kslog;
  for (int idx = blockIdx.x*256 + threadIdx.x; idx < total; idx += gridDim.x*256){
    int c = idx >> J.kslog, k = idx & (ks-1);
    float s = J.scale ? J.scale[k] : 1.0f;
    J.dst[((size_t)(J.c0 + c) << J.dlog) + J.k0 + k] =
        f2bf(J.src[(size_t)(J.row0 + k)*J.src_ld + c] * s);
  }
}

// ---------------- merged prologue: hat rmsnorm (float4 vectorized) + output init + blk2 node tables ----------------
// bid < 4608: hat (16 rows/block, 16 lanes/row, float4); next 1040: copy-init; next 2048: npa/npe
__global__ void hat_init_kernel(const float* __restrict__ ang, u16* __restrict__ hat,
                                const float4* __restrict__ e, float4* __restrict__ oe,
                                const float4* __restrict__ n, float4* __restrict__ on,
                                const float* __restrict__ node, const float* __restrict__ nw,
                                const float* __restrict__ Ba, float* __restrict__ Ca,
                                const float* __restrict__ Bb, float* __restrict__ Cb){
  int bid = blockIdx.x;
  const int t = threadIdx.x;
  if (bid < 4608){
    const int row = bid*16 + (t >> 4);   // 73728 rows total
    const int l = t & 15;
    float4 v = *(const float4*)(ang + (size_t)row*64 + l*4);
    float ss = v.x*v.x + v.y*v.y + v.z*v.z + v.w*v.w;
#pragma unroll
    for (int off=8; off; off>>=1) ss += __shfl_xor(ss, off, 64);
    const float rs = rsqrtf(ss*(1.0f/64.0f) + 1e-6f);
    u16x4 pk;
    pk[0]=f2bf(v.x*rs); pk[1]=f2bf(v.y*rs); pk[2]=f2bf(v.z*rs); pk[3]=f2bf(v.w*rs);
    *(u16x4*)(hat + (size_t)row*64 + l*4) = pk;
  } else if (bid < 4608 + 1040){
    int idx = (bid - 4608)*256 + t;
    if (idx < 262144) oe[idx] = e[idx];
    else if (idx < 262144 + 4096) on[idx - 262144] = n[idx - 262144];
  } else {
    __shared__ float ar[128];
    __shared__ float sred[2];
    const int c2 = bid - (4608 + 1040);      // 0..2047
    const int row = c2 >> 4;                 // 0..127
    const int c = c2 & 15;                   // chunk
    float x = 0.f;
    if (t < 128) x = node[row*128 + t];
    float s = waveSum(x*x);
    if (t < 128 && (t & 63) == 0) sred[t>>6] = s;
    __syncthreads();
    float rs = rsqrtf((sred[0]+sred[1])*(1.0f/128.0f) + 1e-6f);
    if (t < 128) ar[t] = x * rs * nw[t];
    __syncthreads();
    if (t < 128){
      const float* B = (c < 8) ? Ba : Bb;
      float* C = (c < 8) ? Ca : Cb;
      const int cc = c & 7, half = cc >> 2, sub = cc & 3;
      const int brow = 128 + half*128;
      const int col = sub*128 + t;
      float acc = 0.f;
      for (int k=0;k<128;k++) acc = fmaf(ar[k], B[(size_t)(brow+k)*512 + col], acc);
      C[(size_t)row*1024 + half*512 + col] = acc;
    }
  }
}

// compact rmsnorm + node append: enc_aug[3072][256] = [e_n bf16 | node bf16]
__global__ void rmsnorm128c_aug_kernel(const float* __restrict__ x, const float* __restrict__ w,
                                       const float* __restrict__ node, u16* __restrict__ out){
  int row = blockIdx.x*4 + (threadIdx.x >> 6);   // 0..3071
  int lane = threadIdx.x & 63;
  int loc = row/24;
  int src = loc*64 + (row - loc*24);
  float2 v = *(const float2*)(x + (size_t)src*128 + lane*2);
  float ss = waveSum(v.x*v.x + v.y*v.y);
  float rs = rsqrtf(ss*(1.0f/128.0f) + 1e-6f);
  float2 wv = *(const float2*)(w + lane*2);
  u32 pk = (u32)f2bf(v.x*rs*wv.x) | ((u32)f2bf(v.y*rs*wv.y) << 16);
  *(u32*)(out + (size_t)row*256 + lane*2) = pk;
  float2 nv = *(const float2*)(node + loc*128 + lane*2);
  u32 pn = (u32)f2bf(nv.x) | ((u32)f2bf(nv.y) << 16);
  *(u32*)(out + (size_t)row*256 + 128 + lane*2) = pn;
}

// fused node rmsnorm + table GEMM (blk4 npr)
__global__ __launch_bounds__(128) void node_gemm2_kernel(
    const float* __restrict__ node, const float* __restrict__ nw,
    const float* __restrict__ Ba, float* __restrict__ Ca,
    const float* __restrict__ Bb, float* __restrict__ Cb){
  __shared__ float ar[128];
  __shared__ float sred[2];
  const int row = blockIdx.x, t = threadIdx.x;
  float x = node[row*128 + t];
  float s = waveSum(x*x);
  if ((t & 63) == 0) sred[t>>6] = s;
  __syncthreads();
  float rs = rsqrtf((sred[0]+sred[1])*(1.0f/128.0f) + 1e-6f);
  ar[t] = x * rs * nw[t];
  __syncthreads();
  const int c = blockIdx.y;
  const float* B = (c < 8) ? Ba : Bb;
  float* C = (c < 8) ? Ca : Cb;
  const int cc = c & 7, half = cc >> 2, sub = cc & 3;
  const int brow = 128 + half*128;
  const int col = sub*128 + t;
  float acc = 0.f;
  for (int k=0;k<128;k++) acc = fmaf(ar[k], B[(size_t)(brow+k)*512 + col], acc);
  C[(size_t)row*1024 + half*512 + col] = acc;
}

// ---------------- dual MFMA GEMM ----------------
__global__ __launch_bounds__(256) void gemm2_bf16_kernel(
    const u16* __restrict__ A, int lda,
    const u16* __restrict__ Bt0, u16* __restrict__ C0, int N0, int K0, int ny0,
    const u16* __restrict__ Bt1, u16* __restrict__ C1, int N1, int K1){
  __shared__ float cl[32*128];
  const int lane = threadIdx.x & 63, wave = threadIdx.x >> 6;
  const int job1 = ((int)blockIdx.y >= ny0);
  const u16* Bt = job1 ? Bt1 : Bt0;
  u16* C = job1 ? C1 : C0;
  const int N = job1 ? N1 : N0;
  const int K = job1 ? K1 : K0;
  const int by = job1 ? ((int)blockIdx.y - ny0) : (int)blockIdx.y;
  const size_t arow = (size_t)blockIdx.x*32;
  const size_t bcol = (size_t)by*128 + wave*32;
  f32x4 acc00={0,0,0,0}, acc01={0,0,0,0}, acc10={0,0,0,0}, acc11={0,0,0,0};
  for (int k=0; k<K; k+=32){
    int ko = k + (lane>>4)*8;
    bf16x8 a0 = *(const bf16x8*)(A + (arow + (lane&15))*lda + ko);
    bf16x8 a1 = *(const bf16x8*)(A + (arow + 16 + (lane&15))*lda + ko);
    bf16x8 b0 = *(const bf16x8*)(Bt + (bcol + (lane&15))*K + ko);
    bf16x8 b1 = *(const bf16x8*)(Bt + (bcol + 16 + (lane&15))*K + ko);
    acc00 = __builtin_amdgcn_mfma_f32_16x16x32_bf16(a0, b0, acc00, 0,0,0);
    acc01 = __builtin_amdgcn_mfma_f32_16x16x32_bf16(a0, b1, acc01, 0,0,0);
    acc10 = __builtin_amdgcn_mfma_f32_16x16x32_bf16(a1, b0, acc10, 0,0,0);
    acc11 = __builtin_amdgcn_mfma_f32_16x16x32_bf16(a1, b1, acc11, 0,0,0);
  }
  const int cr = (lane>>4)*4, cc = wave*32 + (lane&15);
#pragma unroll
  for (int q=0;q<4;q++){
    cl[(cr+q)*128 + cc]      = acc00[q];
    cl[(cr+q)*128 + cc+16]   = acc01[q];
    cl[(16+cr+q)*128 + cc]    = acc10[q];
    cl[(16+cr+q)*128 + cc+16] = acc11[q];
  }
  __syncthreads();
  const int t = threadIdx.x;
#pragma unroll
  for (int i=0;i<16;i++){
    int idx = i*256 + t; int r = idx>>7, c = idx&127;
    int gcol = by*128 + c;
    C[(arow + r)*(size_t)N + cperm<1>(gcol)] = f2bf(cl[idx]);
  }
}

// ---------------- fused angle kernel v11 (proven R20 version, linear vgn) ----------------
template<bool IS_BLK1>
__global__ __launch_bounds__(512, 4) void angle11_kernel(
    const u16* __restrict__ hat, const u16* __restrict__ preE, const u16* __restrict__ preK,
    const u16* __restrict__ wangT, const u16* __restrict__ woT,
    const float* __restrict__ angle,
    const float* __restrict__ rbf, const float* __restrict__ envW,
    const float* __restrict__ a_sw,
    const u16* __restrict__ aprojTb, const float* __restrict__ eproj,
    float* __restrict__ edge_out, float* __restrict__ angle_out)
{
  constexpr int HW = IS_BLK1 ? 640 : 512;
  constexpr int VGN_B  = 48*264*2;
  constexpr int GATE_O = VGN_B;
  constexpr int SS_O   = GATE_O + (IS_BLK1 ? 48*132*2 : 0);
  constexpr int RS_O   = SS_O + 8*48*4;
  constexpr int SEG_O  = RS_O + 192;
  constexpr int RBF_O  = SEG_O + (IS_BLK1 ? 0 : 1024);
  constexpr int LDS_B  = RBF_O + (IS_BLK1 ? 0 : 1152);
  __shared__ __align__(16) char ldsRaw[LDS_B];
  u16*   vgn    = (u16*)ldsRaw;
  u16*   gateLb = (u16*)(ldsRaw + GATE_O);
  float* ssL    = (float*)(ldsRaw + SS_O);
  float* rsL    = (float*)(ldsRaw + RS_O);
  float* segL   = (float*)(ldsRaw + SEG_O);
  float* rbfL   = (float*)(ldsRaw + RBF_O);
  float* msgL   = (float*)ldsRaw;

  const int t = threadIdx.x, lane = t & 63, w = t >> 6;
  const int l15 = lane & 15, l4 = lane >> 4;
  const int b = blockIdx.x;
  const int xcd = b & 7, idx = b >> 3;
  const int loc = xcd*16 + idx/12;
  const int j0 = (idx - (idx/12)*12)*2;
  const int s0 = loc*24 + j0;
  const int hbase = s0*24;
  const int oc = 16*w + l15;

  if constexpr (!IS_BLK1){
    if (t < 288) rbfL[t] = rbf[(size_t)(loc*64)*12 + t];
  }

  u16x8 pk[3][2], pe[3][2];
  u16x4 pkg[3], peg[3];
#pragma unroll
  for (int nt=0; nt<3; nt++){
    const int r = nt*16 + l15;
    const int hi = (r >= 24);
    const int rr = r - 24*hi;
    const u16* pK = preK + (size_t)(loc*24 + rr)*HW;
    const u16* pE = preE + (size_t)(s0 + hi)*HW;
#pragma unroll
    for (int i=0;i<2;i++){
      const int a = (2*w + i)*4 + l4;
      pk[nt][i] = *(const u16x8*)(pK + a*8);
      pe[nt][i] = *(const u16x8*)(pE + a*8);
    }
    if constexpr (IS_BLK1){
      const int cg = 512 + w*16 + l4*4;
      pkg[nt] = *(const u16x4*)(pK + cg);
      peg[nt] = *(const u16x4*)(pE + cg);
    }
  }

  f32x4 accv[3][2], accg[3][2], accgate[3];
#pragma unroll
  for (int nt=0;nt<3;nt++){
    accv[nt][0]=(f32x4){0,0,0,0}; accv[nt][1]=(f32x4){0,0,0,0};
    accg[nt][0]=(f32x4){0,0,0,0}; accg[nt][1]=(f32x4){0,0,0,0};
    accgate[nt]=(f32x4){0,0,0,0};
  }
#pragma unroll
  for (int kk=0; kk<2; kk++){
    const int ko = kk*32 + l4*8;
    bf16x8 bb[3];
#pragma unroll
    for (int nt=0;nt<3;nt++)
      bb[nt] = *(const bf16x8*)(hat + (size_t)(hbase + nt*16 + l15)*64 + ko);
#pragma unroll
    for (int i=0;i<2;i++){
      const int chv = (2*w + i)*16 + l15;
      bf16x8 av = *(const bf16x8*)(wangT + (size_t)chv*64 + ko);
      bf16x8 ag = *(const bf16x8*)(wangT + (size_t)(256 + chv)*64 + ko);
#pragma unroll
      for (int nt=0;nt<3;nt++){
        accv[nt][i] = __builtin_amdgcn_mfma_f32_16x16x32_bf16(av, bb[nt], accv[nt][i], 0,0,0);
        accg[nt][i] = __builtin_amdgcn_mfma_f32_16x16x32_bf16(ag, bb[nt], accg[nt][i], 0,0,0);
      }
    }
    if constexpr (IS_BLK1){
      bf16x8 aga = *(const bf16x8*)(wangT + (size_t)(512 + w*16 + l15)*64 + ko);
#pragma unroll
      for (int nt=0;nt<3;nt++)
        accgate[nt] = __builtin_amdgcn_mfma_f32_16x16x32_bf16(aga, bb[nt], accgate[nt], 0,0,0);
    }
  }

  float ssr[3] = {0.f, 0.f, 0.f};
#pragma unroll
  for (int nt=0; nt<3; nt++){
    const int r = nt*16 + l15;
#pragma unroll
    for (int i=0;i<2;i++){
      const int cb = (2*w + i)*16 + l4*4;
      u16x4 xs;
#pragma unroll
      for (int q=0;q<4;q++){
        float v = accv[nt][i][q] + bf2f(pk[nt][i][q])   + bf2f(pe[nt][i][q]);
        float g = accg[nt][i][q] + bf2f(pk[nt][i][4+q]) + bf2f(pe[nt][i][4+q]);
        float x = v * silu(g);
        ssr[nt] += x*x;
        xs[q] = f2bf(x);
      }
      *(u16x4*)&vgn[r*264 + cb] = xs;
    }
    if constexpr (IS_BLK1){
      u16x4 gs;
#pragma unroll
      for (int q=0;q<4;q++)
        gs[q] = f2bf((accgate[nt][q] + bf2f(pkg[nt][q]) + bf2f(peg[nt][q])) * A_SCALE_C);
      *(u16x4*)&gateLb[r*132 + w*16 + l4*4] = gs;
    }
  }
#pragma unroll
  for (int nt=0;nt<3;nt++){
    float s = ssr[nt];
    s += __shfl_xor(s,16,64); s += __shfl_xor(s,32,64);
    if (l4 == 0) ssL[w*48 + nt*16 + l15] = s;
  }
  bf16x8 bwp[8];
#pragma unroll
  for (int kk=0; kk<8; kk++)
    bwp[kk] = *(const bf16x8*)(woT + (size_t)oc*256 + kk*32 + l4*8);
  __syncthreads();                    // sync1
  if (t < 48){
    float s_ = 0.f;
#pragma unroll
    for (int k=0;k<8;k++) s_ += ssL[k*48 + t];
    rsL[t] = rsqrtf(s_*(1.0f/256.0f) + 1e-6f);
  }

  f32x4 mac[3];
#pragma unroll
  for (int m=0;m<3;m++) mac[m] = (f32x4){0,0,0,0};
#pragma unroll
  for (int kk=0; kk<8; kk++){
#pragma unroll
    for (int m=0;m<3;m++){
      bf16x8 aw = *(const bf16x8*)&vgn[(m*16 + l15)*264 + kk*32 + l4*8];
      mac[m] = __builtin_amdgcn_mfma_f32_16x16x32_bf16(aw, bwp[kk], mac[m], 0,0,0);
    }
  }
  __syncthreads();                    // sync2
  float rsv[3][4];
#pragma unroll
  for (int m=0;m<3;m++)
#pragma unroll
    for (int q=0;q<4;q++) rsv[m][q] = rsL[m*16 + l4*4 + q];
#pragma unroll
  for (int m=0;m<3;m++)
#pragma unroll
    for (int q=0;q<4;q++)
      msgL[(m*16 + l4*4 + q)*132 + 16*w + l15] = mac[m][q] * rsv[m][q];
  __syncthreads();                    // sync3

  if constexpr (IS_BLK1){
    if (t < 256){
      int s = t>>7, c = t&127;
      float ex[24]; float mx = -1e30f;
#pragma unroll
      for (int k=0;k<24;k++){ ex[k] = bf2f(gateLb[(s*24+k)*132 + c]); mx = fmaxf(mx, ex[k]); }
      float S = 0.f;
#pragma unroll
      for (int k=0;k<24;k++){ ex[k] = __expf(ex[k] - mx); S += ex[k]; }
      float inv = 1.f/(S + 1e-12f);
      float delta = 0.f;
#pragma unroll
      for (int k=0;k<24;k++) delta += msgL[(s*24+k)*132 + c] * ex[k];
      edge_out[(size_t)(loc*64 + j0 + s)*128 + c] += delta * inv;
    }
  } else {
    if (t < 256){
      int s = t>>7, c = t&127;
      float envR[12];
#pragma unroll
      for (int j=0;j<12;j++) envR[j] = envW[j*128 + c];
      float sg_ = 0.f;
#pragma unroll
      for (int k=0;k<24;k++){
        float envC = 0.f;
#pragma unroll
        for (int j=0;j<12;j++) envC = fmaf(rbfL[k*12 + j], envR[j], envC);
        sg_ += msgL[(s*24+k)*132 + c] * envC * a_sw[(size_t)(s0+s)*24 + k];
      }
      segL[s*128 + c] = sg_;
    }
    for (int p = w; p < 12; p += 8){
      const int mt = p >> 2, ntc = p & 3;
      f32x4 am = (f32x4){0,0,0,0};
#pragma unroll
      for (int kk=0; kk<4; kk++){
        const float* mrow = &msgL[(mt*16 + l15)*132 + kk*32 + l4*8];
        bf16x8 a;
#pragma unroll
        for (int e=0;e<8;e++) a[e] = (short)f2bf(mrow[e]);
        bf16x8 bb = *(const bf16x8*)(aprojTb + (size_t)(ntc*16 + l15)*128 + kk*32 + l4*8);
        am = __builtin_amdgcn_mfma_f32_16x16x32_bf16(a, bb, am, 0,0,0);
      }
#pragma unroll
      for (int q=0;q<4;q++){
        int row = mt*16 + l4*4 + q;
        size_t a_ = (size_t)hbase + row;
        int col = ntc*16 + l15;
        angle_out[a_*64 + col] = angle[a_*64 + col] + am[q] * a_sw[a_];
      }
    }
    __syncthreads();
    if (t < 256){
      int s = t>>7, c = t&127;
      float acc2 = 0.f;
      for (int dd=0; dd<128; dd++) acc2 = fmaf(segL[s*128 + dd], eproj[dd*128 + c], acc2);
      edge_out[(size_t)(loc*64 + j0 + s)*128 + c] += acc2 * A_SCALE_C;
    }
  }
}

// ---------------- scores v3: inline rmsnorm + MFMA gate + softmax ----------------
__global__ __launch_bounds__(256) void scores3_kernel(const float* __restrict__ edge_src,
                                                      const float* __restrict__ norm_e,
                                                      const u16* __restrict__ gateT,
                                                      float* __restrict__ scores){
  __shared__ float s[64*132];
  const int t = threadIdx.x, lane = t & 63, w = t >> 6;
  const int l15 = lane & 15, l4 = lane >> 4;
  const int n = blockIdx.x;
  const int row = n*64 + w*16 + l15;
  bf16x8 bfr[4];
  row_rms_frag(edge_src + (size_t)row*128, norm_e, l4, bfr);
  f32x4 acc[8];
#pragma unroll
  for (int j=0;j<8;j++) acc[j] = (f32x4){0,0,0,0};
#pragma unroll
  for (int kk=0; kk<4; kk++){
    const int ko = kk*32 + l4*8;
#pragma unroll
    for (int j=0;j<8;j++){
      bf16x8 b = *(const bf16x8*)(gateT + (size_t)(j*16 + l15)*128 + ko);
      acc[j] = __builtin_amdgcn_mfma_f32_16x16x32_bf16(bfr[kk], b, acc[j], 0,0,0);
    }
  }
#pragma unroll
  for (int j=0;j<8;j++)
#pragma unroll
    for (int q=0;q<4;q++)
      s[(w*16 + l4*4 + q)*132 + j*16 + l15] = acc[j][q] * E_SCALE_C;
  __syncthreads();
  if (t < 128){
    float m = -1e30f;
    for (int r=0;r<64;r++) m = fmaxf(m, s[r*132 + t]);
    float S = 0.f;
    for (int r=0;r<64;r++) S += __expf(s[r*132 + t] - m);
    float inv = 1.f/(S + 1e-12f);
    for (int r=0;r<64;r++)
      scores[(size_t)(n*64 + r)*128 + t] = __expf(s[r*132 + t] - m) * inv;
  }
}

// ---------------- combined blk2 edge kernel (inline rmsnorm) ----------------
__global__ __launch_bounds__(256) void edge_fused01_kernel(
    const float* __restrict__ edge_src,
    const float* __restrict__ norm_e,
    const float* __restrict__ NPa, const float* __restrict__ NPe,
    const int* __restrict__ next2e,
    const u16* __restrict__ aaWT, const u16* __restrict__ aeWT,
    const u16* __restrict__ woaaT, const u16* __restrict__ woaeT,
    const float* __restrict__ scores,
    float* __restrict__ edge_out, float* __restrict__ partial){
  __shared__ __align__(16) char lds[13184];
  u16*   vgn  = (u16*)lds;
  float* msgF = (float*)lds;
  float* ssP  = (float*)(lds + 12800);
  float* rsL  = (float*)(lds + 13056);
  const int t = threadIdx.x, lane = t & 63, w = t >> 6;
  const int l15 = lane & 15, l4 = lane >> 4;
  const int g = blockIdx.x, e0 = g*16, n = e0 >> 6;
  const int nx = next2e[e0 + l15];

  bf16x8 bfr[4];
  row_rms_frag(edge_src + (size_t)(e0 + l15)*128, norm_e, l4, bfr);

#pragma unroll
  for (int path=0; path<2; path++){
    const u16* wT  = path ? aeWT : aaWT;
    const u16* woT = path ? woaeT : woaaT;
    const float* NPt = path ? NPe : NPa;

    f32x4 av4[4], ag4[4];
#pragma unroll
    for (int i=0;i<4;i++){ av4[i]=(f32x4){0,0,0,0}; ag4[i]=(f32x4){0,0,0,0}; }
#pragma unroll
    for (int kk=0; kk<4; kk++){
      const int ko = kk*32 + l4*8;
#pragma unroll
      for (int i=0;i<4;i++){
        const int chr = w*64 + i*16 + l15;
        bf16x8 wv = *(const bf16x8*)(wT + (size_t)chr*128 + ko);
        bf16x8 wg = *(const bf16x8*)(wT + (size_t)(256 + chr)*128 + ko);
        av4[i] = __builtin_amdgcn_mfma_f32_16x16x32_bf16(wv, bfr[kk], av4[i], 0,0,0);
        ag4[i] = __builtin_amdgcn_mfma_f32_16x16x32_bf16(wg, bfr[kk], ag4[i], 0,0,0);
      }
    }

    float ssr = 0.f;
#pragma unroll
    for (int i=0;i<4;i++){
      const int cb = w*64 + i*16 + l4*4;
      float4 sv = *(const float4*)(NPt + n*1024 + cb);
      float4 sg = *(const float4*)(NPt + n*1024 + 256 + cb);
      float4 nv = *(const float4*)(NPt + (size_t)nx*1024 + 512 + cb);
      float4 ng = *(const float4*)(NPt + (size_t)nx*1024 + 768 + cb);
      u16x4 xs;
#pragma unroll
      for (int q=0;q<4;q++){
        float v  = av4[i][q] + ((const float*)&sv)[q] + ((const float*)&nv)[q];
        float gg = ag4[i][q] + ((const float*)&sg)[q] + ((const float*)&ng)[q];
        float x = v * silu(gg);
        ssr += x*x;
        xs[q] = f2bf(x);
      }
      *(u16x4*)&vgn[l15*264 + cb] = xs;
    }
    {
      float s = ssr;
      s += __shfl_xor(s,16,64); s += __shfl_xor(s,32,64);
      if (l4 == 0) ssP[l15*4 + w] = s;
    }
    __syncthreads();
    if (t < 16)
      rsL[t] = rsqrtf((ssP[t*4]+ssP[t*4+1]+ssP[t*4+2]+ssP[t*4+3])*(1.0f/256.0f) + 1e-6f);
    __syncthreads();
    f32x4 mac[2] = {(f32x4){0,0,0,0}, (f32x4){0,0,0,0}};
#pragma unroll
    for (int kk=0; kk<8; kk++){
      bf16x8 a = *(const bf16x8*)&vgn[l15*264 + kk*32 + l4*8];
#pragma unroll
      for (int nt=0; nt<2; nt++){
        bf16x8 bw = *(const bf16x8*)(woT + (size_t)(32*w + nt*16 + l15)*256 + kk*32 + l4*8);
        mac[nt] = __builtin_amdgcn_mfma_f32_16x16x32_bf16(a, bw, mac[nt], 0,0,0);
      }
    }
    float rsv[4];
#pragma unroll
    for (int q=0;q<4;q++) rsv[q] = rsL[l4*4 + q];
    __syncthreads();
#pragma unroll
    for (int nt=0; nt<2; nt++)
#pragma unroll
      for (int q=0;q<4;q++)
        msgF[(l4*4 + q)*132 + 32*w + nt*16 + l15] = mac[nt][q] * rsv[q];
    __syncthreads();

    if (path == 0){
      if (t < 128){
        float p = 0.f;
#pragma unroll
        for (int r=0;r<16;r++) p += msgF[r*132 + t] * scores[(size_t)(e0+r)*128 + t];
        partial[g*128 + t] = p;
      }
    } else {
      const int d = t & 127, rg = (t >> 7) * 8;
#pragma unroll
      for (int i=0;i<8;i++)
        edge_out[(size_t)(e0+rg+i)*128 + d] += msgF[(rg+i)*132 + d];
    }
    __syncthreads();
  }
}

// ---------------- blk4 edge kernel: MODE2 with fused rmsnorm ----------------
__global__ __launch_bounds__(256) void edge_fused2m2_kernel(
    const float* __restrict__ edge_src,
    const float* __restrict__ norm_e,
    const float* __restrict__ NPt,
    const int* __restrict__ next2e,
    const u16* __restrict__ wT,
    const u16* __restrict__ woT,
    const float* __restrict__ rbf, const float* __restrict__ envW,
    const float* __restrict__ sw, const u16* __restrict__ eprojT,
    float* __restrict__ edge_out, float* __restrict__ partial){
  __shared__ __align__(16) char lds[20096];
  u16*   vgn  = (u16*)lds;
  float* msgF = (float*)lds;
  u16*   msgB = (u16*)(lds + 8448);
  float* ssP  = (float*)(lds + 12800);
  float* rsL  = (float*)(lds + 13056);
  float* envWL= (float*)(lds + 13184);
  float* rbfL = (float*)(lds + 19328);
  const int t = threadIdx.x, lane = t & 63, w = t >> 6;
  const int l15 = lane & 15, l4 = lane >> 4;
  const int g = blockIdx.x, e0 = g*16, n = e0 >> 6;
  const int nx = next2e[e0 + l15];
  for (int i=t; i<12*128; i+=256) envWL[i] = envW[i];
  if (t < 192) rbfL[t] = rbf[(size_t)e0*12 + t];

  bf16x8 bfr[4];
  row_rms_frag(edge_src + (size_t)(e0 + l15)*128, norm_e, l4, bfr);

  float4 sv[4], sg[4], nv[4], ng[4];
#pragma unroll
  for (int i=0;i<4;i++){
    const int cb = w*64 + i*16 + l4*4;
    sv[i] = *(const float4*)(NPt + n*1024 + cb);
    sg[i] = *(const float4*)(NPt + n*1024 + 256 + cb);
    nv[i] = *(const float4*)(NPt + (size_t)nx*1024 + 512 + cb);
    ng[i] = *(const float4*)(NPt + (size_t)nx*1024 + 768 + cb);
  }

  f32x4 av4[4], ag4[4];
#pragma unroll
  for (int i=0;i<4;i++){ av4[i]=(f32x4){0,0,0,0}; ag4[i]=(f32x4){0,0,0,0}; }
#pragma unroll
  for (int kk=0; kk<4; kk++){
    const int ko = kk*32 + l4*8;
#pragma unroll
    for (int i=0;i<4;i++){
      const int chr = w*64 + i*16 + l15;
      bf16x8 wv = *(const bf16x8*)(wT + (size_t)chr*128 + ko);
      bf16x8 wg = *(const bf16x8*)(wT + (size_t)(256 + chr)*128 + ko);
      av4[i] = __builtin_amdgcn_mfma_f32_16x16x32_bf16(wv, bfr[kk], av4[i], 0,0,0);
      ag4[i] = __builtin_amdgcn_mfma_f32_16x16x32_bf16(wg, bfr[kk], ag4[i], 0,0,0);
    }
  }

  float ssr = 0.f;
#pragma unroll
  for (int i=0;i<4;i++){
    const int cb = w*64 + i*16 + l4*4;
    u16x4 xs;
#pragma unroll
    for (int q=0;q<4;q++){
      float v = av4[i][q] + ((const float*)&sv[i])[q] + ((const float*)&nv[i])[q];
      float gg = ag4[i][q] + ((const float*)&sg[i])[q] + ((const float*)&ng[i])[q];
      float x = v * silu(gg);
      ssr += x*x;
      xs[q] = f2bf(x);
    }
    *(u16x4*)&vgn[l15*264 + cb] = xs;
  }
  {
    float s = ssr;
    s += __shfl_xor(s,16,64); s += __shfl_xor(s,32,64);
    if (l4 == 0) ssP[l15*4 + w] = s;
  }
  __syncthreads();
  if (t < 16)
    rsL[t] = rsqrtf((ssP[t*4]+ssP[t*4+1]+ssP[t*4+2]+ssP[t*4+3])*(1.0f/256.0f) + 1e-6f);
  __syncthreads();
  f32x4 mac[2] = {(f32x4){0,0,0,0}, (f32x4){0,0,0,0}};
#pragma unroll
  for (int kk=0; kk<8; kk++){
    bf16x8 a = *(const bf16x8*)&vgn[l15*264 + kk*32 + l4*8];
#pragma unroll
    for (int nt=0; nt<2; nt++){
      bf16x8 bw = *(const bf16x8*)(woT + (size_t)(32*w + nt*16 + l15)*256 + kk*32 + l4*8);
      mac[nt] = __builtin_amdgcn_mfma_f32_16x16x32_bf16(a, bw, mac[nt], 0,0,0);
    }
  }
  float rsv[4];
#pragma unroll
  for (int q=0;q<4;q++) rsv[q] = rsL[l4*4 + q];
  __syncthreads();
#pragma unroll
  for (int nt=0; nt<2; nt++)
#pragma unroll
    for (int q=0;q<4;q++){
      float val = mac[nt][q] * rsv[q];
      int row = l4*4 + q, col = 32*w + nt*16 + l15;
      msgF[row*132 + col] = val;
      msgB[row*136 + col] = f2bf(val);
    }
  __syncthreads();

  f32x4 em[2] = {(f32x4){0,0,0,0}, (f32x4){0,0,0,0}};
#pragma unroll
  for (int kk=0; kk<4; kk++){
    bf16x8 a = *(const bf16x8*)&msgB[l15*136 + kk*32 + l4*8];
#pragma unroll
    for (int nt=0; nt<2; nt++){
      bf16x8 bw = *(const bf16x8*)(eprojT + (size_t)(32*w + nt*16 + l15)*128 + kk*32 + l4*8);
      em[nt] = __builtin_amdgcn_mfma_f32_16x16x32_bf16(a, bw, em[nt], 0,0,0);
    }
  }
#pragma unroll
  for (int nt=0; nt<2; nt++)
#pragma unroll
    for (int q=0;q<4;q++)
      edge_out[(size_t)(e0 + l4*4 + q)*128 + 32*w + nt*16 + l15] += em[nt][q];
  if (t < 128){
    float p = 0.f;
#pragma unroll
    for (int r=0;r<16;r++){
      float envC = 0.f;
#pragma unroll
      for (int j=0;j<12;j++) envC = fmaf(rbfL[r*12 + j], envWL[j*128 + t], envC);
      p += msgF[r*132 + t] * envC * sw[e0 + r];
    }
    partial[g*128 + t] = p;
  }
}

__global__ void node_add4_kernel(const float* __restrict__ partial, float* __restrict__ node_out){
  int n = blockIdx.x, t = threadIdx.x;
  node_out[n*128 + t] += partial[(4*n)*128+t] + partial[(4*n+1)*128+t]
                       + partial[(4*n+2)*128+t] + partial[(4*n+3)*128+t];
}

__global__ void node_final4_kernel(const float* __restrict__ partial,
                                   const float* __restrict__ nproj,
                                   float* __restrict__ node_out){
  __shared__ float seg[128];
  int n = blockIdx.x, t = threadIdx.x;
  seg[t] = partial[(4*n)*128+t] + partial[(4*n+1)*128+t]
         + partial[(4*n+2)*128+t] + partial[(4*n+3)*128+t];
  __syncthreads();
  float acc = 0.f;
  for (int dd=0; dd<128; dd++) acc = fmaf(seg[dd], nproj[dd*128 + t], acc);
  node_out[n*128 + t] += acc * E_SCALE_C;
}

// ---------------- launch ----------------
extern "C" void kernel_launch(void* const* d_in, const int* in_sizes, int n_in,
                              void* d_out, int out_size, void* d_ws, size_t ws_size,
                              hipStream_t stream){
  const float* node_in  = (const float*)d_in[0];
  const float* edge_in  = (const float*)d_in[1];
  const float* angle_in = (const float*)d_in[2];
  const float* sw       = (const float*)d_in[3];
  const float* a_sw     = (const float*)d_in[4];
  const float* rbf      = (const float*)d_in[5];
  const int*   edge_index = (const int*)d_in[6];
  const float* la_norm_e = (const float*)d_in[8];
  const float* la_norm_a = (const float*)d_in[9];
  const float* la_win    = (const float*)d_in[10];
  const float* la_nw     = (const float*)d_in[11];
  const float* la_wout   = (const float*)d_in[12];
  const float* la_gate   = (const float*)d_in[13];
  const float* aa_norm_n = (const float*)d_in[14];
  const float* aa_norm_e = (const float*)d_in[15];
  const float* aa_win    = (const float*)d_in[16];
  const float* aa_nw     = (const float*)d_in[17];
  const float* aa_wout   = (const float*)d_in[18];
  const float* aa_src_gate = (const float*)d_in[19];
  const float* ae_win    = (const float*)d_in[20];
  const float* ae_nw     = (const float*)d_in[21];
  const float* ae_wout   = (const float*)d_in[22];
  const float* lr_norm_e = (const float*)d_in[23];
  const float* lr_norm_a = (const float*)d_in[24];
  const float* lr_win    = (const float*)d_in[25];
  const float* lr_nw     = (const float*)d_in[26];
  const float* lr_wout   = (const float*)d_in[27];
  const float* lr_env    = (const float*)d_in[28];
  const float* lr_eproj  = (const float*)d_in[29];
  const float* lr_aproj  = (const float*)d_in[30];
  const float* ar_norm_n = (const float*)d_in[31];
  const float* ar_norm_e = (const float*)d_in[32];
  const float* ar_win    = (const float*)d_in[33];
  const float* ar_nw     = (const float*)d_in[34];
  const float* ar_wout   = (const float*)d_in[35];
  const float* ar_env    = (const float*)d_in[36];
  const float* ar_nproj  = (const float*)d_in[37];
  const float* ar_eproj  = (const float*)d_in[38];

  float* out_node  = (float*)d_out;
  float* out_edge  = out_node + 128*128;
  float* out_angle = out_edge + (size_t)8192*128;

  float* p = (float*)d_ws;
  float* hat_f   = p; p += 2359296;
  float* enca_f  = p; p += 393216;
  float* preE_f  = p; p += 983040;
  float* preK_f  = p; p += 983040;
  float* wang1_f = p; p += 20480;
  float* wang3_f = p; p += 16384;
  float* wij1_f  = p; p += 40960;
  float* wij3_f  = p; p += 32768;
  float* wik1_f  = p; p += 81920;
  float* wik3_f  = p; p += 65536;
  float* wo1T_f  = p; p += 16384;
  float* wo3T_f  = p; p += 16384;
  float* whe2_f  = p; p += 73728;
  float* whe4_f  = p; p += 32768;
  float* woaaT_f = p; p += 16384;
  float* woaeT_f = p; p += 16384;
  float* woarT_f = p; p += 16384;
  float* eprjT_f = p; p += 8192;
  float* aprjT_f = p; p += 4096;
  float* npa     = p; p += 131072;
  float* npe     = p; p += 131072;
  float* npr     = p; p += 131072;
  float* scores2 = p; p += 1048576;
  float* partial = p; p += 65536;

  u16* hat  = (u16*)hat_f;
  u16* enca = (u16*)enca_f;
  u16* preE = (u16*)preE_f;
  u16* preK = (u16*)preK_f;
  u16* wang1= (u16*)wang1_f;
  u16* wang3= (u16*)wang3_f;
  u16* wij1 = (u16*)wij1_f;
  u16* wij3 = (u16*)wij3_f;
  u16* wik1 = (u16*)wik1_f;
  u16* wik3 = (u16*)wik3_f;
  u16* wo1T = (u16*)wo1T_f;
  u16* wo3T = (u16*)wo3T_f;
  u16* whe2 = (u16*)whe2_f;
  u16* whe4 = (u16*)whe4_f;
  u16* woaaT= (u16*)woaaT_f;
  u16* woaeT= (u16*)woaeT_f;
  u16* woarT= (u16*)woarT_f;
  u16* eprjT= (u16*)eprjT_f;
  u16* aprjT= (u16*)aprjT_f;
  u16* aaWT = whe2;
  u16* aeWT = whe2 + 512*128;
  u16* gateT= whe2 + 1024*128;
  u16* arWT = whe4;

  dim3 b512(512), b256(256), b128(128);
  const int* next2e = edge_index + 8192;

  WtJobs jobs;
  int nj = 0;
  auto add = [&](const float* src, const float* scale, u16* dst,
                 int ld, int row0, int c0, int k0, int dlog, int kslog, int C){
    jobs.j[nj++] = WtJob{src, scale, dst, ld, row0, c0, k0, dlog, kslog, C};
  };
  add(la_win, la_norm_a, wang1, 512, 0,   0,   0,   6, 6, 512);
  add(la_gate,la_norm_a, wang1, 128, 0,   512, 0,   6, 6, 128);
  add(la_win, nullptr,   wij1,  512, 192, 0,   0,   7, 7, 512);
  add(la_gate,nullptr,   wij1,  128, 192, 512, 0,   7, 7, 128);
  add(la_win, nullptr,   wik1,  512, 320, 0,   0,   8, 7, 512);
  add(la_gate,nullptr,   wik1,  128, 320, 512, 0,   8, 7, 128);
  add(la_win, nullptr,   wik1,  512, 64,  0,   128, 8, 7, 512);
  add(la_gate,nullptr,   wik1,  128, 64,  512, 128, 8, 7, 128);
  add(la_wout,la_nw,     wo1T,  128, 0,   0,   0,   8, 8, 128);
  add(lr_win, lr_norm_a, wang3, 512, 0,   0,   0,   6, 6, 512);
  add(lr_win, nullptr,   wij3,  512, 192, 0,   0,   7, 7, 512);
  add(lr_win, nullptr,   wik3,  512, 320, 0,   0,   8, 7, 512);
  add(lr_win, nullptr,   wik3,  512, 64,  0,   128, 8, 7, 512);
  add(lr_wout,lr_nw,     wo3T,  128, 0,   0,   0,   8, 8, 128);
  add(aa_win, nullptr,   whe2,  512, 0,   0,   0,   7, 7, 512);
  add(ae_win, nullptr,   whe2,  512, 0,   512, 0,   7, 7, 512);
  add(aa_src_gate,nullptr,whe2, 128, 0,   1024,0,   7, 7, 128);
  add(ar_win, nullptr,   whe4,  512, 0,   0,   0,   7, 7, 512);
  add(aa_wout, aa_nw,    woaaT, 128, 0,   0,   0,   8, 8, 128);
  add(ae_wout, ae_nw,    woaeT, 128, 0,   0,   0,   8, 8, 128);
  add(ar_wout, ar_nw,    woarT, 128, 0,   0,   0,   8, 8, 128);
  add(ar_eproj,nullptr,  eprjT, 128, 0,   0,   0,   7, 7, 128);
  add(lr_aproj,nullptr,  aprjT, 64,  0,   0,   0,   7, 7, 64);
  build_all_wt<<<dim3(64, 23), b256, 0, stream>>>(jobs);

  // prologue: vectorized hat + init + blk2 node tables (input-only deps)
  hat_init_kernel<<<4608 + 1040 + 2048, b256, 0, stream>>>(angle_in, hat,
      (const float4*)edge_in, (float4*)out_edge, (const float4*)node_in, (float4*)out_node,
      node_in, aa_norm_n, aa_win, npa, ae_win, npe);

  // ---- block 1 ----
  rmsnorm128c_aug_kernel<<<768, b256, 0, stream>>>(edge_in, la_norm_e, node_in, enca);
  gemm2_bf16_kernel<<<dim3(96,10), b256, 0, stream>>>(enca, 256,
      wij1, preE, 640, 128, 5, wik1, preK, 640, 256);
  angle11_kernel<true><<<1536, b512, 0, stream>>>(hat, preE, preK, wang1, wo1T,
      angle_in, nullptr, nullptr, nullptr, nullptr, nullptr, out_edge, nullptr);

  // ---- block 2 ----
  scores3_kernel<<<128, b256, 0, stream>>>(out_edge, aa_norm_e, gateT, scores2);
  edge_fused01_kernel<<<512, b256, 0, stream>>>(out_edge, aa_norm_e, npa, npe, next2e,
      aaWT, aeWT, woaaT, woaeT, scores2, out_edge, partial);
  node_add4_kernel<<<128, b128, 0, stream>>>(partial, out_node);

  // ---- block 3 ----
  rmsnorm128c_aug_kernel<<<768, b256, 0, stream>>>(out_edge, lr_norm_e, out_node, enca);
  gemm2_bf16_kernel<<<dim3(96,8), b256, 0, stream>>>(enca, 256,
      wij3, preE, 512, 128, 4, wik3, preK, 512, 256);
  angle11_kernel<false><<<1536, b512, 0, stream>>>(hat, preE, preK, wang3, wo3T,
      angle_in, rbf, lr_env, a_sw, aprjT, lr_eproj, out_edge, out_angle);

  // ---- block 4 ----
  node_gemm2_kernel<<<dim3(128,8), b128, 0, stream>>>(out_node, ar_norm_n,
      ar_win, npr, nullptr, nullptr);
  edge_fused2m2_kernel<<<512, b256, 0, stream>>>(out_edge, ar_norm_e, npr, next2e,
      arWT, woarT, rbf, ar_env, sw, eprjT, out_edge, partial);
  node_final4_kernel<<<128, b128, 0, stream>>>(partial, ar_nproj, out_node);

  (void)in_sizes; (void)n_in; (void)out_size; (void)ws_size;
}

// Round 23
// 252.764 us; speedup vs baseline: 1.0292x; 1.0094x over previous
//
#include <hip/hip_runtime.h>
#include <hip/hip_bf16.h>

#define A_SCALE_C 0.6454972243679028f   // (24/10)^-0.5
#define E_SCALE_C 0.3952847075210474f   // (64/10)^-0.5

typedef unsigned short u16;
typedef unsigned int u32;
typedef __attribute__((ext_vector_type(8))) short bf16x8;
typedef __attribute__((ext_vector_type(4))) float f32x4;
typedef __attribute__((ext_vector_type(4))) unsigned short u16x4;
typedef __attribute__((ext_vector_type(8))) unsigned short u16x8;

static __device__ __forceinline__ float waveSum(float v){
#pragma unroll
  for (int off = 32; off; off >>= 1) v += __shfl_xor(v, off, 64);
  return v;
}
static __device__ __forceinline__ float silu(float g){
  return g / (1.0f + __expf(-g));
}
static __device__ __forceinline__ float bf2f(u16 h){
  union { u32 u; float f; } x; x.u = ((u32)h) << 16; return x.f;
}
static __device__ __forceinline__ u16 f2bf(float f){
  __hip_bfloat16 h = __float2bfloat16(f);
  u16 r; __builtin_memcpy(&r, &h, 2); return r;
}
template<int PERM>
static __device__ __forceinline__ int cperm(int c){
  if constexpr (PERM) return (c < 512) ? (((c>>2)&63)*8 + ((c>>8)<<2) + (c&3)) : c;
  else return c;
}

// inline row rmsnorm -> bf16 A-fragments (row covered by l4-group of 4 lanes)
static __device__ __forceinline__ void row_rms_frag(
    const float* __restrict__ rowp, const float* __restrict__ normw,
    int l4, bf16x8* bfr){
  float xr[4][8];
  float ssx = 0.f;
#pragma unroll
  for (int kk=0; kk<4; kk++){
    const float* rp = rowp + kk*32 + l4*8;
    float4 a = *(const float4*)rp;
    float4 bq = *(const float4*)(rp + 4);
    xr[kk][0]=a.x; xr[kk][1]=a.y; xr[kk][2]=a.z; xr[kk][3]=a.w;
    xr[kk][4]=bq.x; xr[kk][5]=bq.y; xr[kk][6]=bq.z; xr[kk][7]=bq.w;
#pragma unroll
    for (int e=0;e<8;e++) ssx = fmaf(xr[kk][e], xr[kk][e], ssx);
  }
  ssx += __shfl_xor(ssx,16,64);
  ssx += __shfl_xor(ssx,32,64);
  const float rsx = rsqrtf(ssx*(1.0f/128.0f) + 1e-6f);
#pragma unroll
  for (int kk=0; kk<4; kk++){
    const float* wp = normw + kk*32 + l4*8;
#pragma unroll
    for (int e=0;e<8;e++) bfr[kk][e] = (short)f2bf(xr[kk][e] * rsx * wp[e]);
  }
}

// ---------------- batched weight-transpose builder ----------------
struct WtJob { const float* src; const float* scale; u16* dst;
               int src_ld, row0, c0, k0, dlog, kslog, C; };
struct WtJobs { WtJob j[23]; };

__global__ __launch_bounds__(256) void build_all_wt(WtJobs P){
  const WtJob J = P.j[blockIdx.y];
  const int ks = 1 << J.kslog;
  const int total = J.C << J.kslog;
  for (int idx = blockIdx.x*256 + threadIdx.x; idx < total; idx += gridDim.x*256){
    int c = idx >> J.kslog, k = idx & (ks-1);
    float s = J.scale ? J.scale[k] : 1.0f;
    J.dst[((size_t)(J.c0 + c) << J.dlog) + J.k0 + k] =
        f2bf(J.src[(size_t)(J.row0 + k)*J.src_ld + c] * s);
  }
}

// ---------------- merged prologue: hat rmsnorm (float4) + edge copy + blk2 node tables ----------------
// bid < 4608: hat (16 rows/block, float4); next 1024: edge copy; next 2048: npa/npe
__global__ void hat_init_kernel(const float* __restrict__ ang, u16* __restrict__ hat,
                                const float4* __restrict__ e, float4* __restrict__ oe,
                                const float* __restrict__ node, const float* __restrict__ nw,
                                const float* __restrict__ Ba, float* __restrict__ Ca,
                                const float* __restrict__ Bb, float* __restrict__ Cb){
  int bid = blockIdx.x;
  const int t = threadIdx.x;
  if (bid < 4608){
    const int row = bid*16 + (t >> 4);   // 73728 rows total
    const int l = t & 15;
    float4 v = *(const float4*)(ang + (size_t)row*64 + l*4);
    float ss = v.x*v.x + v.y*v.y + v.z*v.z + v.w*v.w;
#pragma unroll
    for (int off=8; off; off>>=1) ss += __shfl_xor(ss, off, 64);
    const float rs = rsqrtf(ss*(1.0f/64.0f) + 1e-6f);
    u16x4 pk;
    pk[0]=f2bf(v.x*rs); pk[1]=f2bf(v.y*rs); pk[2]=f2bf(v.z*rs); pk[3]=f2bf(v.w*rs);
    *(u16x4*)(hat + (size_t)row*64 + l*4) = pk;
  } else if (bid < 4608 + 1024){
    int idx = (bid - 4608)*256 + t;      // 262144 float4 = out_edge init
    oe[idx] = e[idx];
  } else {
    __shared__ float ar[128];
    __shared__ float sred[2];
    const int c2 = bid - (4608 + 1024);      // 0..2047
    const int row = c2 >> 4;                 // 0..127
    const int c = c2 & 15;                   // chunk
    float x = 0.f;
    if (t < 128) x = node[row*128 + t];
    float s = waveSum(x*x);
    if (t < 128 && (t & 63) == 0) sred[t>>6] = s;
    __syncthreads();
    float rs = rsqrtf((sred[0]+sred[1])*(1.0f/128.0f) + 1e-6f);
    if (t < 128) ar[t] = x * rs * nw[t];
    __syncthreads();
    if (t < 128){
      const float* B = (c < 8) ? Ba : Bb;
      float* C = (c < 8) ? Ca : Cb;
      const int cc = c & 7, half = cc >> 2, sub = cc & 3;
      const int brow = 128 + half*128;
      const int col = sub*128 + t;
      float acc = 0.f;
      for (int k=0;k<128;k++) acc = fmaf(ar[k], B[(size_t)(brow+k)*512 + col], acc);
      C[(size_t)row*1024 + half*512 + col] = acc;
    }
  }
}

// compact rmsnorm + node append: enc_aug[3072][256] = [e_n bf16 | node bf16]
__global__ void rmsnorm128c_aug_kernel(const float* __restrict__ x, const float* __restrict__ w,
                                       const float* __restrict__ node, u16* __restrict__ out){
  int row = blockIdx.x*4 + (threadIdx.x >> 6);   // 0..3071
  int lane = threadIdx.x & 63;
  int loc = row/24;
  int src = loc*64 + (row - loc*24);
  float2 v = *(const float2*)(x + (size_t)src*128 + lane*2);
  float ss = waveSum(v.x*v.x + v.y*v.y);
  float rs = rsqrtf(ss*(1.0f/128.0f) + 1e-6f);
  float2 wv = *(const float2*)(w + lane*2);
  u32 pk = (u32)f2bf(v.x*rs*wv.x) | ((u32)f2bf(v.y*rs*wv.y) << 16);
  *(u32*)(out + (size_t)row*256 + lane*2) = pk;
  float2 nv = *(const float2*)(node + loc*128 + lane*2);
  u32 pn = (u32)f2bf(nv.x) | ((u32)f2bf(nv.y) << 16);
  *(u32*)(out + (size_t)row*256 + 128 + lane*2) = pn;
}

// fused blk2 node-add + blk4 npr table: x = node_in + 4 partials; y==0 writes out_node;
// all blocks rmsnorm(x) and compute npr chunk
__global__ __launch_bounds__(128) void node_add_gemm2_kernel(
    const float* __restrict__ node_in, const float* __restrict__ partial,
    float* __restrict__ node_out, const float* __restrict__ nw,
    const float* __restrict__ B, float* __restrict__ C){
  __shared__ float ar[128];
  __shared__ float sred[2];
  const int row = blockIdx.x, t = threadIdx.x;
  float x = node_in[row*128 + t]
          + (partial[(4*row)*128+t] + partial[(4*row+1)*128+t]
           + partial[(4*row+2)*128+t] + partial[(4*row+3)*128+t]);
  if (blockIdx.y == 0) node_out[row*128 + t] = x;
  float s = waveSum(x*x);
  if ((t & 63) == 0) sred[t>>6] = s;
  __syncthreads();
  float rs = rsqrtf((sred[0]+sred[1])*(1.0f/128.0f) + 1e-6f);
  ar[t] = x * rs * nw[t];
  __syncthreads();
  const int c = blockIdx.y;
  const int half = c >> 2, sub = c & 3;
  const int brow = 128 + half*128;
  const int col = sub*128 + t;
  float acc = 0.f;
  for (int k=0;k<128;k++) acc = fmaf(ar[k], B[(size_t)(brow+k)*512 + col], acc);
  C[(size_t)row*1024 + half*512 + col] = acc;
}

// ---------------- dual MFMA GEMM ----------------
__global__ __launch_bounds__(256) void gemm2_bf16_kernel(
    const u16* __restrict__ A, int lda,
    const u16* __restrict__ Bt0, u16* __restrict__ C0, int N0, int K0, int ny0,
    const u16* __restrict__ Bt1, u16* __restrict__ C1, int N1, int K1){
  __shared__ float cl[32*128];
  const int lane = threadIdx.x & 63, wave = threadIdx.x >> 6;
  const int job1 = ((int)blockIdx.y >= ny0);
  const u16* Bt = job1 ? Bt1 : Bt0;
  u16* C = job1 ? C1 : C0;
  const int N = job1 ? N1 : N0;
  const int K = job1 ? K1 : K0;
  const int by = job1 ? ((int)blockIdx.y - ny0) : (int)blockIdx.y;
  const size_t arow = (size_t)blockIdx.x*32;
  const size_t bcol = (size_t)by*128 + wave*32;
  f32x4 acc00={0,0,0,0}, acc01={0,0,0,0}, acc10={0,0,0,0}, acc11={0,0,0,0};
  for (int k=0; k<K; k+=32){
    int ko = k + (lane>>4)*8;
    bf16x8 a0 = *(const bf16x8*)(A + (arow + (lane&15))*lda + ko);
    bf16x8 a1 = *(const bf16x8*)(A + (arow + 16 + (lane&15))*lda + ko);
    bf16x8 b0 = *(const bf16x8*)(Bt + (bcol + (lane&15))*K + ko);
    bf16x8 b1 = *(const bf16x8*)(Bt + (bcol + 16 + (lane&15))*K + ko);
    acc00 = __builtin_amdgcn_mfma_f32_16x16x32_bf16(a0, b0, acc00, 0,0,0);
    acc01 = __builtin_amdgcn_mfma_f32_16x16x32_bf16(a0, b1, acc01, 0,0,0);
    acc10 = __builtin_amdgcn_mfma_f32_16x16x32_bf16(a1, b0, acc10, 0,0,0);
    acc11 = __builtin_amdgcn_mfma_f32_16x16x32_bf16(a1, b1, acc11, 0,0,0);
  }
  const int cr = (lane>>4)*4, cc = wave*32 + (lane&15);
#pragma unroll
  for (int q=0;q<4;q++){
    cl[(cr+q)*128 + cc]      = acc00[q];
    cl[(cr+q)*128 + cc+16]   = acc01[q];
    cl[(16+cr+q)*128 + cc]    = acc10[q];
    cl[(16+cr+q)*128 + cc+16] = acc11[q];
  }
  __syncthreads();
  const int t = threadIdx.x;
#pragma unroll
  for (int i=0;i<16;i++){
    int idx = i*256 + t; int r = idx>>7, c = idx&127;
    int gcol = by*128 + c;
    C[(arow + r)*(size_t)N + cperm<1>(gcol)] = f2bf(cl[idx]);
  }
}

// ---------------- fused angle kernel v11 (proven, linear vgn) ----------------
template<bool IS_BLK1>
__global__ __launch_bounds__(512, 4) void angle11_kernel(
    const u16* __restrict__ hat, const u16* __restrict__ preE, const u16* __restrict__ preK,
    const u16* __restrict__ wangT, const u16* __restrict__ woT,
    const float* __restrict__ angle,
    const float* __restrict__ rbf, const float* __restrict__ envW,
    const float* __restrict__ a_sw,
    const u16* __restrict__ aprojTb, const float* __restrict__ eproj,
    float* __restrict__ edge_out, float* __restrict__ angle_out)
{
  constexpr int HW = IS_BLK1 ? 640 : 512;
  constexpr int VGN_B  = 48*264*2;
  constexpr int GATE_O = VGN_B;
  constexpr int SS_O   = GATE_O + (IS_BLK1 ? 48*132*2 : 0);
  constexpr int RS_O   = SS_O + 8*48*4;
  constexpr int SEG_O  = RS_O + 192;
  constexpr int RBF_O  = SEG_O + (IS_BLK1 ? 0 : 1024);
  constexpr int LDS_B  = RBF_O + (IS_BLK1 ? 0 : 1152);
  __shared__ __align__(16) char ldsRaw[LDS_B];
  u16*   vgn    = (u16*)ldsRaw;
  u16*   gateLb = (u16*)(ldsRaw + GATE_O);
  float* ssL    = (float*)(ldsRaw + SS_O);
  float* rsL    = (float*)(ldsRaw + RS_O);
  float* segL   = (float*)(ldsRaw + SEG_O);
  float* rbfL   = (float*)(ldsRaw + RBF_O);
  float* msgL   = (float*)ldsRaw;

  const int t = threadIdx.x, lane = t & 63, w = t >> 6;
  const int l15 = lane & 15, l4 = lane >> 4;
  const int b = blockIdx.x;
  const int xcd = b & 7, idx = b >> 3;
  const int loc = xcd*16 + idx/12;
  const int j0 = (idx - (idx/12)*12)*2;
  const int s0 = loc*24 + j0;
  const int hbase = s0*24;
  const int oc = 16*w + l15;

  if constexpr (!IS_BLK1){
    if (t < 288) rbfL[t] = rbf[(size_t)(loc*64)*12 + t];
  }

  u16x8 pk[3][2], pe[3][2];
  u16x4 pkg[3], peg[3];
#pragma unroll
  for (int nt=0; nt<3; nt++){
    const int r = nt*16 + l15;
    const int hi = (r >= 24);
    const int rr = r - 24*hi;
    const u16* pK = preK + (size_t)(loc*24 + rr)*HW;
    const u16* pE = preE + (size_t)(s0 + hi)*HW;
#pragma unroll
    for (int i=0;i<2;i++){
      const int a = (2*w + i)*4 + l4;
      pk[nt][i] = *(const u16x8*)(pK + a*8);
      pe[nt][i] = *(const u16x8*)(pE + a*8);
    }
    if constexpr (IS_BLK1){
      const int cg = 512 + w*16 + l4*4;
      pkg[nt] = *(const u16x4*)(pK + cg);
      peg[nt] = *(const u16x4*)(pE + cg);
    }
  }

  f32x4 accv[3][2], accg[3][2], accgate[3];
#pragma unroll
  for (int nt=0;nt<3;nt++){
    accv[nt][0]=(f32x4){0,0,0,0}; accv[nt][1]=(f32x4){0,0,0,0};
    accg[nt][0]=(f32x4){0,0,0,0}; accg[nt][1]=(f32x4){0,0,0,0};
    accgate[nt]=(f32x4){0,0,0,0};
  }
#pragma unroll
  for (int kk=0; kk<2; kk++){
    const int ko = kk*32 + l4*8;
    bf16x8 bb[3];
#pragma unroll
    for (int nt=0;nt<3;nt++)
      bb[nt] = *(const bf16x8*)(hat + (size_t)(hbase + nt*16 + l15)*64 + ko);
#pragma unroll
    for (int i=0;i<2;i++){
      const int chv = (2*w + i)*16 + l15;
      bf16x8 av = *(const bf16x8*)(wangT + (size_t)chv*64 + ko);
      bf16x8 ag = *(const bf16x8*)(wangT + (size_t)(256 + chv)*64 + ko);
#pragma unroll
      for (int nt=0;nt<3;nt++){
        accv[nt][i] = __builtin_amdgcn_mfma_f32_16x16x32_bf16(av, bb[nt], accv[nt][i], 0,0,0);
        accg[nt][i] = __builtin_amdgcn_mfma_f32_16x16x32_bf16(ag, bb[nt], accg[nt][i], 0,0,0);
      }
    }
    if constexpr (IS_BLK1){
      bf16x8 aga = *(const bf16x8*)(wangT + (size_t)(512 + w*16 + l15)*64 + ko);
#pragma unroll
      for (int nt=0;nt<3;nt++)
        accgate[nt] = __builtin_amdgcn_mfma_f32_16x16x32_bf16(aga, bb[nt], accgate[nt], 0,0,0);
    }
  }

  float ssr[3] = {0.f, 0.f, 0.f};
#pragma unroll
  for (int nt=0; nt<3; nt++){
    const int r = nt*16 + l15;
#pragma unroll
    for (int i=0;i<2;i++){
      const int cb = (2*w + i)*16 + l4*4;
      u16x4 xs;
#pragma unroll
      for (int q=0;q<4;q++){
        float v = accv[nt][i][q] + bf2f(pk[nt][i][q])   + bf2f(pe[nt][i][q]);
        float g = accg[nt][i][q] + bf2f(pk[nt][i][4+q]) + bf2f(pe[nt][i][4+q]);
        float x = v * silu(g);
        ssr[nt] += x*x;
        xs[q] = f2bf(x);
      }
      *(u16x4*)&vgn[r*264 + cb] = xs;
    }
    if constexpr (IS_BLK1){
      u16x4 gs;
#pragma unroll
      for (int q=0;q<4;q++)
        gs[q] = f2bf((accgate[nt][q] + bf2f(pkg[nt][q]) + bf2f(peg[nt][q])) * A_SCALE_C);
      *(u16x4*)&gateLb[r*132 + w*16 + l4*4] = gs;
    }
  }
#pragma unroll
  for (int nt=0;nt<3;nt++){
    float s = ssr[nt];
    s += __shfl_xor(s,16,64); s += __shfl_xor(s,32,64);
    if (l4 == 0) ssL[w*48 + nt*16 + l15] = s;
  }
  bf16x8 bwp[8];
#pragma unroll
  for (int kk=0; kk<8; kk++)
    bwp[kk] = *(const bf16x8*)(woT + (size_t)oc*256 + kk*32 + l4*8);
  __syncthreads();                    // sync1
  if (t < 48){
    float s_ = 0.f;
#pragma unroll
    for (int k=0;k<8;k++) s_ += ssL[k*48 + t];
    rsL[t] = rsqrtf(s_*(1.0f/256.0f) + 1e-6f);
  }

  f32x4 mac[3];
#pragma unroll
  for (int m=0;m<3;m++) mac[m] = (f32x4){0,0,0,0};
#pragma unroll
  for (int kk=0; kk<8; kk++){
#pragma unroll
    for (int m=0;m<3;m++){
      bf16x8 aw = *(const bf16x8*)&vgn[(m*16 + l15)*264 + kk*32 + l4*8];
      mac[m] = __builtin_amdgcn_mfma_f32_16x16x32_bf16(aw, bwp[kk], mac[m], 0,0,0);
    }
  }
  __syncthreads();                    // sync2
  float rsv[3][4];
#pragma unroll
  for (int m=0;m<3;m++)
#pragma unroll
    for (int q=0;q<4;q++) rsv[m][q] = rsL[m*16 + l4*4 + q];
#pragma unroll
  for (int m=0;m<3;m++)
#pragma unroll
    for (int q=0;q<4;q++)
      msgL[(m*16 + l4*4 + q)*132 + 16*w + l15] = mac[m][q] * rsv[m][q];
  __syncthreads();                    // sync3

  if constexpr (IS_BLK1){
    if (t < 256){
      int s = t>>7, c = t&127;
      float ex[24]; float mx = -1e30f;
#pragma unroll
      for (int k=0;k<24;k++){ ex[k] = bf2f(gateLb[(s*24+k)*132 + c]); mx = fmaxf(mx, ex[k]); }
      float S = 0.f;
#pragma unroll
      for (int k=0;k<24;k++){ ex[k] = __expf(ex[k] - mx); S += ex[k]; }
      float inv = 1.f/(S + 1e-12f);
      float delta = 0.f;
#pragma unroll
      for (int k=0;k<24;k++) delta += msgL[(s*24+k)*132 + c] * ex[k];
      edge_out[(size_t)(loc*64 + j0 + s)*128 + c] += delta * inv;
    }
  } else {
    if (t < 256){
      int s = t>>7, c = t&127;
      float envR[12];
#pragma unroll
      for (int j=0;j<12;j++) envR[j] = envW[j*128 + c];
      float sg_ = 0.f;
#pragma unroll
      for (int k=0;k<24;k++){
        float envC = 0.f;
#pragma unroll
        for (int j=0;j<12;j++) envC = fmaf(rbfL[k*12 + j], envR[j], envC);
        sg_ += msgL[(s*24+k)*132 + c] * envC * a_sw[(size_t)(s0+s)*24 + k];
      }
      segL[s*128 + c] = sg_;
    }
    for (int p = w; p < 12; p += 8){
      const int mt = p >> 2, ntc = p & 3;
      f32x4 am = (f32x4){0,0,0,0};
#pragma unroll
      for (int kk=0; kk<4; kk++){
        const float* mrow = &msgL[(mt*16 + l15)*132 + kk*32 + l4*8];
        bf16x8 a;
#pragma unroll
        for (int e=0;e<8;e++) a[e] = (short)f2bf(mrow[e]);
        bf16x8 bb = *(const bf16x8*)(aprojTb + (size_t)(ntc*16 + l15)*128 + kk*32 + l4*8);
        am = __builtin_amdgcn_mfma_f32_16x16x32_bf16(a, bb, am, 0,0,0);
      }
#pragma unroll
      for (int q=0;q<4;q++){
        int row = mt*16 + l4*4 + q;
        size_t a_ = (size_t)hbase + row;
        int col = ntc*16 + l15;
        angle_out[a_*64 + col] = angle[a_*64 + col] + am[q] * a_sw[a_];
      }
    }
    __syncthreads();
    if (t < 256){
      int s = t>>7, c = t&127;
      float acc2 = 0.f;
      for (int dd=0; dd<128; dd++) acc2 = fmaf(segL[s*128 + dd], eproj[dd*128 + c], acc2);
      edge_out[(size_t)(loc*64 + j0 + s)*128 + c] += acc2 * A_SCALE_C;
    }
  }
}

// ---------------- scores v4: inline rmsnorm + MFMA gate + 2-way parallel softmax ----------------
__global__ __launch_bounds__(256) void scores3_kernel(const float* __restrict__ edge_src,
                                                      const float* __restrict__ norm_e,
                                                      const u16* __restrict__ gateT,
                                                      float* __restrict__ scores){
  __shared__ float s[64*132];
  __shared__ float red[2][128];
  const int t = threadIdx.x, lane = t & 63, w = t >> 6;
  const int l15 = lane & 15, l4 = lane >> 4;
  const int n = blockIdx.x;
  const int row = n*64 + w*16 + l15;
  bf16x8 bfr[4];
  row_rms_frag(edge_src + (size_t)row*128, norm_e, l4, bfr);
  f32x4 acc[8];
#pragma unroll
  for (int j=0;j<8;j++) acc[j] = (f32x4){0,0,0,0};
#pragma unroll
  for (int kk=0; kk<4; kk++){
    const int ko = kk*32 + l4*8;
#pragma unroll
    for (int j=0;j<8;j++){
      bf16x8 b = *(const bf16x8*)(gateT + (size_t)(j*16 + l15)*128 + ko);
      acc[j] = __builtin_amdgcn_mfma_f32_16x16x32_bf16(bfr[kk], b, acc[j], 0,0,0);
    }
  }
#pragma unroll
  for (int j=0;j<8;j++)
#pragma unroll
    for (int q=0;q<4;q++)
      s[(w*16 + l4*4 + q)*132 + j*16 + l15] = acc[j][q] * E_SCALE_C;
  __syncthreads();
  {
    const int c = t & 127, h = t >> 7;
    const int r0 = h*32;
    float m = -1e30f;
    for (int r=r0; r<r0+32; r++) m = fmaxf(m, s[r*132 + c]);
    red[h][c] = m;
    __syncthreads();
    m = fmaxf(red[0][c], red[1][c]);
    __syncthreads();
    float S = 0.f;
    for (int r=r0; r<r0+32; r++) S += __expf(s[r*132 + c] - m);
    red[h][c] = S;
    __syncthreads();
    S = red[0][c] + red[1][c];
    float inv = 1.f/(S + 1e-12f);
    for (int r=r0; r<r0+32; r++)
      scores[(size_t)(n*64 + r)*128 + c] = __expf(s[r*132 + c] - m) * inv;
  }
}

// ---------------- combined blk2 edge kernel (inline rmsnorm) ----------------
__global__ __launch_bounds__(256) void edge_fused01_kernel(
    const float* __restrict__ edge_src,
    const float* __restrict__ norm_e,
    const float* __restrict__ NPa, const float* __restrict__ NPe,
    const int* __restrict__ next2e,
    const u16* __restrict__ aaWT, const u16* __restrict__ aeWT,
    const u16* __restrict__ woaaT, const u16* __restrict__ woaeT,
    const float* __restrict__ scores,
    float* __restrict__ edge_out, float* __restrict__ partial){
  __shared__ __align__(16) char lds[13184];
  u16*   vgn  = (u16*)lds;
  float* msgF = (float*)lds;
  float* ssP  = (float*)(lds + 12800);
  float* rsL  = (float*)(lds + 13056);
  const int t = threadIdx.x, lane = t & 63, w = t >> 6;
  const int l15 = lane & 15, l4 = lane >> 4;
  const int g = blockIdx.x, e0 = g*16, n = e0 >> 6;
  const int nx = next2e[e0 + l15];

  bf16x8 bfr[4];
  row_rms_frag(edge_src + (size_t)(e0 + l15)*128, norm_e, l4, bfr);

#pragma unroll
  for (int path=0; path<2; path++){
    const u16* wT  = path ? aeWT : aaWT;
    const u16* woT = path ? woaeT : woaaT;
    const float* NPt = path ? NPe : NPa;

    f32x4 av4[4], ag4[4];
#pragma unroll
    for (int i=0;i<4;i++){ av4[i]=(f32x4){0,0,0,0}; ag4[i]=(f32x4){0,0,0,0}; }
#pragma unroll
    for (int kk=0; kk<4; kk++){
      const int ko = kk*32 + l4*8;
#pragma unroll
      for (int i=0;i<4;i++){
        const int chr = w*64 + i*16 + l15;
        bf16x8 wv = *(const bf16x8*)(wT + (size_t)chr*128 + ko);
        bf16x8 wg = *(const bf16x8*)(wT + (size_t)(256 + chr)*128 + ko);
        av4[i] = __builtin_amdgcn_mfma_f32_16x16x32_bf16(wv, bfr[kk], av4[i], 0,0,0);
        ag4[i] = __builtin_amdgcn_mfma_f32_16x16x32_bf16(wg, bfr[kk], ag4[i], 0,0,0);
      }
    }

    float ssr = 0.f;
#pragma unroll
    for (int i=0;i<4;i++){
      const int cb = w*64 + i*16 + l4*4;
      float4 sv = *(const float4*)(NPt + n*1024 + cb);
      float4 sg = *(const float4*)(NPt + n*1024 + 256 + cb);
      float4 nv = *(const float4*)(NPt + (size_t)nx*1024 + 512 + cb);
      float4 ng = *(const float4*)(NPt + (size_t)nx*1024 + 768 + cb);
      u16x4 xs;
#pragma unroll
      for (int q=0;q<4;q++){
        float v  = av4[i][q] + ((const float*)&sv)[q] + ((const float*)&nv)[q];
        float gg = ag4[i][q] + ((const float*)&sg)[q] + ((const float*)&ng)[q];
        float x = v * silu(gg);
        ssr += x*x;
        xs[q] = f2bf(x);
      }
      *(u16x4*)&vgn[l15*264 + cb] = xs;
    }
    {
      float s = ssr;
      s += __shfl_xor(s,16,64); s += __shfl_xor(s,32,64);
      if (l4 == 0) ssP[l15*4 + w] = s;
    }
    __syncthreads();
    if (t < 16)
      rsL[t] = rsqrtf((ssP[t*4]+ssP[t*4+1]+ssP[t*4+2]+ssP[t*4+3])*(1.0f/256.0f) + 1e-6f);
    __syncthreads();
    f32x4 mac[2] = {(f32x4){0,0,0,0}, (f32x4){0,0,0,0}};
#pragma unroll
    for (int kk=0; kk<8; kk++){
      bf16x8 a = *(const bf16x8*)&vgn[l15*264 + kk*32 + l4*8];
#pragma unroll
      for (int nt=0; nt<2; nt++){
        bf16x8 bw = *(const bf16x8*)(woT + (size_t)(32*w + nt*16 + l15)*256 + kk*32 + l4*8);
        mac[nt] = __builtin_amdgcn_mfma_f32_16x16x32_bf16(a, bw, mac[nt], 0,0,0);
      }
    }
    float rsv[4];
#pragma unroll
    for (int q=0;q<4;q++) rsv[q] = rsL[l4*4 + q];
    __syncthreads();
#pragma unroll
    for (int nt=0; nt<2; nt++)
#pragma unroll
      for (int q=0;q<4;q++)
        msgF[(l4*4 + q)*132 + 32*w + nt*16 + l15] = mac[nt][q] * rsv[q];
    __syncthreads();

    if (path == 0){
      if (t < 128){
        float p = 0.f;
#pragma unroll
        for (int r=0;r<16;r++) p += msgF[r*132 + t] * scores[(size_t)(e0+r)*128 + t];
        partial[g*128 + t] = p;
      }
    } else {
      const int d = t & 127, rg = (t >> 7) * 8;
#pragma unroll
      for (int i=0;i<8;i++)
        edge_out[(size_t)(e0+rg+i)*128 + d] += msgF[(rg+i)*132 + d];
    }
    __syncthreads();
  }
}

// ---------------- blk4 edge kernel: MODE2 with fused rmsnorm ----------------
__global__ __launch_bounds__(256) void edge_fused2m2_kernel(
    const float* __restrict__ edge_src,
    const float* __restrict__ norm_e,
    const float* __restrict__ NPt,
    const int* __restrict__ next2e,
    const u16* __restrict__ wT,
    const u16* __restrict__ woT,
    const float* __restrict__ rbf, const float* __restrict__ envW,
    const float* __restrict__ sw, const u16* __restrict__ eprojT,
    float* __restrict__ edge_out, float* __restrict__ partial){
  __shared__ __align__(16) char lds[20096];
  u16*   vgn  = (u16*)lds;
  float* msgF = (float*)lds;
  u16*   msgB = (u16*)(lds + 8448);
  float* ssP  = (float*)(lds + 12800);
  float* rsL  = (float*)(lds + 13056);
  float* envWL= (float*)(lds + 13184);
  float* rbfL = (float*)(lds + 19328);
  const int t = threadIdx.x, lane = t & 63, w = t >> 6;
  const int l15 = lane & 15, l4 = lane >> 4;
  const int g = blockIdx.x, e0 = g*16, n = e0 >> 6;
  const int nx = next2e[e0 + l15];
  for (int i=t; i<12*128; i+=256) envWL[i] = envW[i];
  if (t < 192) rbfL[t] = rbf[(size_t)e0*12 + t];

  bf16x8 bfr[4];
  row_rms_frag(edge_src + (size_t)(e0 + l15)*128, norm_e, l4, bfr);

  float4 sv[4], sg[4], nv[4], ng[4];
#pragma unroll
  for (int i=0;i<4;i++){
    const int cb = w*64 + i*16 + l4*4;
    sv[i] = *(const float4*)(NPt + n*1024 + cb);
    sg[i] = *(const float4*)(NPt + n*1024 + 256 + cb);
    nv[i] = *(const float4*)(NPt + (size_t)nx*1024 + 512 + cb);
    ng[i] = *(const float4*)(NPt + (size_t)nx*1024 + 768 + cb);
  }

  f32x4 av4[4], ag4[4];
#pragma unroll
  for (int i=0;i<4;i++){ av4[i]=(f32x4){0,0,0,0}; ag4[i]=(f32x4){0,0,0,0}; }
#pragma unroll
  for (int kk=0; kk<4; kk++){
    const int ko = kk*32 + l4*8;
#pragma unroll
    for (int i=0;i<4;i++){
      const int chr = w*64 + i*16 + l15;
      bf16x8 wv = *(const bf16x8*)(wT + (size_t)chr*128 + ko);
      bf16x8 wg = *(const bf16x8*)(wT + (size_t)(256 + chr)*128 + ko);
      av4[i] = __builtin_amdgcn_mfma_f32_16x16x32_bf16(wv, bfr[kk], av4[i], 0,0,0);
      ag4[i] = __builtin_amdgcn_mfma_f32_16x16x32_bf16(wg, bfr[kk], ag4[i], 0,0,0);
    }
  }

  float ssr = 0.f;
#pragma unroll
  for (int i=0;i<4;i++){
    const int cb = w*64 + i*16 + l4*4;
    u16x4 xs;
#pragma unroll
    for (int q=0;q<4;q++){
      float v = av4[i][q] + ((const float*)&sv[i])[q] + ((const float*)&nv[i])[q];
      float gg = ag4[i][q] + ((const float*)&sg[i])[q] + ((const float*)&ng[i])[q];
      float x = v * silu(gg);
      ssr += x*x;
      xs[q] = f2bf(x);
    }
    *(u16x4*)&vgn[l15*264 + cb] = xs;
  }
  {
    float s = ssr;
    s += __shfl_xor(s,16,64); s += __shfl_xor(s,32,64);
    if (l4 == 0) ssP[l15*4 + w] = s;
  }
  __syncthreads();
  if (t < 16)
    rsL[t] = rsqrtf((ssP[t*4]+ssP[t*4+1]+ssP[t*4+2]+ssP[t*4+3])*(1.0f/256.0f) + 1e-6f);
  __syncthreads();
  f32x4 mac[2] = {(f32x4){0,0,0,0}, (f32x4){0,0,0,0}};
#pragma unroll
  for (int kk=0; kk<8; kk++){
    bf16x8 a = *(const bf16x8*)&vgn[l15*264 + kk*32 + l4*8];
#pragma unroll
    for (int nt=0; nt<2; nt++){
      bf16x8 bw = *(const bf16x8*)(woT + (size_t)(32*w + nt*16 + l15)*256 + kk*32 + l4*8);
      mac[nt] = __builtin_amdgcn_mfma_f32_16x16x32_bf16(a, bw, mac[nt], 0,0,0);
    }
  }
  float rsv[4];
#pragma unroll
  for (int q=0;q<4;q++) rsv[q] = rsL[l4*4 + q];
  __syncthreads();
#pragma unroll
  for (int nt=0; nt<2; nt++)
#pragma unroll
    for (int q=0;q<4;q++){
      float val = mac[nt][q] * rsv[q];
      int row = l4*4 + q, col = 32*w + nt*16 + l15;
      msgF[row*132 + col] = val;
      msgB[row*136 + col] = f2bf(val);
    }
  __syncthreads();

  f32x4 em[2] = {(f32x4){0,0,0,0}, (f32x4){0,0,0,0}};
#pragma unroll
  for (int kk=0; kk<4; kk++){
    bf16x8 a = *(const bf16x8*)&msgB[l15*136 + kk*32 + l4*8];
#pragma unroll
    for (int nt=0; nt<2; nt++){
      bf16x8 bw = *(const bf16x8*)(eprojT + (size_t)(32*w + nt*16 + l15)*128 + kk*32 + l4*8);
      em[nt] = __builtin_amdgcn_mfma_f32_16x16x32_bf16(a, bw, em[nt], 0,0,0);
    }
  }
#pragma unroll
  for (int nt=0; nt<2; nt++)
#pragma unroll
    for (int q=0;q<4;q++)
      edge_out[(size_t)(e0 + l4*4 + q)*128 + 32*w + nt*16 + l15] += em[nt][q];
  if (t < 128){
    float p = 0.f;
#pragma unroll
    for (int r=0;r<16;r++){
      float envC = 0.f;
#pragma unroll
      for (int j=0;j<12;j++) envC = fmaf(rbfL[r*12 + j], envWL[j*128 + t], envC);
      p += msgF[r*132 + t] * envC * sw[e0 + r];
    }
    partial[g*128 + t] = p;
  }
}

__global__ void node_final4_kernel(const float* __restrict__ partial,
                                   const float* __restrict__ nproj,
                                   float* __restrict__ node_out){
  __shared__ float seg[128];
  int n = blockIdx.x, t = threadIdx.x;
  seg[t] = partial[(4*n)*128+t] + partial[(4*n+1)*128+t]
         + partial[(4*n+2)*128+t] + partial[(4*n+3)*128+t];
  __syncthreads();
  float acc = 0.f;
  for (int dd=0; dd<128; dd++) acc = fmaf(seg[dd], nproj[dd*128 + t], acc);
  node_out[n*128 + t] += acc * E_SCALE_C;
}

// ---------------- launch ----------------
extern "C" void kernel_launch(void* const* d_in, const int* in_sizes, int n_in,
                              void* d_out, int out_size, void* d_ws, size_t ws_size,
                              hipStream_t stream){
  const float* node_in  = (const float*)d_in[0];
  const float* edge_in  = (const float*)d_in[1];
  const float* angle_in = (const float*)d_in[2];
  const float* sw       = (const float*)d_in[3];
  const float* a_sw     = (const float*)d_in[4];
  const float* rbf      = (const float*)d_in[5];
  const int*   edge_index = (const int*)d_in[6];
  const float* la_norm_e = (const float*)d_in[8];
  const float* la_norm_a = (const float*)d_in[9];
  const float* la_win    = (const float*)d_in[10];
  const float* la_nw     = (const float*)d_in[11];
  const float* la_wout   = (const float*)d_in[12];
  const float* la_gate   = (const float*)d_in[13];
  const float* aa_norm_n = (const float*)d_in[14];
  const float* aa_norm_e = (const float*)d_in[15];
  const float* aa_win    = (const float*)d_in[16];
  const float* aa_nw     = (const float*)d_in[17];
  const float* aa_wout   = (const float*)d_in[18];
  const float* aa_src_gate = (const float*)d_in[19];
  const float* ae_win    = (const float*)d_in[20];
  const float* ae_nw     = (const float*)d_in[21];
  const float* ae_wout   = (const float*)d_in[22];
  const float* lr_norm_e = (const float*)d_in[23];
  const float* lr_norm_a = (const float*)d_in[24];
  const float* lr_win    = (const float*)d_in[25];
  const float* lr_nw     = (const float*)d_in[26];
  const float* lr_wout   = (const float*)d_in[27];
  const float* lr_env    = (const float*)d_in[28];
  const float* lr_eproj  = (const float*)d_in[29];
  const float* lr_aproj  = (const float*)d_in[30];
  const float* ar_norm_n = (const float*)d_in[31];
  const float* ar_norm_e = (const float*)d_in[32];
  const float* ar_win    = (const float*)d_in[33];
  const float* ar_nw     = (const float*)d_in[34];
  const float* ar_wout   = (const float*)d_in[35];
  const float* ar_env    = (const float*)d_in[36];
  const float* ar_nproj  = (const float*)d_in[37];
  const float* ar_eproj  = (const float*)d_in[38];

  float* out_node  = (float*)d_out;
  float* out_edge  = out_node + 128*128;
  float* out_angle = out_edge + (size_t)8192*128;

  float* p = (float*)d_ws;
  float* hat_f   = p; p += 2359296;
  float* enca_f  = p; p += 393216;
  float* preE_f  = p; p += 983040;
  float* preK_f  = p; p += 983040;
  float* wang1_f = p; p += 20480;
  float* wang3_f = p; p += 16384;
  float* wij1_f  = p; p += 40960;
  float* wij3_f  = p; p += 32768;
  float* wik1_f  = p; p += 81920;
  float* wik3_f  = p; p += 65536;
  float* wo1T_f  = p; p += 16384;
  float* wo3T_f  = p; p += 16384;
  float* whe2_f  = p; p += 73728;
  float* whe4_f  = p; p += 32768;
  float* woaaT_f = p; p += 16384;
  float* woaeT_f = p; p += 16384;
  float* woarT_f = p; p += 16384;
  float* eprjT_f = p; p += 8192;
  float* aprjT_f = p; p += 4096;
  float* npa     = p; p += 131072;
  float* npe     = p; p += 131072;
  float* npr     = p; p += 131072;
  float* scores2 = p; p += 1048576;
  float* partial = p; p += 65536;

  u16* hat  = (u16*)hat_f;
  u16* enca = (u16*)enca_f;
  u16* preE = (u16*)preE_f;
  u16* preK = (u16*)preK_f;
  u16* wang1= (u16*)wang1_f;
  u16* wang3= (u16*)wang3_f;
  u16* wij1 = (u16*)wij1_f;
  u16* wij3 = (u16*)wij3_f;
  u16* wik1 = (u16*)wik1_f;
  u16* wik3 = (u16*)wik3_f;
  u16* wo1T = (u16*)wo1T_f;
  u16* wo3T = (u16*)wo3T_f;
  u16* whe2 = (u16*)whe2_f;
  u16* whe4 = (u16*)whe4_f;
  u16* woaaT= (u16*)woaaT_f;
  u16* woaeT= (u16*)woaeT_f;
  u16* woarT= (u16*)woarT_f;
  u16* eprjT= (u16*)eprjT_f;
  u16* aprjT= (u16*)aprjT_f;
  u16* aaWT = whe2;
  u16* aeWT = whe2 + 512*128;
  u16* gateT= whe2 + 1024*128;
  u16* arWT = whe4;

  dim3 b512(512), b256(256), b128(128);
  const int* next2e = edge_index + 8192;

  WtJobs jobs;
  int nj = 0;
  auto add = [&](const float* src, const float* scale, u16* dst,
                 int ld, int row0, int c0, int k0, int dlog, int kslog, int C){
    jobs.j[nj++] = WtJob{src, scale, dst, ld, row0, c0, k0, dlog, kslog, C};
  };
  add(la_win, la_norm_a, wang1, 512, 0,   0,   0,   6, 6, 512);
  add(la_gate,la_norm_a, wang1, 128, 0,   512, 0,   6, 6, 128);
  add(la_win, nullptr,   wij1,  512, 192, 0,   0,   7, 7, 512);
  add(la_gate,nullptr,   wij1,  128, 192, 512, 0,   7, 7, 128);
  add(la_win, nullptr,   wik1,  512, 320, 0,   0,   8, 7, 512);
  add(la_gate,nullptr,   wik1,  128, 320, 512, 0,   8, 7, 128);
  add(la_win, nullptr,   wik1,  512, 64,  0,   128, 8, 7, 512);
  add(la_gate,nullptr,   wik1,  128, 64,  512, 128, 8, 7, 128);
  add(la_wout,la_nw,     wo1T,  128, 0,   0,   0,   8, 8, 128);
  add(lr_win, lr_norm_a, wang3, 512, 0,   0,   0,   6, 6, 512);
  add(lr_win, nullptr,   wij3,  512, 192, 0,   0,   7, 7, 512);
  add(lr_win, nullptr,   wik3,  512, 320, 0,   0,   8, 7, 512);
  add(lr_win, nullptr,   wik3,  512, 64,  0,   128, 8, 7, 512);
  add(lr_wout,lr_nw,     wo3T,  128, 0,   0,   0,   8, 8, 128);
  add(aa_win, nullptr,   whe2,  512, 0,   0,   0,   7, 7, 512);
  add(ae_win, nullptr,   whe2,  512, 0,   512, 0,   7, 7, 512);
  add(aa_src_gate,nullptr,whe2, 128, 0,   1024,0,   7, 7, 128);
  add(ar_win, nullptr,   whe4,  512, 0,   0,   0,   7, 7, 512);
  add(aa_wout, aa_nw,    woaaT, 128, 0,   0,   0,   8, 8, 128);
  add(ae_wout, ae_nw,    woaeT, 128, 0,   0,   0,   8, 8, 128);
  add(ar_wout, ar_nw,    woarT, 128, 0,   0,   0,   8, 8, 128);
  add(ar_eproj,nullptr,  eprjT, 128, 0,   0,   0,   7, 7, 128);
  add(lr_aproj,nullptr,  aprjT, 64,  0,   0,   0,   7, 7, 64);
  build_all_wt<<<dim3(64, 23), b256, 0, stream>>>(jobs);

  // prologue: vectorized hat + edge copy + blk2 node tables (input-only deps)
  hat_init_kernel<<<4608 + 1024 + 2048, b256, 0, stream>>>(angle_in, hat,
      (const float4*)edge_in, (float4*)out_edge,
      node_in, aa_norm_n, aa_win, npa, ae_win, npe);

  // ---- block 1 ----
  rmsnorm128c_aug_kernel<<<768, b256, 0, stream>>>(edge_in, la_norm_e, node_in, enca);
  gemm2_bf16_kernel<<<dim3(96,10), b256, 0, stream>>>(enca, 256,
      wij1, preE, 640, 128, 5, wik1, preK, 640, 256);
  angle11_kernel<true><<<1536, b512, 0, stream>>>(hat, preE, preK, wang1, wo1T,
      angle_in, nullptr, nullptr, nullptr, nullptr, nullptr, out_edge, nullptr);

  // ---- block 2 (edge rmsnorm fused; node add fused with blk4 npr table) ----
  scores3_kernel<<<128, b256, 0, stream>>>(out_edge, aa_norm_e, gateT, scores2);
  edge_fused01_kernel<<<512, b256, 0, stream>>>(out_edge, aa_norm_e, npa, npe, next2e,
      aaWT, aeWT, woaaT, woaeT, scores2, out_edge, partial);
  node_add_gemm2_kernel<<<dim3(128,8), b128, 0, stream>>>(node_in, partial,
      out_node, ar_norm_n, ar_win, npr);

  // ---- block 3 ----
  rmsnorm128c_aug_kernel<<<768, b256, 0, stream>>>(out_edge, lr_norm_e, out_node, enca);
  gemm2_bf16_kernel<<<dim3(96,8), b256, 0, stream>>>(enca, 256,
      wij3, preE, 512, 128, 4, wik3, preK, 512, 256);
  angle11_kernel<false><<<1536, b512, 0, stream>>>(hat, preE, preK, wang3, wo3T,
      angle_in, rbf, lr_env, a_sw, aprjT, lr_eproj, out_edge, out_angle);

  // ---- block 4 (npr precomputed at blk2) ----
  edge_fused2m2_kernel<<<512, b256, 0, stream>>>(out_edge, ar_norm_e, npr, next2e,
      arWT, woarT, rbf, ar_env, sw, eprjT, out_edge, partial);
  node_final4_kernel<<<128, b128, 0, stream>>>(partial, ar_nproj, out_node);

  (void)in_sizes; (void)n_in; (void)out_size; (void)ws_size;
}

// Round 24
// 246.994 us; speedup vs baseline: 1.0532x; 1.0234x over previous
//
#include <hip/hip_runtime.h>
#include <hip/hip_bf16.h>

#define A_SCALE_C 0.6454972243679028f   // (24/10)^-0.5
#define E_SCALE_C 0.3952847075210474f   // (64/10)^-0.5

typedef unsigned short u16;
typedef unsigned int u32;
typedef __attribute__((ext_vector_type(8))) short bf16x8;
typedef __attribute__((ext_vector_type(4))) float f32x4;
typedef __attribute__((ext_vector_type(4))) unsigned short u16x4;
typedef __attribute__((ext_vector_type(8))) unsigned short u16x8;

static __device__ __forceinline__ float waveSum(float v){
#pragma unroll
  for (int off = 32; off; off >>= 1) v += __shfl_xor(v, off, 64);
  return v;
}
static __device__ __forceinline__ float silu(float g){
  return g / (1.0f + __expf(-g));
}
static __device__ __forceinline__ float bf2f(u16 h){
  union { u32 u; float f; } x; x.u = ((u32)h) << 16; return x.f;
}
static __device__ __forceinline__ u16 f2bf(float f){
  __hip_bfloat16 h = __float2bfloat16(f);
  u16 r; __builtin_memcpy(&r, &h, 2); return r;
}
template<int PERM>
static __device__ __forceinline__ int cperm(int c){
  if constexpr (PERM) return (c < 512) ? (((c>>2)&63)*8 + ((c>>8)<<2) + (c&3)) : c;
  else return c;
}

// inline row rmsnorm -> bf16 A-fragments (row covered by l4-group of 4 lanes)
static __device__ __forceinline__ void row_rms_frag(
    const float* __restrict__ rowp, const float* __restrict__ normw,
    int l4, bf16x8* bfr){
  float xr[4][8];
  float ssx = 0.f;
#pragma unroll
  for (int kk=0; kk<4; kk++){
    const float* rp = rowp + kk*32 + l4*8;
    float4 a = *(const float4*)rp;
    float4 bq = *(const float4*)(rp + 4);
    xr[kk][0]=a.x; xr[kk][1]=a.y; xr[kk][2]=a.z; xr[kk][3]=a.w;
    xr[kk][4]=bq.x; xr[kk][5]=bq.y; xr[kk][6]=bq.z; xr[kk][7]=bq.w;
#pragma unroll
    for (int e=0;e<8;e++) ssx = fmaf(xr[kk][e], xr[kk][e], ssx);
  }
  ssx += __shfl_xor(ssx,16,64);
  ssx += __shfl_xor(ssx,32,64);
  const float rsx = rsqrtf(ssx*(1.0f/128.0f) + 1e-6f);
#pragma unroll
  for (int kk=0; kk<4; kk++){
    const float* wp = normw + kk*32 + l4*8;
#pragma unroll
    for (int e=0;e<8;e++) bfr[kk][e] = (short)f2bf(xr[kk][e] * rsx * wp[e]);
  }
}

// ---------------- weight-transpose job table ----------------
struct WtJob { const float* src; const float* scale; u16* dst;
               int src_ld, row0, c0, k0, dlog, kslog, C; };
struct WtJobs { WtJob j[23]; };

// ---------------- mega-prologue: all input-only work in one launch ----------------
// [0,4608): hat rmsnorm (float4, 16 rows/block)
// [4608,5632): out_edge copy-init
// [5632,7680): npa/npe node-table GEMM
// [7680,8448): blk1 enc_aug (edge_in rmsnorm + node append)
// [8448,9920): 23 weight-transpose jobs x 64 blocks
__global__ void prologue_kernel(WtJobs P,
                                const float* __restrict__ ang, u16* __restrict__ hat,
                                const float4* __restrict__ e, float4* __restrict__ oe,
                                const float* __restrict__ node, const float* __restrict__ nw,
                                const float* __restrict__ Ba, float* __restrict__ Ca,
                                const float* __restrict__ Bb, float* __restrict__ Cb,
                                const float* __restrict__ edge_in,
                                const float* __restrict__ la_ne, u16* __restrict__ enca){
  int bid = blockIdx.x;
  const int t = threadIdx.x;
  if (bid < 4608){
    const int row = bid*16 + (t >> 4);   // 73728 rows total
    const int l = t & 15;
    float4 v = *(const float4*)(ang + (size_t)row*64 + l*4);
    float ss = v.x*v.x + v.y*v.y + v.z*v.z + v.w*v.w;
#pragma unroll
    for (int off=8; off; off>>=1) ss += __shfl_xor(ss, off, 64);
    const float rs = rsqrtf(ss*(1.0f/64.0f) + 1e-6f);
    u16x4 pk;
    pk[0]=f2bf(v.x*rs); pk[1]=f2bf(v.y*rs); pk[2]=f2bf(v.z*rs); pk[3]=f2bf(v.w*rs);
    *(u16x4*)(hat + (size_t)row*64 + l*4) = pk;
  } else if (bid < 5632){
    int idx = (bid - 4608)*256 + t;      // 262144 float4 = out_edge init
    oe[idx] = e[idx];
  } else if (bid < 7680){
    __shared__ float ar[128];
    __shared__ float sred[2];
    const int c2 = bid - 5632;               // 0..2047
    const int row = c2 >> 4;                 // 0..127
    const int c = c2 & 15;                   // chunk
    float x = 0.f;
    if (t < 128) x = node[row*128 + t];
    float s = waveSum(x*x);
    if (t < 128 && (t & 63) == 0) sred[t>>6] = s;
    __syncthreads();
    float rs = rsqrtf((sred[0]+sred[1])*(1.0f/128.0f) + 1e-6f);
    if (t < 128) ar[t] = x * rs * nw[t];
    __syncthreads();
    if (t < 128){
      const float* B = (c < 8) ? Ba : Bb;
      float* C = (c < 8) ? Ca : Cb;
      const int cc = c & 7, half = cc >> 2, sub = cc & 3;
      const int brow = 128 + half*128;
      const int col = sub*128 + t;
      float acc = 0.f;
      for (int k=0;k<128;k++) acc = fmaf(ar[k], B[(size_t)(brow+k)*512 + col], acc);
      C[(size_t)row*1024 + half*512 + col] = acc;
    }
  } else if (bid < 8448){
    // blk1 enc_aug: rmsnorm(edge_in) + node append -> enca[3072][256]
    int row = (bid - 7680)*4 + (t >> 6);   // 0..3071
    int lane = t & 63;
    int loc = row/24;
    int src = loc*64 + (row - loc*24);
    float2 v = *(const float2*)(edge_in + (size_t)src*128 + lane*2);
    float ss = waveSum(v.x*v.x + v.y*v.y);
    float rs = rsqrtf(ss*(1.0f/128.0f) + 1e-6f);
    float2 wv = *(const float2*)(la_ne + lane*2);
    u32 pk = (u32)f2bf(v.x*rs*wv.x) | ((u32)f2bf(v.y*rs*wv.y) << 16);
    *(u32*)(enca + (size_t)row*256 + lane*2) = pk;
    float2 nv = *(const float2*)(node + loc*128 + lane*2);
    u32 pn = (u32)f2bf(nv.x) | ((u32)f2bf(nv.y) << 16);
    *(u32*)(enca + (size_t)row*256 + 128 + lane*2) = pn;
  } else {
    // weight-transpose jobs
    const int jb = bid - 8448;               // 0..1471
    const WtJob J = P.j[jb >> 6];
    const int inner = jb & 63;
    const int ks = 1 << J.kslog;
    const int total = J.C << J.kslog;
    for (int idx = inner*256 + t; idx < total; idx += 64*256){
      int c = idx >> J.kslog, k = idx & (ks-1);
      float s = J.scale ? J.scale[k] : 1.0f;
      J.dst[((size_t)(J.c0 + c) << J.dlog) + J.k0 + k] =
          f2bf(J.src[(size_t)(J.row0 + k)*J.src_ld + c] * s);
    }
  }
}

// compact rmsnorm + node append (blk3 only): enc_aug[3072][256] = [e_n bf16 | node bf16]
__global__ void rmsnorm128c_aug_kernel(const float* __restrict__ x, const float* __restrict__ w,
                                       const float* __restrict__ node, u16* __restrict__ out){
  int row = blockIdx.x*4 + (threadIdx.x >> 6);   // 0..3071
  int lane = threadIdx.x & 63;
  int loc = row/24;
  int src = loc*64 + (row - loc*24);
  float2 v = *(const float2*)(x + (size_t)src*128 + lane*2);
  float ss = waveSum(v.x*v.x + v.y*v.y);
  float rs = rsqrtf(ss*(1.0f/128.0f) + 1e-6f);
  float2 wv = *(const float2*)(w + lane*2);
  u32 pk = (u32)f2bf(v.x*rs*wv.x) | ((u32)f2bf(v.y*rs*wv.y) << 16);
  *(u32*)(out + (size_t)row*256 + lane*2) = pk;
  float2 nv = *(const float2*)(node + loc*128 + lane*2);
  u32 pn = (u32)f2bf(nv.x) | ((u32)f2bf(nv.y) << 16);
  *(u32*)(out + (size_t)row*256 + 128 + lane*2) = pn;
}

// fused blk2 node-add + blk4 npr table
__global__ __launch_bounds__(128) void node_add_gemm2_kernel(
    const float* __restrict__ node_in, const float* __restrict__ partial,
    float* __restrict__ node_out, const float* __restrict__ nw,
    const float* __restrict__ B, float* __restrict__ C){
  __shared__ float ar[128];
  __shared__ float sred[2];
  const int row = blockIdx.x, t = threadIdx.x;
  float x = node_in[row*128 + t]
          + (partial[(4*row)*128+t] + partial[(4*row+1)*128+t]
           + partial[(4*row+2)*128+t] + partial[(4*row+3)*128+t]);
  if (blockIdx.y == 0) node_out[row*128 + t] = x;
  float s = waveSum(x*x);
  if ((t & 63) == 0) sred[t>>6] = s;
  __syncthreads();
  float rs = rsqrtf((sred[0]+sred[1])*(1.0f/128.0f) + 1e-6f);
  ar[t] = x * rs * nw[t];
  __syncthreads();
  const int c = blockIdx.y;
  const int half = c >> 2, sub = c & 3;
  const int brow = 128 + half*128;
  const int col = sub*128 + t;
  float acc = 0.f;
  for (int k=0;k<128;k++) acc = fmaf(ar[k], B[(size_t)(brow+k)*512 + col], acc);
  C[(size_t)row*1024 + half*512 + col] = acc;
}

// ---------------- dual MFMA GEMM ----------------
__global__ __launch_bounds__(256) void gemm2_bf16_kernel(
    const u16* __restrict__ A, int lda,
    const u16* __restrict__ Bt0, u16* __restrict__ C0, int N0, int K0, int ny0,
    const u16* __restrict__ Bt1, u16* __restrict__ C1, int N1, int K1){
  __shared__ float cl[32*128];
  const int lane = threadIdx.x & 63, wave = threadIdx.x >> 6;
  const int job1 = ((int)blockIdx.y >= ny0);
  const u16* Bt = job1 ? Bt1 : Bt0;
  u16* C = job1 ? C1 : C0;
  const int N = job1 ? N1 : N0;
  const int K = job1 ? K1 : K0;
  const int by = job1 ? ((int)blockIdx.y - ny0) : (int)blockIdx.y;
  const size_t arow = (size_t)blockIdx.x*32;
  const size_t bcol = (size_t)by*128 + wave*32;
  f32x4 acc00={0,0,0,0}, acc01={0,0,0,0}, acc10={0,0,0,0}, acc11={0,0,0,0};
  for (int k=0; k<K; k+=32){
    int ko = k + (lane>>4)*8;
    bf16x8 a0 = *(const bf16x8*)(A + (arow + (lane&15))*lda + ko);
    bf16x8 a1 = *(const bf16x8*)(A + (arow + 16 + (lane&15))*lda + ko);
    bf16x8 b0 = *(const bf16x8*)(Bt + (bcol + (lane&15))*K + ko);
    bf16x8 b1 = *(const bf16x8*)(Bt + (bcol + 16 + (lane&15))*K + ko);
    acc00 = __builtin_amdgcn_mfma_f32_16x16x32_bf16(a0, b0, acc00, 0,0,0);
    acc01 = __builtin_amdgcn_mfma_f32_16x16x32_bf16(a0, b1, acc01, 0,0,0);
    acc10 = __builtin_amdgcn_mfma_f32_16x16x32_bf16(a1, b0, acc10, 0,0,0);
    acc11 = __builtin_amdgcn_mfma_f32_16x16x32_bf16(a1, b1, acc11, 0,0,0);
  }
  const int cr = (lane>>4)*4, cc = wave*32 + (lane&15);
#pragma unroll
  for (int q=0;q<4;q++){
    cl[(cr+q)*128 + cc]      = acc00[q];
    cl[(cr+q)*128 + cc+16]   = acc01[q];
    cl[(16+cr+q)*128 + cc]    = acc10[q];
    cl[(16+cr+q)*128 + cc+16] = acc11[q];
  }
  __syncthreads();
  const int t = threadIdx.x;
#pragma unroll
  for (int i=0;i<16;i++){
    int idx = i*256 + t; int r = idx>>7, c = idx&127;
    int gcol = by*128 + c;
    C[(arow + r)*(size_t)N + cperm<1>(gcol)] = f2bf(cl[idx]);
  }
}

// ---------------- fused angle kernel v11 (proven, linear vgn) ----------------
template<bool IS_BLK1>
__global__ __launch_bounds__(512, 4) void angle11_kernel(
    const u16* __restrict__ hat, const u16* __restrict__ preE, const u16* __restrict__ preK,
    const u16* __restrict__ wangT, const u16* __restrict__ woT,
    const float* __restrict__ angle,
    const float* __restrict__ rbf, const float* __restrict__ envW,
    const float* __restrict__ a_sw,
    const u16* __restrict__ aprojTb, const float* __restrict__ eproj,
    float* __restrict__ edge_out, float* __restrict__ angle_out)
{
  constexpr int HW = IS_BLK1 ? 640 : 512;
  constexpr int VGN_B  = 48*264*2;
  constexpr int GATE_O = VGN_B;
  constexpr int SS_O   = GATE_O + (IS_BLK1 ? 48*132*2 : 0);
  constexpr int RS_O   = SS_O + 8*48*4;
  constexpr int SEG_O  = RS_O + 192;
  constexpr int RBF_O  = SEG_O + (IS_BLK1 ? 0 : 1024);
  constexpr int LDS_B  = RBF_O + (IS_BLK1 ? 0 : 1152);
  __shared__ __align__(16) char ldsRaw[LDS_B];
  u16*   vgn    = (u16*)ldsRaw;
  u16*   gateLb = (u16*)(ldsRaw + GATE_O);
  float* ssL    = (float*)(ldsRaw + SS_O);
  float* rsL    = (float*)(ldsRaw + RS_O);
  float* segL   = (float*)(ldsRaw + SEG_O);
  float* rbfL   = (float*)(ldsRaw + RBF_O);
  float* msgL   = (float*)ldsRaw;

  const int t = threadIdx.x, lane = t & 63, w = t >> 6;
  const int l15 = lane & 15, l4 = lane >> 4;
  const int b = blockIdx.x;
  const int xcd = b & 7, idx = b >> 3;
  const int loc = xcd*16 + idx/12;
  const int j0 = (idx - (idx/12)*12)*2;
  const int s0 = loc*24 + j0;
  const int hbase = s0*24;
  const int oc = 16*w + l15;

  if constexpr (!IS_BLK1){
    if (t < 288) rbfL[t] = rbf[(size_t)(loc*64)*12 + t];
  }

  u16x8 pk[3][2], pe[3][2];
  u16x4 pkg[3], peg[3];
#pragma unroll
  for (int nt=0; nt<3; nt++){
    const int r = nt*16 + l15;
    const int hi = (r >= 24);
    const int rr = r - 24*hi;
    const u16* pK = preK + (size_t)(loc*24 + rr)*HW;
    const u16* pE = preE + (size_t)(s0 + hi)*HW;
#pragma unroll
    for (int i=0;i<2;i++){
      const int a = (2*w + i)*4 + l4;
      pk[nt][i] = *(const u16x8*)(pK + a*8);
      pe[nt][i] = *(const u16x8*)(pE + a*8);
    }
    if constexpr (IS_BLK1){
      const int cg = 512 + w*16 + l4*4;
      pkg[nt] = *(const u16x4*)(pK + cg);
      peg[nt] = *(const u16x4*)(pE + cg);
    }
  }

  f32x4 accv[3][2], accg[3][2], accgate[3];
#pragma unroll
  for (int nt=0;nt<3;nt++){
    accv[nt][0]=(f32x4){0,0,0,0}; accv[nt][1]=(f32x4){0,0,0,0};
    accg[nt][0]=(f32x4){0,0,0,0}; accg[nt][1]=(f32x4){0,0,0,0};
    accgate[nt]=(f32x4){0,0,0,0};
  }
#pragma unroll
  for (int kk=0; kk<2; kk++){
    const int ko = kk*32 + l4*8;
    bf16x8 bb[3];
#pragma unroll
    for (int nt=0;nt<3;nt++)
      bb[nt] = *(const bf16x8*)(hat + (size_t)(hbase + nt*16 + l15)*64 + ko);
#pragma unroll
    for (int i=0;i<2;i++){
      const int chv = (2*w + i)*16 + l15;
      bf16x8 av = *(const bf16x8*)(wangT + (size_t)chv*64 + ko);
      bf16x8 ag = *(const bf16x8*)(wangT + (size_t)(256 + chv)*64 + ko);
#pragma unroll
      for (int nt=0;nt<3;nt++){
        accv[nt][i] = __builtin_amdgcn_mfma_f32_16x16x32_bf16(av, bb[nt], accv[nt][i], 0,0,0);
        accg[nt][i] = __builtin_amdgcn_mfma_f32_16x16x32_bf16(ag, bb[nt], accg[nt][i], 0,0,0);
      }
    }
    if constexpr (IS_BLK1){
      bf16x8 aga = *(const bf16x8*)(wangT + (size_t)(512 + w*16 + l15)*64 + ko);
#pragma unroll
      for (int nt=0;nt<3;nt++)
        accgate[nt] = __builtin_amdgcn_mfma_f32_16x16x32_bf16(aga, bb[nt], accgate[nt], 0,0,0);
    }
  }

  float ssr[3] = {0.f, 0.f, 0.f};
#pragma unroll
  for (int nt=0; nt<3; nt++){
    const int r = nt*16 + l15;
#pragma unroll
    for (int i=0;i<2;i++){
      const int cb = (2*w + i)*16 + l4*4;
      u16x4 xs;
#pragma unroll
      for (int q=0;q<4;q++){
        float v = accv[nt][i][q] + bf2f(pk[nt][i][q])   + bf2f(pe[nt][i][q]);
        float g = accg[nt][i][q] + bf2f(pk[nt][i][4+q]) + bf2f(pe[nt][i][4+q]);
        float x = v * silu(g);
        ssr[nt] += x*x;
        xs[q] = f2bf(x);
      }
      *(u16x4*)&vgn[r*264 + cb] = xs;
    }
    if constexpr (IS_BLK1){
      u16x4 gs;
#pragma unroll
      for (int q=0;q<4;q++)
        gs[q] = f2bf((accgate[nt][q] + bf2f(pkg[nt][q]) + bf2f(peg[nt][q])) * A_SCALE_C);
      *(u16x4*)&gateLb[r*132 + w*16 + l4*4] = gs;
    }
  }
#pragma unroll
  for (int nt=0;nt<3;nt++){
    float s = ssr[nt];
    s += __shfl_xor(s,16,64); s += __shfl_xor(s,32,64);
    if (l4 == 0) ssL[w*48 + nt*16 + l15] = s;
  }
  bf16x8 bwp[8];
#pragma unroll
  for (int kk=0; kk<8; kk++)
    bwp[kk] = *(const bf16x8*)(woT + (size_t)oc*256 + kk*32 + l4*8);
  __syncthreads();                    // sync1
  if (t < 48){
    float s_ = 0.f;
#pragma unroll
    for (int k=0;k<8;k++) s_ += ssL[k*48 + t];
    rsL[t] = rsqrtf(s_*(1.0f/256.0f) + 1e-6f);
  }

  f32x4 mac[3];
#pragma unroll
  for (int m=0;m<3;m++) mac[m] = (f32x4){0,0,0,0};
#pragma unroll
  for (int kk=0; kk<8; kk++){
#pragma unroll
    for (int m=0;m<3;m++){
      bf16x8 aw = *(const bf16x8*)&vgn[(m*16 + l15)*264 + kk*32 + l4*8];
      mac[m] = __builtin_amdgcn_mfma_f32_16x16x32_bf16(aw, bwp[kk], mac[m], 0,0,0);
    }
  }
  __syncthreads();                    // sync2
  float rsv[3][4];
#pragma unroll
  for (int m=0;m<3;m++)
#pragma unroll
    for (int q=0;q<4;q++) rsv[m][q] = rsL[m*16 + l4*4 + q];
#pragma unroll
  for (int m=0;m<3;m++)
#pragma unroll
    for (int q=0;q<4;q++)
      msgL[(m*16 + l4*4 + q)*132 + 16*w + l15] = mac[m][q] * rsv[m][q];
  __syncthreads();                    // sync3

  if constexpr (IS_BLK1){
    if (t < 256){
      int s = t>>7, c = t&127;
      float ex[24]; float mx = -1e30f;
#pragma unroll
      for (int k=0;k<24;k++){ ex[k] = bf2f(gateLb[(s*24+k)*132 + c]); mx = fmaxf(mx, ex[k]); }
      float S = 0.f;
#pragma unroll
      for (int k=0;k<24;k++){ ex[k] = __expf(ex[k] - mx); S += ex[k]; }
      float inv = 1.f/(S + 1e-12f);
      float delta = 0.f;
#pragma unroll
      for (int k=0;k<24;k++) delta += msgL[(s*24+k)*132 + c] * ex[k];
      edge_out[(size_t)(loc*64 + j0 + s)*128 + c] += delta * inv;
    }
  } else {
    if (t < 256){
      int s = t>>7, c = t&127;
      float envR[12];
#pragma unroll
      for (int j=0;j<12;j++) envR[j] = envW[j*128 + c];
      float sg_ = 0.f;
#pragma unroll
      for (int k=0;k<24;k++){
        float envC = 0.f;
#pragma unroll
        for (int j=0;j<12;j++) envC = fmaf(rbfL[k*12 + j], envR[j], envC);
        sg_ += msgL[(s*24+k)*132 + c] * envC * a_sw[(size_t)(s0+s)*24 + k];
      }
      segL[s*128 + c] = sg_;
    }
    for (int p = w; p < 12; p += 8){
      const int mt = p >> 2, ntc = p & 3;
      f32x4 am = (f32x4){0,0,0,0};
#pragma unroll
      for (int kk=0; kk<4; kk++){
        const float* mrow = &msgL[(mt*16 + l15)*132 + kk*32 + l4*8];
        bf16x8 a;
#pragma unroll
        for (int e=0;e<8;e++) a[e] = (short)f2bf(mrow[e]);
        bf16x8 bb = *(const bf16x8*)(aprojTb + (size_t)(ntc*16 + l15)*128 + kk*32 + l4*8);
        am = __builtin_amdgcn_mfma_f32_16x16x32_bf16(a, bb, am, 0,0,0);
      }
#pragma unroll
      for (int q=0;q<4;q++){
        int row = mt*16 + l4*4 + q;
        size_t a_ = (size_t)hbase + row;
        int col = ntc*16 + l15;
        angle_out[a_*64 + col] = angle[a_*64 + col] + am[q] * a_sw[a_];
      }
    }
    __syncthreads();
    if (t < 256){
      int s = t>>7, c = t&127;
      float acc2 = 0.f;
      for (int dd=0; dd<128; dd++) acc2 = fmaf(segL[s*128 + dd], eproj[dd*128 + c], acc2);
      edge_out[(size_t)(loc*64 + j0 + s)*128 + c] += acc2 * A_SCALE_C;
    }
  }
}

// ---------------- scores v4: inline rmsnorm + MFMA gate + 2-way parallel softmax ----------------
__global__ __launch_bounds__(256) void scores3_kernel(const float* __restrict__ edge_src,
                                                      const float* __restrict__ norm_e,
                                                      const u16* __restrict__ gateT,
                                                      float* __restrict__ scores){
  __shared__ float s[64*132];
  __shared__ float red[2][128];
  const int t = threadIdx.x, lane = t & 63, w = t >> 6;
  const int l15 = lane & 15, l4 = lane >> 4;
  const int n = blockIdx.x;
  const int row = n*64 + w*16 + l15;
  bf16x8 bfr[4];
  row_rms_frag(edge_src + (size_t)row*128, norm_e, l4, bfr);
  f32x4 acc[8];
#pragma unroll
  for (int j=0;j<8;j++) acc[j] = (f32x4){0,0,0,0};
#pragma unroll
  for (int kk=0; kk<4; kk++){
    const int ko = kk*32 + l4*8;
#pragma unroll
    for (int j=0;j<8;j++){
      bf16x8 b = *(const bf16x8*)(gateT + (size_t)(j*16 + l15)*128 + ko);
      acc[j] = __builtin_amdgcn_mfma_f32_16x16x32_bf16(bfr[kk], b, acc[j], 0,0,0);
    }
  }
#pragma unroll
  for (int j=0;j<8;j++)
#pragma unroll
    for (int q=0;q<4;q++)
      s[(w*16 + l4*4 + q)*132 + j*16 + l15] = acc[j][q] * E_SCALE_C;
  __syncthreads();
  {
    const int c = t & 127, h = t >> 7;
    const int r0 = h*32;
    float m = -1e30f;
    for (int r=r0; r<r0+32; r++) m = fmaxf(m, s[r*132 + c]);
    red[h][c] = m;
    __syncthreads();
    m = fmaxf(red[0][c], red[1][c]);
    __syncthreads();
    float S = 0.f;
    for (int r=r0; r<r0+32; r++) S += __expf(s[r*132 + c] - m);
    red[h][c] = S;
    __syncthreads();
    S = red[0][c] + red[1][c];
    float inv = 1.f/(S + 1e-12f);
    for (int r=r0; r<r0+32; r++)
      scores[(size_t)(n*64 + r)*128 + c] = __expf(s[r*132 + c] - m) * inv;
  }
}

// ---------------- combined blk2 edge kernel (inline rmsnorm) ----------------
__global__ __launch_bounds__(256) void edge_fused01_kernel(
    const float* __restrict__ edge_src,
    const float* __restrict__ norm_e,
    const float* __restrict__ NPa, const float* __restrict__ NPe,
    const int* __restrict__ next2e,
    const u16* __restrict__ aaWT, const u16* __restrict__ aeWT,
    const u16* __restrict__ woaaT, const u16* __restrict__ woaeT,
    const float* __restrict__ scores,
    float* __restrict__ edge_out, float* __restrict__ partial){
  __shared__ __align__(16) char lds[13184];
  u16*   vgn  = (u16*)lds;
  float* msgF = (float*)lds;
  float* ssP  = (float*)(lds + 12800);
  float* rsL  = (float*)(lds + 13056);
  const int t = threadIdx.x, lane = t & 63, w = t >> 6;
  const int l15 = lane & 15, l4 = lane >> 4;
  const int g = blockIdx.x, e0 = g*16, n = e0 >> 6;
  const int nx = next2e[e0 + l15];

  bf16x8 bfr[4];
  row_rms_frag(edge_src + (size_t)(e0 + l15)*128, norm_e, l4, bfr);

#pragma unroll
  for (int path=0; path<2; path++){
    const u16* wT  = path ? aeWT : aaWT;
    const u16* woT = path ? woaeT : woaaT;
    const float* NPt = path ? NPe : NPa;

    f32x4 av4[4], ag4[4];
#pragma unroll
    for (int i=0;i<4;i++){ av4[i]=(f32x4){0,0,0,0}; ag4[i]=(f32x4){0,0,0,0}; }
#pragma unroll
    for (int kk=0; kk<4; kk++){
      const int ko = kk*32 + l4*8;
#pragma unroll
      for (int i=0;i<4;i++){
        const int chr = w*64 + i*16 + l15;
        bf16x8 wv = *(const bf16x8*)(wT + (size_t)chr*128 + ko);
        bf16x8 wg = *(const bf16x8*)(wT + (size_t)(256 + chr)*128 + ko);
        av4[i] = __builtin_amdgcn_mfma_f32_16x16x32_bf16(wv, bfr[kk], av4[i], 0,0,0);
        ag4[i] = __builtin_amdgcn_mfma_f32_16x16x32_bf16(wg, bfr[kk], ag4[i], 0,0,0);
      }
    }

    float ssr = 0.f;
#pragma unroll
    for (int i=0;i<4;i++){
      const int cb = w*64 + i*16 + l4*4;
      float4 sv = *(const float4*)(NPt + n*1024 + cb);
      float4 sg = *(const float4*)(NPt + n*1024 + 256 + cb);
      float4 nv = *(const float4*)(NPt + (size_t)nx*1024 + 512 + cb);
      float4 ng = *(const float4*)(NPt + (size_t)nx*1024 + 768 + cb);
      u16x4 xs;
#pragma unroll
      for (int q=0;q<4;q++){
        float v  = av4[i][q] + ((const float*)&sv)[q] + ((const float*)&nv)[q];
        float gg = ag4[i][q] + ((const float*)&sg)[q] + ((const float*)&ng)[q];
        float x = v * silu(gg);
        ssr += x*x;
        xs[q] = f2bf(x);
      }
      *(u16x4*)&vgn[l15*264 + cb] = xs;
    }
    {
      float s = ssr;
      s += __shfl_xor(s,16,64); s += __shfl_xor(s,32,64);
      if (l4 == 0) ssP[l15*4 + w] = s;
    }
    __syncthreads();
    if (t < 16)
      rsL[t] = rsqrtf((ssP[t*4]+ssP[t*4+1]+ssP[t*4+2]+ssP[t*4+3])*(1.0f/256.0f) + 1e-6f);
    __syncthreads();
    f32x4 mac[2] = {(f32x4){0,0,0,0}, (f32x4){0,0,0,0}};
#pragma unroll
    for (int kk=0; kk<8; kk++){
      bf16x8 a = *(const bf16x8*)&vgn[l15*264 + kk*32 + l4*8];
#pragma unroll
      for (int nt=0; nt<2; nt++){
        bf16x8 bw = *(const bf16x8*)(woT + (size_t)(32*w + nt*16 + l15)*256 + kk*32 + l4*8);
        mac[nt] = __builtin_amdgcn_mfma_f32_16x16x32_bf16(a, bw, mac[nt], 0,0,0);
      }
    }
    float rsv[4];
#pragma unroll
    for (int q=0;q<4;q++) rsv[q] = rsL[l4*4 + q];
    __syncthreads();
#pragma unroll
    for (int nt=0; nt<2; nt++)
#pragma unroll
      for (int q=0;q<4;q++)
        msgF[(l4*4 + q)*132 + 32*w + nt*16 + l15] = mac[nt][q] * rsv[q];
    __syncthreads();

    if (path == 0){
      if (t < 128){
        float p = 0.f;
#pragma unroll
        for (int r=0;r<16;r++) p += msgF[r*132 + t] * scores[(size_t)(e0+r)*128 + t];
        partial[g*128 + t] = p;
      }
    } else {
      const int d = t & 127, rg = (t >> 7) * 8;
#pragma unroll
      for (int i=0;i<8;i++)
        edge_out[(size_t)(e0+rg+i)*128 + d] += msgF[(rg+i)*132 + d];
    }
    __syncthreads();
  }
}

// ---------------- blk4 edge kernel: MODE2 with fused rmsnorm ----------------
__global__ __launch_bounds__(256) void edge_fused2m2_kernel(
    const float* __restrict__ edge_src,
    const float* __restrict__ norm_e,
    const float* __restrict__ NPt,
    const int* __restrict__ next2e,
    const u16* __restrict__ wT,
    const u16* __restrict__ woT,
    const float* __restrict__ rbf, const float* __restrict__ envW,
    const float* __restrict__ sw, const u16* __restrict__ eprojT,
    float* __restrict__ edge_out, float* __restrict__ partial){
  __shared__ __align__(16) char lds[20096];
  u16*   vgn  = (u16*)lds;
  float* msgF = (float*)lds;
  u16*   msgB = (u16*)(lds + 8448);
  float* ssP  = (float*)(lds + 12800);
  float* rsL  = (float*)(lds + 13056);
  float* envWL= (float*)(lds + 13184);
  float* rbfL = (float*)(lds + 19328);
  const int t = threadIdx.x, lane = t & 63, w = t >> 6;
  const int l15 = lane & 15, l4 = lane >> 4;
  const int g = blockIdx.x, e0 = g*16, n = e0 >> 6;
  const int nx = next2e[e0 + l15];
  for (int i=t; i<12*128; i+=256) envWL[i] = envW[i];
  if (t < 192) rbfL[t] = rbf[(size_t)e0*12 + t];

  bf16x8 bfr[4];
  row_rms_frag(edge_src + (size_t)(e0 + l15)*128, norm_e, l4, bfr);

  float4 sv[4], sg[4], nv[4], ng[4];
#pragma unroll
  for (int i=0;i<4;i++){
    const int cb = w*64 + i*16 + l4*4;
    sv[i] = *(const float4*)(NPt + n*1024 + cb);
    sg[i] = *(const float4*)(NPt + n*1024 + 256 + cb);
    nv[i] = *(const float4*)(NPt + (size_t)nx*1024 + 512 + cb);
    ng[i] = *(const float4*)(NPt + (size_t)nx*1024 + 768 + cb);
  }

  f32x4 av4[4], ag4[4];
#pragma unroll
  for (int i=0;i<4;i++){ av4[i]=(f32x4){0,0,0,0}; ag4[i]=(f32x4){0,0,0,0}; }
#pragma unroll
  for (int kk=0; kk<4; kk++){
    const int ko = kk*32 + l4*8;
#pragma unroll
    for (int i=0;i<4;i++){
      const int chr = w*64 + i*16 + l15;
      bf16x8 wv = *(const bf16x8*)(wT + (size_t)chr*128 + ko);
      bf16x8 wg = *(const bf16x8*)(wT + (size_t)(256 + chr)*128 + ko);
      av4[i] = __builtin_amdgcn_mfma_f32_16x16x32_bf16(wv, bfr[kk], av4[i], 0,0,0);
      ag4[i] = __builtin_amdgcn_mfma_f32_16x16x32_bf16(wg, bfr[kk], ag4[i], 0,0,0);
    }
  }

  float ssr = 0.f;
#pragma unroll
  for (int i=0;i<4;i++){
    const int cb = w*64 + i*16 + l4*4;
    u16x4 xs;
#pragma unroll
    for (int q=0;q<4;q++){
      float v = av4[i][q] + ((const float*)&sv[i])[q] + ((const float*)&nv[i])[q];
      float gg = ag4[i][q] + ((const float*)&sg[i])[q] + ((const float*)&ng[i])[q];
      float x = v * silu(gg);
      ssr += x*x;
      xs[q] = f2bf(x);
    }
    *(u16x4*)&vgn[l15*264 + cb] = xs;
  }
  {
    float s = ssr;
    s += __shfl_xor(s,16,64); s += __shfl_xor(s,32,64);
    if (l4 == 0) ssP[l15*4 + w] = s;
  }
  __syncthreads();
  if (t < 16)
    rsL[t] = rsqrtf((ssP[t*4]+ssP[t*4+1]+ssP[t*4+2]+ssP[t*4+3])*(1.0f/256.0f) + 1e-6f);
  __syncthreads();
  f32x4 mac[2] = {(f32x4){0,0,0,0}, (f32x4){0,0,0,0}};
#pragma unroll
  for (int kk=0; kk<8; kk++){
    bf16x8 a = *(const bf16x8*)&vgn[l15*264 + kk*32 + l4*8];
#pragma unroll
    for (int nt=0; nt<2; nt++){
      bf16x8 bw = *(const bf16x8*)(woT + (size_t)(32*w + nt*16 + l15)*256 + kk*32 + l4*8);
      mac[nt] = __builtin_amdgcn_mfma_f32_16x16x32_bf16(a, bw, mac[nt], 0,0,0);
    }
  }
  float rsv[4];
#pragma unroll
  for (int q=0;q<4;q++) rsv[q] = rsL[l4*4 + q];
  __syncthreads();
#pragma unroll
  for (int nt=0; nt<2; nt++)
#pragma unroll
    for (int q=0;q<4;q++){
      float val = mac[nt][q] * rsv[q];
      int row = l4*4 + q, col = 32*w + nt*16 + l15;
      msgF[row*132 + col] = val;
      msgB[row*136 + col] = f2bf(val);
    }
  __syncthreads();

  f32x4 em[2] = {(f32x4){0,0,0,0}, (f32x4){0,0,0,0}};
#pragma unroll
  for (int kk=0; kk<4; kk++){
    bf16x8 a = *(const bf16x8*)&msgB[l15*136 + kk*32 + l4*8];
#pragma unroll
    for (int nt=0; nt<2; nt++){
      bf16x8 bw = *(const bf16x8*)(eprojT + (size_t)(32*w + nt*16 + l15)*128 + kk*32 + l4*8);
      em[nt] = __builtin_amdgcn_mfma_f32_16x16x32_bf16(a, bw, em[nt], 0,0,0);
    }
  }
#pragma unroll
  for (int nt=0; nt<2; nt++)
#pragma unroll
    for (int q=0;q<4;q++)
      edge_out[(size_t)(e0 + l4*4 + q)*128 + 32*w + nt*16 + l15] += em[nt][q];
  if (t < 128){
    float p = 0.f;
#pragma unroll
    for (int r=0;r<16;r++){
      float envC = 0.f;
#pragma unroll
      for (int j=0;j<12;j++) envC = fmaf(rbfL[r*12 + j], envWL[j*128 + t], envC);
      p += msgF[r*132 + t] * envC * sw[e0 + r];
    }
    partial[g*128 + t] = p;
  }
}

__global__ void node_final4_kernel(const float* __restrict__ partial,
                                   const float* __restrict__ nproj,
                                   float* __restrict__ node_out){
  __shared__ float seg[128];
  int n = blockIdx.x, t = threadIdx.x;
  seg[t] = partial[(4*n)*128+t] + partial[(4*n+1)*128+t]
         + partial[(4*n+2)*128+t] + partial[(4*n+3)*128+t];
  __syncthreads();
  float acc = 0.f;
  for (int dd=0; dd<128; dd++) acc = fmaf(seg[dd], nproj[dd*128 + t], acc);
  node_out[n*128 + t] += acc * E_SCALE_C;
}

// ---------------- launch ----------------
extern "C" void kernel_launch(void* const* d_in, const int* in_sizes, int n_in,
                              void* d_out, int out_size, void* d_ws, size_t ws_size,
                              hipStream_t stream){
  const float* node_in  = (const float*)d_in[0];
  const float* edge_in  = (const float*)d_in[1];
  const float* angle_in = (const float*)d_in[2];
  const float* sw       = (const float*)d_in[3];
  const float* a_sw     = (const float*)d_in[4];
  const float* rbf      = (const float*)d_in[5];
  const int*   edge_index = (const int*)d_in[6];
  const float* la_norm_e = (const float*)d_in[8];
  const float* la_norm_a = (const float*)d_in[9];
  const float* la_win    = (const float*)d_in[10];
  const float* la_nw     = (const float*)d_in[11];
  const float* la_wout   = (const float*)d_in[12];
  const float* la_gate   = (const float*)d_in[13];
  const float* aa_norm_n = (const float*)d_in[14];
  const float* aa_norm_e = (const float*)d_in[15];
  const float* aa_win    = (const float*)d_in[16];
  const float* aa_nw     = (const float*)d_in[17];
  const float* aa_wout   = (const float*)d_in[18];
  const float* aa_src_gate = (const float*)d_in[19];
  const float* ae_win    = (const float*)d_in[20];
  const float* ae_nw     = (const float*)d_in[21];
  const float* ae_wout   = (const float*)d_in[22];
  const float* lr_norm_e = (const float*)d_in[23];
  const float* lr_norm_a = (const float*)d_in[24];
  const float* lr_win    = (const float*)d_in[25];
  const float* lr_nw     = (const float*)d_in[26];
  const float* lr_wout   = (const float*)d_in[27];
  const float* lr_env    = (const float*)d_in[28];
  const float* lr_eproj  = (const float*)d_in[29];
  const float* lr_aproj  = (const float*)d_in[30];
  const float* ar_norm_n = (const float*)d_in[31];
  const float* ar_norm_e = (const float*)d_in[32];
  const float* ar_win    = (const float*)d_in[33];
  const float* ar_nw     = (const float*)d_in[34];
  const float* ar_wout   = (const float*)d_in[35];
  const float* ar_env    = (const float*)d_in[36];
  const float* ar_nproj  = (const float*)d_in[37];
  const float* ar_eproj  = (const float*)d_in[38];

  float* out_node  = (float*)d_out;
  float* out_edge  = out_node + 128*128;
  float* out_angle = out_edge + (size_t)8192*128;

  float* p = (float*)d_ws;
  float* hat_f   = p; p += 2359296;
  float* enca_f  = p; p += 393216;
  float* preE_f  = p; p += 983040;
  float* preK_f  = p; p += 983040;
  float* wang1_f = p; p += 20480;
  float* wang3_f = p; p += 16384;
  float* wij1_f  = p; p += 40960;
  float* wij3_f  = p; p += 32768;
  float* wik1_f  = p; p += 81920;
  float* wik3_f  = p; p += 65536;
  float* wo1T_f  = p; p += 16384;
  float* wo3T_f  = p; p += 16384;
  float* whe2_f  = p; p += 73728;
  float* whe4_f  = p; p += 32768;
  float* woaaT_f = p; p += 16384;
  float* woaeT_f = p; p += 16384;
  float* woarT_f = p; p += 16384;
  float* eprjT_f = p; p += 8192;
  float* aprjT_f = p; p += 4096;
  float* npa     = p; p += 131072;
  float* npe     = p; p += 131072;
  float* npr     = p; p += 131072;
  float* scores2 = p; p += 1048576;
  float* partial = p; p += 65536;

  u16* hat  = (u16*)hat_f;
  u16* enca = (u16*)enca_f;
  u16* preE = (u16*)preE_f;
  u16* preK = (u16*)preK_f;
  u16* wang1= (u16*)wang1_f;
  u16* wang3= (u16*)wang3_f;
  u16* wij1 = (u16*)wij1_f;
  u16* wij3 = (u16*)wij3_f;
  u16* wik1 = (u16*)wik1_f;
  u16* wik3 = (u16*)wik3_f;
  u16* wo1T = (u16*)wo1T_f;
  u16* wo3T = (u16*)wo3T_f;
  u16* whe2 = (u16*)whe2_f;
  u16* whe4 = (u16*)whe4_f;
  u16* woaaT= (u16*)woaaT_f;
  u16* woaeT= (u16*)woaeT_f;
  u16* woarT= (u16*)woarT_f;
  u16* eprjT= (u16*)eprjT_f;
  u16* aprjT= (u16*)aprjT_f;
  u16* aaWT = whe2;
  u16* aeWT = whe2 + 512*128;
  u16* gateT= whe2 + 1024*128;
  u16* arWT = whe4;

  dim3 b512(512), b256(256), b128(128);
  const int* next2e = edge_index + 8192;

  WtJobs jobs;
  int nj = 0;
  auto add = [&](const float* src, const float* scale, u16* dst,
                 int ld, int row0, int c0, int k0, int dlog, int kslog, int C){
    jobs.j[nj++] = WtJob{src, scale, dst, ld, row0, c0, k0, dlog, kslog, C};
  };
  add(la_win, la_norm_a, wang1, 512, 0,   0,   0,   6, 6, 512);
  add(la_gate,la_norm_a, wang1, 128, 0,   512, 0,   6, 6, 128);
  add(la_win, nullptr,   wij1,  512, 192, 0,   0,   7, 7, 512);
  add(la_gate,nullptr,   wij1,  128, 192, 512, 0,   7, 7, 128);
  add(la_win, nullptr,   wik1,  512, 320, 0,   0,   8, 7, 512);
  add(la_gate,nullptr,   wik1,  128, 320, 512, 0,   8, 7, 128);
  add(la_win, nullptr,   wik1,  512, 64,  0,   128, 8, 7, 512);
  add(la_gate,nullptr,   wik1,  128, 64,  512, 128, 8, 7, 128);
  add(la_wout,la_nw,     wo1T,  128, 0,   0,   0,   8, 8, 128);
  add(lr_win, lr_norm_a, wang3, 512, 0,   0,   0,   6, 6, 512);
  add(lr_win, nullptr,   wij3,  512, 192, 0,   0,   7, 7, 512);
  add(lr_win, nullptr,   wik3,  512, 320, 0,   0,   8, 7, 512);
  add(lr_win, nullptr,   wik3,  512, 64,  0,   128, 8, 7, 512);
  add(lr_wout,lr_nw,     wo3T,  128, 0,   0,   0,   8, 8, 128);
  add(aa_win, nullptr,   whe2,  512, 0,   0,   0,   7, 7, 512);
  add(ae_win, nullptr,   whe2,  512, 0,   512, 0,   7, 7, 512);
  add(aa_src_gate,nullptr,whe2, 128, 0,   1024,0,   7, 7, 128);
  add(ar_win, nullptr,   whe4,  512, 0,   0,   0,   7, 7, 512);
  add(aa_wout, aa_nw,    woaaT, 128, 0,   0,   0,   8, 8, 128);
  add(ae_wout, ae_nw,    woaeT, 128, 0,   0,   0,   8, 8, 128);
  add(ar_wout, ar_nw,    woarT, 128, 0,   0,   0,   8, 8, 128);
  add(ar_eproj,nullptr,  eprjT, 128, 0,   0,   0,   7, 7, 128);
  add(lr_aproj,nullptr,  aprjT, 64,  0,   0,   0,   7, 7, 64);

  // mega-prologue: all input-only work (hat, edge copy, npa/npe, blk1 enc_aug, wt jobs)
  prologue_kernel<<<4608 + 1024 + 2048 + 768 + 64*23, b256, 0, stream>>>(jobs,
      angle_in, hat, (const float4*)edge_in, (float4*)out_edge,
      node_in, aa_norm_n, aa_win, npa, ae_win, npe,
      edge_in, la_norm_e, enca);

  // ---- block 1 ----
  gemm2_bf16_kernel<<<dim3(96,10), b256, 0, stream>>>(enca, 256,
      wij1, preE, 640, 128, 5, wik1, preK, 640, 256);
  angle11_kernel<true><<<1536, b512, 0, stream>>>(hat, preE, preK, wang1, wo1T,
      angle_in, nullptr, nullptr, nullptr, nullptr, nullptr, out_edge, nullptr);

  // ---- block 2 (edge rmsnorm fused; node add fused with blk4 npr table) ----
  scores3_kernel<<<128, b256, 0, stream>>>(out_edge, aa_norm_e, gateT, scores2);
  edge_fused01_kernel<<<512, b256, 0, stream>>>(out_edge, aa_norm_e, npa, npe, next2e,
      aaWT, aeWT, woaaT, woaeT, scores2, out_edge, partial);
  node_add_gemm2_kernel<<<dim3(128,8), b128, 0, stream>>>(node_in, partial,
      out_node, ar_norm_n, ar_win, npr);

  // ---- block 3 ----
  rmsnorm128c_aug_kernel<<<768, b256, 0, stream>>>(out_edge, lr_norm_e, out_node, enca);
  gemm2_bf16_kernel<<<dim3(96,8), b256, 0, stream>>>(enca, 256,
      wij3, preE, 512, 128, 4, wik3, preK, 512, 256);
  angle11_kernel<false><<<1536, b512, 0, stream>>>(hat, preE, preK, wang3, wo3T,
      angle_in, rbf, lr_env, a_sw, aprjT, lr_eproj, out_edge, out_angle);

  // ---- block 4 (npr precomputed at blk2) ----
  edge_fused2m2_kernel<<<512, b256, 0, stream>>>(out_edge, ar_norm_e, npr, next2e,
      arWT, woarT, rbf, ar_env, sw, eprjT, out_edge, partial);
  node_final4_kernel<<<128, b128, 0, stream>>>(partial, ar_nproj, out_node);

  (void)in_sizes; (void)n_in; (void)out_size; (void)ws_size;
}

// Round 25
// 245.093 us; speedup vs baseline: 1.0614x; 1.0078x over previous
//
#include <hip/hip_runtime.h>
#include <hip/hip_bf16.h>

#define A_SCALE_C 0.6454972243679028f   // (24/10)^-0.5
#define E_SCALE_C 0.3952847075210474f   // (64/10)^-0.5

typedef unsigned short u16;
typedef unsigned int u32;
typedef __attribute__((ext_vector_type(8))) short bf16x8;
typedef __attribute__((ext_vector_type(4))) float f32x4;
typedef __attribute__((ext_vector_type(4))) unsigned short u16x4;
typedef __attribute__((ext_vector_type(8))) unsigned short u16x8;

static __device__ __forceinline__ float waveSum(float v){
#pragma unroll
  for (int off = 32; off; off >>= 1) v += __shfl_xor(v, off, 64);
  return v;
}
static __device__ __forceinline__ float silu(float g){
  return g / (1.0f + __expf(-g));
}
static __device__ __forceinline__ float bf2f(u16 h){
  union { u32 u; float f; } x; x.u = ((u32)h) << 16; return x.f;
}
static __device__ __forceinline__ u16 f2bf(float f){
  __hip_bfloat16 h = __float2bfloat16(f);
  u16 r; __builtin_memcpy(&r, &h, 2); return r;
}
template<int PERM>
static __device__ __forceinline__ int cperm(int c){
  if constexpr (PERM) return (c < 512) ? (((c>>2)&63)*8 + ((c>>8)<<2) + (c&3)) : c;
  else return c;
}

// inline row rmsnorm -> bf16 A-fragments (row covered by l4-group of 4 lanes)
static __device__ __forceinline__ void row_rms_frag(
    const float* __restrict__ rowp, const float* __restrict__ normw,
    int l4, bf16x8* bfr){
  float xr[4][8];
  float ssx = 0.f;
#pragma unroll
  for (int kk=0; kk<4; kk++){
    const float* rp = rowp + kk*32 + l4*8;
    float4 a = *(const float4*)rp;
    float4 bq = *(const float4*)(rp + 4);
    xr[kk][0]=a.x; xr[kk][1]=a.y; xr[kk][2]=a.z; xr[kk][3]=a.w;
    xr[kk][4]=bq.x; xr[kk][5]=bq.y; xr[kk][6]=bq.z; xr[kk][7]=bq.w;
#pragma unroll
    for (int e=0;e<8;e++) ssx = fmaf(xr[kk][e], xr[kk][e], ssx);
  }
  ssx += __shfl_xor(ssx,16,64);
  ssx += __shfl_xor(ssx,32,64);
  const float rsx = rsqrtf(ssx*(1.0f/128.0f) + 1e-6f);
#pragma unroll
  for (int kk=0; kk<4; kk++){
    const float* wp = normw + kk*32 + l4*8;
#pragma unroll
    for (int e=0;e<8;e++) bfr[kk][e] = (short)f2bf(xr[kk][e] * rsx * wp[e]);
  }
}

// ---------------- weight-transpose job table ----------------
struct WtJob { const float* src; const float* scale; u16* dst;
               int src_ld, row0, c0, k0, dlog, kslog, C; };
struct WtJobs { WtJob j[23]; };

// ---------------- mega-prologue: all input-only work in one launch ----------------
__global__ void prologue_kernel(WtJobs P,
                                const float* __restrict__ ang, u16* __restrict__ hat,
                                const float4* __restrict__ e, float4* __restrict__ oe,
                                const float* __restrict__ node, const float* __restrict__ nw,
                                const float* __restrict__ Ba, float* __restrict__ Ca,
                                const float* __restrict__ Bb, float* __restrict__ Cb,
                                const float* __restrict__ edge_in,
                                const float* __restrict__ la_ne, u16* __restrict__ enca){
  int bid = blockIdx.x;
  const int t = threadIdx.x;
  if (bid < 4608){
    const int row = bid*16 + (t >> 4);   // 73728 rows total
    const int l = t & 15;
    float4 v = *(const float4*)(ang + (size_t)row*64 + l*4);
    float ss = v.x*v.x + v.y*v.y + v.z*v.z + v.w*v.w;
#pragma unroll
    for (int off=8; off; off>>=1) ss += __shfl_xor(ss, off, 64);
    const float rs = rsqrtf(ss*(1.0f/64.0f) + 1e-6f);
    u16x4 pk;
    pk[0]=f2bf(v.x*rs); pk[1]=f2bf(v.y*rs); pk[2]=f2bf(v.z*rs); pk[3]=f2bf(v.w*rs);
    *(u16x4*)(hat + (size_t)row*64 + l*4) = pk;
  } else if (bid < 5632){
    int idx = (bid - 4608)*256 + t;      // 262144 float4 = out_edge init
    oe[idx] = e[idx];
  } else if (bid < 7680){
    __shared__ float ar[128];
    __shared__ float sred[2];
    const int c2 = bid - 5632;               // 0..2047
    const int row = c2 >> 4;                 // 0..127
    const int c = c2 & 15;                   // chunk
    float x = 0.f;
    if (t < 128) x = node[row*128 + t];
    float s = waveSum(x*x);
    if (t < 128 && (t & 63) == 0) sred[t>>6] = s;
    __syncthreads();
    float rs = rsqrtf((sred[0]+sred[1])*(1.0f/128.0f) + 1e-6f);
    if (t < 128) ar[t] = x * rs * nw[t];
    __syncthreads();
    if (t < 128){
      const float* B = (c < 8) ? Ba : Bb;
      float* C = (c < 8) ? Ca : Cb;
      const int cc = c & 7, half = cc >> 2, sub = cc & 3;
      const int brow = 128 + half*128;
      const int col = sub*128 + t;
      float acc = 0.f;
      for (int k=0;k<128;k++) acc = fmaf(ar[k], B[(size_t)(brow+k)*512 + col], acc);
      C[(size_t)row*1024 + half*512 + col] = acc;
    }
  } else if (bid < 8448){
    // blk1 enc_aug: rmsnorm(edge_in) + node append -> enca[3072][256]
    int row = (bid - 7680)*4 + (t >> 6);   // 0..3071
    int lane = t & 63;
    int loc = row/24;
    int src = loc*64 + (row - loc*24);
    float2 v = *(const float2*)(edge_in + (size_t)src*128 + lane*2);
    float ss = waveSum(v.x*v.x + v.y*v.y);
    float rs = rsqrtf(ss*(1.0f/128.0f) + 1e-6f);
    float2 wv = *(const float2*)(la_ne + lane*2);
    u32 pk = (u32)f2bf(v.x*rs*wv.x) | ((u32)f2bf(v.y*rs*wv.y) << 16);
    *(u32*)(enca + (size_t)row*256 + lane*2) = pk;
    float2 nv = *(const float2*)(node + loc*128 + lane*2);
    u32 pn = (u32)f2bf(nv.x) | ((u32)f2bf(nv.y) << 16);
    *(u32*)(enca + (size_t)row*256 + 128 + lane*2) = pn;
  } else {
    // weight-transpose jobs
    const int jb = bid - 8448;               // 0..1471
    const WtJob J = P.j[jb >> 6];
    const int inner = jb & 63;
    const int ks = 1 << J.kslog;
    const int total = J.C << J.kslog;
    for (int idx = inner*256 + t; idx < total; idx += 64*256){
      int c = idx >> J.kslog, k = idx & (ks-1);
      float s = J.scale ? J.scale[k] : 1.0f;
      J.dst[((size_t)(J.c0 + c) << J.dlog) + J.k0 + k] =
          f2bf(J.src[(size_t)(J.row0 + k)*J.src_ld + c] * s);
    }
  }
}

// fused blk2 node-add + blk4 npr table + blk3 enca node-half
__global__ __launch_bounds__(128) void node_add_gemm2_kernel(
    const float* __restrict__ node_in, const float* __restrict__ partial,
    float* __restrict__ node_out, const float* __restrict__ nw,
    const float* __restrict__ B, float* __restrict__ C,
    u16* __restrict__ enca){
  __shared__ float ar[128];
  __shared__ float sred[2];
  const int row = blockIdx.x, t = threadIdx.x;
  float x = node_in[row*128 + t]
          + (partial[(4*row)*128+t] + partial[(4*row+1)*128+t]
           + partial[(4*row+2)*128+t] + partial[(4*row+3)*128+t]);
  if (blockIdx.y == 0){
    node_out[row*128 + t] = x;
    u16 xb = f2bf(x);
    u16* er = enca + (size_t)(row*24)*256 + 128 + t;
#pragma unroll 4
    for (int j=0;j<24;j++) er[(size_t)j*256] = xb;
  }
  float s = waveSum(x*x);
  if ((t & 63) == 0) sred[t>>6] = s;
  __syncthreads();
  float rs = rsqrtf((sred[0]+sred[1])*(1.0f/128.0f) + 1e-6f);
  ar[t] = x * rs * nw[t];
  __syncthreads();
  const int c = blockIdx.y;
  const int half = c >> 2, sub = c & 3;
  const int brow = 128 + half*128;
  const int col = sub*128 + t;
  float acc = 0.f;
  for (int k=0;k<128;k++) acc = fmaf(ar[k], B[(size_t)(brow+k)*512 + col], acc);
  C[(size_t)row*1024 + half*512 + col] = acc;
}

// ---------------- dual MFMA GEMM ----------------
__global__ __launch_bounds__(256) void gemm2_bf16_kernel(
    const u16* __restrict__ A, int lda,
    const u16* __restrict__ Bt0, u16* __restrict__ C0, int N0, int K0, int ny0,
    const u16* __restrict__ Bt1, u16* __restrict__ C1, int N1, int K1){
  __shared__ float cl[32*128];
  const int lane = threadIdx.x & 63, wave = threadIdx.x >> 6;
  const int job1 = ((int)blockIdx.y >= ny0);
  const u16* Bt = job1 ? Bt1 : Bt0;
  u16* C = job1 ? C1 : C0;
  const int N = job1 ? N1 : N0;
  const int K = job1 ? K1 : K0;
  const int by = job1 ? ((int)blockIdx.y - ny0) : (int)blockIdx.y;
  const size_t arow = (size_t)blockIdx.x*32;
  const size_t bcol = (size_t)by*128 + wave*32;
  f32x4 acc00={0,0,0,0}, acc01={0,0,0,0}, acc10={0,0,0,0}, acc11={0,0,0,0};
  for (int k=0; k<K; k+=32){
    int ko = k + (lane>>4)*8;
    bf16x8 a0 = *(const bf16x8*)(A + (arow + (lane&15))*lda + ko);
    bf16x8 a1 = *(const bf16x8*)(A + (arow + 16 + (lane&15))*lda + ko);
    bf16x8 b0 = *(const bf16x8*)(Bt + (bcol + (lane&15))*K + ko);
    bf16x8 b1 = *(const bf16x8*)(Bt + (bcol + 16 + (lane&15))*K + ko);
    acc00 = __builtin_amdgcn_mfma_f32_16x16x32_bf16(a0, b0, acc00, 0,0,0);
    acc01 = __builtin_amdgcn_mfma_f32_16x16x32_bf16(a0, b1, acc01, 0,0,0);
    acc10 = __builtin_amdgcn_mfma_f32_16x16x32_bf16(a1, b0, acc10, 0,0,0);
    acc11 = __builtin_amdgcn_mfma_f32_16x16x32_bf16(a1, b1, acc11, 0,0,0);
  }
  const int cr = (lane>>4)*4, cc = wave*32 + (lane&15);
#pragma unroll
  for (int q=0;q<4;q++){
    cl[(cr+q)*128 + cc]      = acc00[q];
    cl[(cr+q)*128 + cc+16]   = acc01[q];
    cl[(16+cr+q)*128 + cc]    = acc10[q];
    cl[(16+cr+q)*128 + cc+16] = acc11[q];
  }
  __syncthreads();
  const int t = threadIdx.x;
#pragma unroll
  for (int i=0;i<16;i++){
    int idx = i*256 + t; int r = idx>>7, c = idx&127;
    int gcol = by*128 + c;
    C[(arow + r)*(size_t)N + cperm<1>(gcol)] = f2bf(cl[idx]);
  }
}

// ---------------- fused angle kernel v11 (proven, linear vgn) ----------------
template<bool IS_BLK1>
__global__ __launch_bounds__(512, 4) void angle11_kernel(
    const u16* __restrict__ hat, const u16* __restrict__ preE, const u16* __restrict__ preK,
    const u16* __restrict__ wangT, const u16* __restrict__ woT,
    const float* __restrict__ angle,
    const float* __restrict__ rbf, const float* __restrict__ envW,
    const float* __restrict__ a_sw,
    const u16* __restrict__ aprojTb, const float* __restrict__ eproj,
    float* __restrict__ edge_out, float* __restrict__ angle_out)
{
  constexpr int HW = IS_BLK1 ? 640 : 512;
  constexpr int VGN_B  = 48*264*2;
  constexpr int GATE_O = VGN_B;
  constexpr int SS_O   = GATE_O + (IS_BLK1 ? 48*132*2 : 0);
  constexpr int RS_O   = SS_O + 8*48*4;
  constexpr int SEG_O  = RS_O + 192;
  constexpr int RBF_O  = SEG_O + (IS_BLK1 ? 0 : 1024);
  constexpr int LDS_B  = RBF_O + (IS_BLK1 ? 0 : 1152);
  __shared__ __align__(16) char ldsRaw[LDS_B];
  u16*   vgn    = (u16*)ldsRaw;
  u16*   gateLb = (u16*)(ldsRaw + GATE_O);
  float* ssL    = (float*)(ldsRaw + SS_O);
  float* rsL    = (float*)(ldsRaw + RS_O);
  float* segL   = (float*)(ldsRaw + SEG_O);
  float* rbfL   = (float*)(ldsRaw + RBF_O);
  float* msgL   = (float*)ldsRaw;

  const int t = threadIdx.x, lane = t & 63, w = t >> 6;
  const int l15 = lane & 15, l4 = lane >> 4;
  const int b = blockIdx.x;
  const int xcd = b & 7, idx = b >> 3;
  const int loc = xcd*16 + idx/12;
  const int j0 = (idx - (idx/12)*12)*2;
  const int s0 = loc*24 + j0;
  const int hbase = s0*24;
  const int oc = 16*w + l15;

  if constexpr (!IS_BLK1){
    if (t < 288) rbfL[t] = rbf[(size_t)(loc*64)*12 + t];
  }

  u16x8 pk[3][2], pe[3][2];
  u16x4 pkg[3], peg[3];
#pragma unroll
  for (int nt=0; nt<3; nt++){
    const int r = nt*16 + l15;
    const int hi = (r >= 24);
    const int rr = r - 24*hi;
    const u16* pK = preK + (size_t)(loc*24 + rr)*HW;
    const u16* pE = preE + (size_t)(s0 + hi)*HW;
#pragma unroll
    for (int i=0;i<2;i++){
      const int a = (2*w + i)*4 + l4;
      pk[nt][i] = *(const u16x8*)(pK + a*8);
      pe[nt][i] = *(const u16x8*)(pE + a*8);
    }
    if constexpr (IS_BLK1){
      const int cg = 512 + w*16 + l4*4;
      pkg[nt] = *(const u16x4*)(pK + cg);
      peg[nt] = *(const u16x4*)(pE + cg);
    }
  }

  f32x4 accv[3][2], accg[3][2], accgate[3];
#pragma unroll
  for (int nt=0;nt<3;nt++){
    accv[nt][0]=(f32x4){0,0,0,0}; accv[nt][1]=(f32x4){0,0,0,0};
    accg[nt][0]=(f32x4){0,0,0,0}; accg[nt][1]=(f32x4){0,0,0,0};
    accgate[nt]=(f32x4){0,0,0,0};
  }
#pragma unroll
  for (int kk=0; kk<2; kk++){
    const int ko = kk*32 + l4*8;
    bf16x8 bb[3];
#pragma unroll
    for (int nt=0;nt<3;nt++)
      bb[nt] = *(const bf16x8*)(hat + (size_t)(hbase + nt*16 + l15)*64 + ko);
#pragma unroll
    for (int i=0;i<2;i++){
      const int chv = (2*w + i)*16 + l15;
      bf16x8 av = *(const bf16x8*)(wangT + (size_t)chv*64 + ko);
      bf16x8 ag = *(const bf16x8*)(wangT + (size_t)(256 + chv)*64 + ko);
#pragma unroll
      for (int nt=0;nt<3;nt++){
        accv[nt][i] = __builtin_amdgcn_mfma_f32_16x16x32_bf16(av, bb[nt], accv[nt][i], 0,0,0);
        accg[nt][i] = __builtin_amdgcn_mfma_f32_16x16x32_bf16(ag, bb[nt], accg[nt][i], 0,0,0);
      }
    }
    if constexpr (IS_BLK1){
      bf16x8 aga = *(const bf16x8*)(wangT + (size_t)(512 + w*16 + l15)*64 + ko);
#pragma unroll
      for (int nt=0;nt<3;nt++)
        accgate[nt] = __builtin_amdgcn_mfma_f32_16x16x32_bf16(aga, bb[nt], accgate[nt], 0,0,0);
    }
  }

  float ssr[3] = {0.f, 0.f, 0.f};
#pragma unroll
  for (int nt=0; nt<3; nt++){
    const int r = nt*16 + l15;
#pragma unroll
    for (int i=0;i<2;i++){
      const int cb = (2*w + i)*16 + l4*4;
      u16x4 xs;
#pragma unroll
      for (int q=0;q<4;q++){
        float v = accv[nt][i][q] + bf2f(pk[nt][i][q])   + bf2f(pe[nt][i][q]);
        float g = accg[nt][i][q] + bf2f(pk[nt][i][4+q]) + bf2f(pe[nt][i][4+q]);
        float x = v * silu(g);
        ssr[nt] += x*x;
        xs[q] = f2bf(x);
      }
      *(u16x4*)&vgn[r*264 + cb] = xs;
    }
    if constexpr (IS_BLK1){
      u16x4 gs;
#pragma unroll
      for (int q=0;q<4;q++)
        gs[q] = f2bf((accgate[nt][q] + bf2f(pkg[nt][q]) + bf2f(peg[nt][q])) * A_SCALE_C);
      *(u16x4*)&gateLb[r*132 + w*16 + l4*4] = gs;
    }
  }
#pragma unroll
  for (int nt=0;nt<3;nt++){
    float s = ssr[nt];
    s += __shfl_xor(s,16,64); s += __shfl_xor(s,32,64);
    if (l4 == 0) ssL[w*48 + nt*16 + l15] = s;
  }
  bf16x8 bwp[8];
#pragma unroll
  for (int kk=0; kk<8; kk++)
    bwp[kk] = *(const bf16x8*)(woT + (size_t)oc*256 + kk*32 + l4*8);
  __syncthreads();                    // sync1
  if (t < 48){
    float s_ = 0.f;
#pragma unroll
    for (int k=0;k<8;k++) s_ += ssL[k*48 + t];
    rsL[t] = rsqrtf(s_*(1.0f/256.0f) + 1e-6f);
  }

  f32x4 mac[3];
#pragma unroll
  for (int m=0;m<3;m++) mac[m] = (f32x4){0,0,0,0};
#pragma unroll
  for (int kk=0; kk<8; kk++){
#pragma unroll
    for (int m=0;m<3;m++){
      bf16x8 aw = *(const bf16x8*)&vgn[(m*16 + l15)*264 + kk*32 + l4*8];
      mac[m] = __builtin_amdgcn_mfma_f32_16x16x32_bf16(aw, bwp[kk], mac[m], 0,0,0);
    }
  }
  __syncthreads();                    // sync2
  float rsv[3][4];
#pragma unroll
  for (int m=0;m<3;m++)
#pragma unroll
    for (int q=0;q<4;q++) rsv[m][q] = rsL[m*16 + l4*4 + q];
#pragma unroll
  for (int m=0;m<3;m++)
#pragma unroll
    for (int q=0;q<4;q++)
      msgL[(m*16 + l4*4 + q)*132 + 16*w + l15] = mac[m][q] * rsv[m][q];
  __syncthreads();                    // sync3

  if constexpr (IS_BLK1){
    if (t < 256){
      int s = t>>7, c = t&127;
      float ex[24]; float mx = -1e30f;
#pragma unroll
      for (int k=0;k<24;k++){ ex[k] = bf2f(gateLb[(s*24+k)*132 + c]); mx = fmaxf(mx, ex[k]); }
      float S = 0.f;
#pragma unroll
      for (int k=0;k<24;k++){ ex[k] = __expf(ex[k] - mx); S += ex[k]; }
      float inv = 1.f/(S + 1e-12f);
      float delta = 0.f;
#pragma unroll
      for (int k=0;k<24;k++) delta += msgL[(s*24+k)*132 + c] * ex[k];
      edge_out[(size_t)(loc*64 + j0 + s)*128 + c] += delta * inv;
    }
  } else {
    if (t < 256){
      int s = t>>7, c = t&127;
      float envR[12];
#pragma unroll
      for (int j=0;j<12;j++) envR[j] = envW[j*128 + c];
      float sg_ = 0.f;
#pragma unroll
      for (int k=0;k<24;k++){
        float envC = 0.f;
#pragma unroll
        for (int j=0;j<12;j++) envC = fmaf(rbfL[k*12 + j], envR[j], envC);
        sg_ += msgL[(s*24+k)*132 + c] * envC * a_sw[(size_t)(s0+s)*24 + k];
      }
      segL[s*128 + c] = sg_;
    }
    for (int p = w; p < 12; p += 8){
      const int mt = p >> 2, ntc = p & 3;
      f32x4 am = (f32x4){0,0,0,0};
#pragma unroll
      for (int kk=0; kk<4; kk++){
        const float* mrow = &msgL[(mt*16 + l15)*132 + kk*32 + l4*8];
        bf16x8 a;
#pragma unroll
        for (int e=0;e<8;e++) a[e] = (short)f2bf(mrow[e]);
        bf16x8 bb = *(const bf16x8*)(aprojTb + (size_t)(ntc*16 + l15)*128 + kk*32 + l4*8);
        am = __builtin_amdgcn_mfma_f32_16x16x32_bf16(a, bb, am, 0,0,0);
      }
#pragma unroll
      for (int q=0;q<4;q++){
        int row = mt*16 + l4*4 + q;
        size_t a_ = (size_t)hbase + row;
        int col = ntc*16 + l15;
        angle_out[a_*64 + col] = angle[a_*64 + col] + am[q] * a_sw[a_];
      }
    }
    __syncthreads();
    if (t < 256){
      int s = t>>7, c = t&127;
      float acc2 = 0.f;
      for (int dd=0; dd<128; dd++) acc2 = fmaf(segL[s*128 + dd], eproj[dd*128 + c], acc2);
      edge_out[(size_t)(loc*64 + j0 + s)*128 + c] += acc2 * A_SCALE_C;
    }
  }
}

// ---------------- scores v4: inline rmsnorm + MFMA gate + 2-way parallel softmax ----------------
__global__ __launch_bounds__(256) void scores3_kernel(const float* __restrict__ edge_src,
                                                      const float* __restrict__ norm_e,
                                                      const u16* __restrict__ gateT,
                                                      float* __restrict__ scores){
  __shared__ float s[64*132];
  __shared__ float red[2][128];
  const int t = threadIdx.x, lane = t & 63, w = t >> 6;
  const int l15 = lane & 15, l4 = lane >> 4;
  const int n = blockIdx.x;
  const int row = n*64 + w*16 + l15;
  bf16x8 bfr[4];
  row_rms_frag(edge_src + (size_t)row*128, norm_e, l4, bfr);
  f32x4 acc[8];
#pragma unroll
  for (int j=0;j<8;j++) acc[j] = (f32x4){0,0,0,0};
#pragma unroll
  for (int kk=0; kk<4; kk++){
    const int ko = kk*32 + l4*8;
#pragma unroll
    for (int j=0;j<8;j++){
      bf16x8 b = *(const bf16x8*)(gateT + (size_t)(j*16 + l15)*128 + ko);
      acc[j] = __builtin_amdgcn_mfma_f32_16x16x32_bf16(bfr[kk], b, acc[j], 0,0,0);
    }
  }
#pragma unroll
  for (int j=0;j<8;j++)
#pragma unroll
    for (int q=0;q<4;q++)
      s[(w*16 + l4*4 + q)*132 + j*16 + l15] = acc[j][q] * E_SCALE_C;
  __syncthreads();
  {
    const int c = t & 127, h = t >> 7;
    const int r0 = h*32;
    float m = -1e30f;
    for (int r=r0; r<r0+32; r++) m = fmaxf(m, s[r*132 + c]);
    red[h][c] = m;
    __syncthreads();
    m = fmaxf(red[0][c], red[1][c]);
    __syncthreads();
    float S = 0.f;
    for (int r=r0; r<r0+32; r++) S += __expf(s[r*132 + c] - m);
    red[h][c] = S;
    __syncthreads();
    S = red[0][c] + red[1][c];
    float inv = 1.f/(S + 1e-12f);
    for (int r=r0; r<r0+32; r++)
      scores[(size_t)(n*64 + r)*128 + c] = __expf(s[r*132 + c] - m) * inv;
  }
}

// ---------------- combined blk2 edge kernel (inline rmsnorm + blk3 enca e-half) ----------------
__global__ __launch_bounds__(256) void edge_fused01_kernel(
    const float* __restrict__ edge_src,
    const float* __restrict__ norm_e,
    const float* __restrict__ NPa, const float* __restrict__ NPe,
    const int* __restrict__ next2e,
    const u16* __restrict__ aaWT, const u16* __restrict__ aeWT,
    const u16* __restrict__ woaaT, const u16* __restrict__ woaeT,
    const float* __restrict__ scores,
    float* __restrict__ edge_out, float* __restrict__ partial,
    const float* __restrict__ lr_norm_e, u16* __restrict__ enca){
  __shared__ __align__(16) char lds[13184];
  u16*   vgn  = (u16*)lds;
  float* msgF = (float*)lds;
  float* ssP  = (float*)(lds + 12800);
  float* rsL  = (float*)(lds + 13056);
  const int t = threadIdx.x, lane = t & 63, w = t >> 6;
  const int l15 = lane & 15, l4 = lane >> 4;
  const int g = blockIdx.x, e0 = g*16, n = e0 >> 6;
  const int nx = next2e[e0 + l15];

  bf16x8 bfr[4];
  row_rms_frag(edge_src + (size_t)(e0 + l15)*128, norm_e, l4, bfr);

#pragma unroll
  for (int path=0; path<2; path++){
    const u16* wT  = path ? aeWT : aaWT;
    const u16* woT = path ? woaeT : woaaT;
    const float* NPt = path ? NPe : NPa;

    f32x4 av4[4], ag4[4];
#pragma unroll
    for (int i=0;i<4;i++){ av4[i]=(f32x4){0,0,0,0}; ag4[i]=(f32x4){0,0,0,0}; }
#pragma unroll
    for (int kk=0; kk<4; kk++){
      const int ko = kk*32 + l4*8;
#pragma unroll
      for (int i=0;i<4;i++){
        const int chr = w*64 + i*16 + l15;
        bf16x8 wv = *(const bf16x8*)(wT + (size_t)chr*128 + ko);
        bf16x8 wg = *(const bf16x8*)(wT + (size_t)(256 + chr)*128 + ko);
        av4[i] = __builtin_amdgcn_mfma_f32_16x16x32_bf16(wv, bfr[kk], av4[i], 0,0,0);
        ag4[i] = __builtin_amdgcn_mfma_f32_16x16x32_bf16(wg, bfr[kk], ag4[i], 0,0,0);
      }
    }

    float ssr = 0.f;
#pragma unroll
    for (int i=0;i<4;i++){
      const int cb = w*64 + i*16 + l4*4;
      float4 sv = *(const float4*)(NPt + n*1024 + cb);
      float4 sg = *(const float4*)(NPt + n*1024 + 256 + cb);
      float4 nv = *(const float4*)(NPt + (size_t)nx*1024 + 512 + cb);
      float4 ng = *(const float4*)(NPt + (size_t)nx*1024 + 768 + cb);
      u16x4 xs;
#pragma unroll
      for (int q=0;q<4;q++){
        float v  = av4[i][q] + ((const float*)&sv)[q] + ((const float*)&nv)[q];
        float gg = ag4[i][q] + ((const float*)&sg)[q] + ((const float*)&ng)[q];
        float x = v * silu(gg);
        ssr += x*x;
        xs[q] = f2bf(x);
      }
      *(u16x4*)&vgn[l15*264 + cb] = xs;
    }
    {
      float s = ssr;
      s += __shfl_xor(s,16,64); s += __shfl_xor(s,32,64);
      if (l4 == 0) ssP[l15*4 + w] = s;
    }
    __syncthreads();
    if (t < 16)
      rsL[t] = rsqrtf((ssP[t*4]+ssP[t*4+1]+ssP[t*4+2]+ssP[t*4+3])*(1.0f/256.0f) + 1e-6f);
    __syncthreads();
    f32x4 mac[2] = {(f32x4){0,0,0,0}, (f32x4){0,0,0,0}};
#pragma unroll
    for (int kk=0; kk<8; kk++){
      bf16x8 a = *(const bf16x8*)&vgn[l15*264 + kk*32 + l4*8];
#pragma unroll
      for (int nt=0; nt<2; nt++){
        bf16x8 bw = *(const bf16x8*)(woT + (size_t)(32*w + nt*16 + l15)*256 + kk*32 + l4*8);
        mac[nt] = __builtin_amdgcn_mfma_f32_16x16x32_bf16(a, bw, mac[nt], 0,0,0);
      }
    }
    float rsv[4];
#pragma unroll
    for (int q=0;q<4;q++) rsv[q] = rsL[l4*4 + q];
    __syncthreads();
#pragma unroll
    for (int nt=0; nt<2; nt++)
#pragma unroll
      for (int q=0;q<4;q++)
        msgF[(l4*4 + q)*132 + 32*w + nt*16 + l15] = mac[nt][q] * rsv[q];
    __syncthreads();

    if (path == 0){
      if (t < 128){
        float p = 0.f;
#pragma unroll
        for (int r=0;r<16;r++) p += msgF[r*132 + t] * scores[(size_t)(e0+r)*128 + t];
        partial[g*128 + t] = p;
      }
    } else {
      const int d = t & 127, rg = (t >> 7) * 8;
#pragma unroll
      for (int i=0;i<8;i++){
        float fin = edge_out[(size_t)(e0+rg+i)*128 + d] + msgF[(rg+i)*132 + d];
        edge_out[(size_t)(e0+rg+i)*128 + d] = fin;
        msgF[(rg+i)*132 + d] = fin;   // keep final fp32 for blk3 rmsnorm
      }
    }
    __syncthreads();
  }

  // ---- blk3 enca e-half: rmsnorm(final edge rows) for j<24 of this loc ----
  if ((e0 & 63) < 24){
    const int jrow = (e0 & 63) + l15;
    float xr2[4][8]; float ss2 = 0.f;
#pragma unroll
    for (int kk=0; kk<4; kk++)
#pragma unroll
      for (int e=0;e<8;e++){
        float v = msgF[l15*132 + kk*32 + l4*8 + e];
        xr2[kk][e] = v; ss2 = fmaf(v, v, ss2);
      }
    ss2 += __shfl_xor(ss2,16,64);
    ss2 += __shfl_xor(ss2,32,64);
    const float rs2 = rsqrtf(ss2*(1.0f/128.0f) + 1e-6f);
    if (jrow < 24 && w == (l15 & 3)){
#pragma unroll
      for (int kk=0; kk<4; kk++){
        const float* wp = lr_norm_e + kk*32 + l4*8;
        u16x8 ob;
#pragma unroll
        for (int e=0;e<8;e++) ob[e] = f2bf(xr2[kk][e] * rs2 * wp[e]);
        *(u16x8*)(enca + (size_t)(n*24 + jrow)*256 + kk*32 + l4*8) = ob;
      }
    }
  }
}

// ---------------- blk4 edge kernel: MODE2 with fused rmsnorm ----------------
__global__ __launch_bounds__(256) void edge_fused2m2_kernel(
    const float* __restrict__ edge_src,
    const float* __restrict__ norm_e,
    const float* __restrict__ NPt,
    const int* __restrict__ next2e,
    const u16* __restrict__ wT,
    const u16* __restrict__ woT,
    const float* __restrict__ rbf, const float* __restrict__ envW,
    const float* __restrict__ sw, const u16* __restrict__ eprojT,
    float* __restrict__ edge_out, float* __restrict__ partial){
  __shared__ __align__(16) char lds[20096];
  u16*   vgn  = (u16*)lds;
  float* msgF = (float*)lds;
  u16*   msgB = (u16*)(lds + 8448);
  float* ssP  = (float*)(lds + 12800);
  float* rsL  = (float*)(lds + 13056);
  float* envWL= (float*)(lds + 13184);
  float* rbfL = (float*)(lds + 19328);
  const int t = threadIdx.x, lane = t & 63, w = t >> 6;
  const int l15 = lane & 15, l4 = lane >> 4;
  const int g = blockIdx.x, e0 = g*16, n = e0 >> 6;
  const int nx = next2e[e0 + l15];
  for (int i=t; i<12*128; i+=256) envWL[i] = envW[i];
  if (t < 192) rbfL[t] = rbf[(size_t)e0*12 + t];

  bf16x8 bfr[4];
  row_rms_frag(edge_src + (size_t)(e0 + l15)*128, norm_e, l4, bfr);

  float4 sv[4], sg[4], nv[4], ng[4];
#pragma unroll
  for (int i=0;i<4;i++){
    const int cb = w*64 + i*16 + l4*4;
    sv[i] = *(const float4*)(NPt + n*1024 + cb);
    sg[i] = *(const float4*)(NPt + n*1024 + 256 + cb);
    nv[i] = *(const float4*)(NPt + (size_t)nx*1024 + 512 + cb);
    ng[i] = *(const float4*)(NPt + (size_t)nx*1024 + 768 + cb);
  }

  f32x4 av4[4], ag4[4];
#pragma unroll
  for (int i=0;i<4;i++){ av4[i]=(f32x4){0,0,0,0}; ag4[i]=(f32x4){0,0,0,0}; }
#pragma unroll
  for (int kk=0; kk<4; kk++){
    const int ko = kk*32 + l4*8;
#pragma unroll
    for (int i=0;i<4;i++){
      const int chr = w*64 + i*16 + l15;
      bf16x8 wv = *(const bf16x8*)(wT + (size_t)chr*128 + ko);
      bf16x8 wg = *(const bf16x8*)(wT + (size_t)(256 + chr)*128 + ko);
      av4[i] = __builtin_amdgcn_mfma_f32_16x16x32_bf16(wv, bfr[kk], av4[i], 0,0,0);
      ag4[i] = __builtin_amdgcn_mfma_f32_16x16x32_bf16(wg, bfr[kk], ag4[i], 0,0,0);
    }
  }

  float ssr = 0.f;
#pragma unroll
  for (int i=0;i<4;i++){
    const int cb = w*64 + i*16 + l4*4;
    u16x4 xs;
#pragma unroll
    for (int q=0;q<4;q++){
      float v = av4[i][q] + ((const float*)&sv[i])[q] + ((const float*)&nv[i])[q];
      float gg = ag4[i][q] + ((const float*)&sg[i])[q] + ((const float*)&ng[i])[q];
      float x = v * silu(gg);
      ssr += x*x;
      xs[q] = f2bf(x);
    }
    *(u16x4*)&vgn[l15*264 + cb] = xs;
  }
  {
    float s = ssr;
    s += __shfl_xor(s,16,64); s += __shfl_xor(s,32,64);
    if (l4 == 0) ssP[l15*4 + w] = s;
  }
  __syncthreads();
  if (t < 16)
    rsL[t] = rsqrtf((ssP[t*4]+ssP[t*4+1]+ssP[t*4+2]+ssP[t*4+3])*(1.0f/256.0f) + 1e-6f);
  __syncthreads();
  f32x4 mac[2] = {(f32x4){0,0,0,0}, (f32x4){0,0,0,0}};
#pragma unroll
  for (int kk=0; kk<8; kk++){
    bf16x8 a = *(const bf16x8*)&vgn[l15*264 + kk*32 + l4*8];
#pragma unroll
    for (int nt=0; nt<2; nt++){
      bf16x8 bw = *(const bf16x8*)(woT + (size_t)(32*w + nt*16 + l15)*256 + kk*32 + l4*8);
      mac[nt] = __builtin_amdgcn_mfma_f32_16x16x32_bf16(a, bw, mac[nt], 0,0,0);
    }
  }
  float rsv[4];
#pragma unroll
  for (int q=0;q<4;q++) rsv[q] = rsL[l4*4 + q];
  __syncthreads();
#pragma unroll
  for (int nt=0; nt<2; nt++)
#pragma unroll
    for (int q=0;q<4;q++){
      float val = mac[nt][q] * rsv[q];
      int row = l4*4 + q, col = 32*w + nt*16 + l15;
      msgF[row*132 + col] = val;
      msgB[row*136 + col] = f2bf(val);
    }
  __syncthreads();

  f32x4 em[2] = {(f32x4){0,0,0,0}, (f32x4){0,0,0,0}};
#pragma unroll
  for (int kk=0; kk<4; kk++){
    bf16x8 a = *(const bf16x8*)&msgB[l15*136 + kk*32 + l4*8];
#pragma unroll
    for (int nt=0; nt<2; nt++){
      bf16x8 bw = *(const bf16x8*)(eprojT + (size_t)(32*w + nt*16 + l15)*128 + kk*32 + l4*8);
      em[nt] = __builtin_amdgcn_mfma_f32_16x16x32_bf16(a, bw, em[nt], 0,0,0);
    }
  }
#pragma unroll
  for (int nt=0; nt<2; nt++)
#pragma unroll
    for (int q=0;q<4;q++)
      edge_out[(size_t)(e0 + l4*4 + q)*128 + 32*w + nt*16 + l15] += em[nt][q];
  if (t < 128){
    float p = 0.f;
#pragma unroll
    for (int r=0;r<16;r++){
      float envC = 0.f;
#pragma unroll
      for (int j=0;j<12;j++) envC = fmaf(rbfL[r*12 + j], envWL[j*128 + t], envC);
      p += msgF[r*132 + t] * envC * sw[e0 + r];
    }
    partial[g*128 + t] = p;
  }
}

__global__ void node_final4_kernel(const float* __restrict__ partial,
                                   const float* __restrict__ nproj,
                                   float* __restrict__ node_out){
  __shared__ float seg[128];
  int n = blockIdx.x, t = threadIdx.x;
  seg[t] = partial[(4*n)*128+t] + partial[(4*n+1)*128+t]
         + partial[(4*n+2)*128+t] + partial[(4*n+3)*128+t];
  __syncthreads();
  float acc = 0.f;
  for (int dd=0; dd<128; dd++) acc = fmaf(seg[dd], nproj[dd*128 + t], acc);
  node_out[n*128 + t] += acc * E_SCALE_C;
}

// ---------------- launch ----------------
extern "C" void kernel_launch(void* const* d_in, const int* in_sizes, int n_in,
                              void* d_out, int out_size, void* d_ws, size_t ws_size,
                              hipStream_t stream){
  const float* node_in  = (const float*)d_in[0];
  const float* edge_in  = (const float*)d_in[1];
  const float* angle_in = (const float*)d_in[2];
  const float* sw       = (const float*)d_in[3];
  const float* a_sw     = (const float*)d_in[4];
  const float* rbf      = (const float*)d_in[5];
  const int*   edge_index = (const int*)d_in[6];
  const float* la_norm_e = (const float*)d_in[8];
  const float* la_norm_a = (const float*)d_in[9];
  const float* la_win    = (const float*)d_in[10];
  const float* la_nw     = (const float*)d_in[11];
  const float* la_wout   = (const float*)d_in[12];
  const float* la_gate   = (const float*)d_in[13];
  const float* aa_norm_n = (const float*)d_in[14];
  const float* aa_norm_e = (const float*)d_in[15];
  const float* aa_win    = (const float*)d_in[16];
  const float* aa_nw     = (const float*)d_in[17];
  const float* aa_wout   = (const float*)d_in[18];
  const float* aa_src_gate = (const float*)d_in[19];
  const float* ae_win    = (const float*)d_in[20];
  const float* ae_nw     = (const float*)d_in[21];
  const float* ae_wout   = (const float*)d_in[22];
  const float* lr_norm_e = (const float*)d_in[23];
  const float* lr_norm_a = (const float*)d_in[24];
  const float* lr_win    = (const float*)d_in[25];
  const float* lr_nw     = (const float*)d_in[26];
  const float* lr_wout   = (const float*)d_in[27];
  const float* lr_env    = (const float*)d_in[28];
  const float* lr_eproj  = (const float*)d_in[29];
  const float* lr_aproj  = (const float*)d_in[30];
  const float* ar_norm_n = (const float*)d_in[31];
  const float* ar_norm_e = (const float*)d_in[32];
  const float* ar_win    = (const float*)d_in[33];
  const float* ar_nw     = (const float*)d_in[34];
  const float* ar_wout   = (const float*)d_in[35];
  const float* ar_env    = (const float*)d_in[36];
  const float* ar_nproj  = (const float*)d_in[37];
  const float* ar_eproj  = (const float*)d_in[38];

  float* out_node  = (float*)d_out;
  float* out_edge  = out_node + 128*128;
  float* out_angle = out_edge + (size_t)8192*128;

  float* p = (float*)d_ws;
  float* hat_f   = p; p += 2359296;
  float* enca_f  = p; p += 393216;
  float* preE_f  = p; p += 983040;
  float* preK_f  = p; p += 983040;
  float* wang1_f = p; p += 20480;
  float* wang3_f = p; p += 16384;
  float* wij1_f  = p; p += 40960;
  float* wij3_f  = p; p += 32768;
  float* wik1_f  = p; p += 81920;
  float* wik3_f  = p; p += 65536;
  float* wo1T_f  = p; p += 16384;
  float* wo3T_f  = p; p += 16384;
  float* whe2_f  = p; p += 73728;
  float* whe4_f  = p; p += 32768;
  float* woaaT_f = p; p += 16384;
  float* woaeT_f = p; p += 16384;
  float* woarT_f = p; p += 16384;
  float* eprjT_f = p; p += 8192;
  float* aprjT_f = p; p += 4096;
  float* npa     = p; p += 131072;
  float* npe     = p; p += 131072;
  float* npr     = p; p += 131072;
  float* scores2 = p; p += 1048576;
  float* partial = p; p += 65536;

  u16* hat  = (u16*)hat_f;
  u16* enca = (u16*)enca_f;
  u16* preE = (u16*)preE_f;
  u16* preK = (u16*)preK_f;
  u16* wang1= (u16*)wang1_f;
  u16* wang3= (u16*)wang3_f;
  u16* wij1 = (u16*)wij1_f;
  u16* wij3 = (u16*)wij3_f;
  u16* wik1 = (u16*)wik1_f;
  u16* wik3 = (u16*)wik3_f;
  u16* wo1T = (u16*)wo1T_f;
  u16* wo3T = (u16*)wo3T_f;
  u16* whe2 = (u16*)whe2_f;
  u16* whe4 = (u16*)whe4_f;
  u16* woaaT= (u16*)woaaT_f;
  u16* woaeT= (u16*)woaeT_f;
  u16* woarT= (u16*)woarT_f;
  u16* eprjT= (u16*)eprjT_f;
  u16* aprjT= (u16*)aprjT_f;
  u16* aaWT = whe2;
  u16* aeWT = whe2 + 512*128;
  u16* gateT= whe2 + 1024*128;
  u16* arWT = whe4;

  dim3 b512(512), b256(256), b128(128);
  const int* next2e = edge_index + 8192;

  WtJobs jobs;
  int nj = 0;
  auto add = [&](const float* src, const float* scale, u16* dst,
                 int ld, int row0, int c0, int k0, int dlog, int kslog, int C){
    jobs.j[nj++] = WtJob{src, scale, dst, ld, row0, c0, k0, dlog, kslog, C};
  };
  add(la_win, la_norm_a, wang1, 512, 0,   0,   0,   6, 6, 512);
  add(la_gate,la_norm_a, wang1, 128, 0,   512, 0,   6, 6, 128);
  add(la_win, nullptr,   wij1,  512, 192, 0,   0,   7, 7, 512);
  add(la_gate,nullptr,   wij1,  128, 192, 512, 0,   7, 7, 128);
  add(la_win, nullptr,   wik1,  512, 320, 0,   0,   8, 7, 512);
  add(la_gate,nullptr,   wik1,  128, 320, 512, 0,   8, 7, 128);
  add(la_win, nullptr,   wik1,  512, 64,  0,   128, 8, 7, 512);
  add(la_gate,nullptr,   wik1,  128, 64,  512, 128, 8, 7, 128);
  add(la_wout,la_nw,     wo1T,  128, 0,   0,   0,   8, 8, 128);
  add(lr_win, lr_norm_a, wang3, 512, 0,   0,   0,   6, 6, 512);
  add(lr_win, nullptr,   wij3,  512, 192, 0,   0,   7, 7, 512);
  add(lr_win, nullptr,   wik3,  512, 320, 0,   0,   8, 7, 512);
  add(lr_win, nullptr,   wik3,  512, 64,  0,   128, 8, 7, 512);
  add(lr_wout,lr_nw,     wo3T,  128, 0,   0,   0,   8, 8, 128);
  add(aa_win, nullptr,   whe2,  512, 0,   0,   0,   7, 7, 512);
  add(ae_win, nullptr,   whe2,  512, 0,   512, 0,   7, 7, 512);
  add(aa_src_gate,nullptr,whe2, 128, 0,   1024,0,   7, 7, 128);
  add(ar_win, nullptr,   whe4,  512, 0,   0,   0,   7, 7, 512);
  add(aa_wout, aa_nw,    woaaT, 128, 0,   0,   0,   8, 8, 128);
  add(ae_wout, ae_nw,    woaeT, 128, 0,   0,   0,   8, 8, 128);
  add(ar_wout, ar_nw,    woarT, 128, 0,   0,   0,   8, 8, 128);
  add(ar_eproj,nullptr,  eprjT, 128, 0,   0,   0,   7, 7, 128);
  add(lr_aproj,nullptr,  aprjT, 64,  0,   0,   0,   7, 7, 64);

  // mega-prologue: all input-only work (hat, edge copy, npa/npe, blk1 enc_aug, wt jobs)
  prologue_kernel<<<4608 + 1024 + 2048 + 768 + 64*23, b256, 0, stream>>>(jobs,
      angle_in, hat, (const float4*)edge_in, (float4*)out_edge,
      node_in, aa_norm_n, aa_win, npa, ae_win, npe,
      edge_in, la_norm_e, enca);

  // ---- block 1 ----
  gemm2_bf16_kernel<<<dim3(96,10), b256, 0, stream>>>(enca, 256,
      wij1, preE, 640, 128, 5, wik1, preK, 640, 256);
  angle11_kernel<true><<<1536, b512, 0, stream>>>(hat, preE, preK, wang1, wo1T,
      angle_in, nullptr, nullptr, nullptr, nullptr, nullptr, out_edge, nullptr);

  // ---- block 2 (edge rmsnorm fused; writes blk3 enca e-half; node add fused with npr) ----
  scores3_kernel<<<128, b256, 0, stream>>>(out_edge, aa_norm_e, gateT, scores2);
  edge_fused01_kernel<<<512, b256, 0, stream>>>(out_edge, aa_norm_e, npa, npe, next2e,
      aaWT, aeWT, woaaT, woaeT, scores2, out_edge, partial, lr_norm_e, enca);
  node_add_gemm2_kernel<<<dim3(128,8), b128, 0, stream>>>(node_in, partial,
      out_node, ar_norm_n, ar_win, npr, enca);

  // ---- block 3 (enca fully built by blk2 kernels) ----
  gemm2_bf16_kernel<<<dim3(96,8), b256, 0, stream>>>(enca, 256,
      wij3, preE, 512, 128, 4, wik3, preK, 512, 256);
  angle11_kernel<false><<<1536, b512, 0, stream>>>(hat, preE, preK, wang3, wo3T,
      angle_in, rbf, lr_env, a_sw, aprjT, lr_eproj, out_edge, out_angle);

  // ---- block 4 (npr precomputed at blk2) ----
  edge_fused2m2_kernel<<<512, b256, 0, stream>>>(out_edge, ar_norm_e, npr, next2e,
      arWT, woarT, rbf, ar_env, sw, eprjT, out_edge, partial);
  node_final4_kernel<<<128, b128, 0, stream>>>(partial, ar_nproj, out_node);

  (void)in_sizes; (void)n_in; (void)out_size; (void)ws_size;
}

// Round 26
// 243.270 us; speedup vs baseline: 1.0694x; 1.0075x over previous
//
#include <hip/hip_runtime.h>
#include <hip/hip_bf16.h>

#define A_SCALE_C 0.6454972243679028f   // (24/10)^-0.5
#define E_SCALE_C 0.3952847075210474f   // (64/10)^-0.5

typedef unsigned short u16;
typedef unsigned int u32;
typedef __attribute__((ext_vector_type(8))) short bf16x8;
typedef __attribute__((ext_vector_type(4))) float f32x4;
typedef __attribute__((ext_vector_type(4))) unsigned short u16x4;
typedef __attribute__((ext_vector_type(8))) unsigned short u16x8;

static __device__ __forceinline__ float waveSum(float v){
#pragma unroll
  for (int off = 32; off; off >>= 1) v += __shfl_xor(v, off, 64);
  return v;
}
static __device__ __forceinline__ float silu(float g){
  return g / (1.0f + __expf(-g));
}
static __device__ __forceinline__ float bf2f(u16 h){
  union { u32 u; float f; } x; x.u = ((u32)h) << 16; return x.f;
}
static __device__ __forceinline__ u16 f2bf(float f){
  __hip_bfloat16 h = __float2bfloat16(f);
  u16 r; __builtin_memcpy(&r, &h, 2); return r;
}
template<int PERM>
static __device__ __forceinline__ int cperm(int c){
  if constexpr (PERM) return (c < 512) ? (((c>>2)&63)*8 + ((c>>8)<<2) + (c&3)) : c;
  else return c;
}

// inline row rmsnorm -> bf16 A-fragments (row covered by l4-group of 4 lanes)
static __device__ __forceinline__ void row_rms_frag(
    const float* __restrict__ rowp, const float* __restrict__ normw,
    int l4, bf16x8* bfr){
  float xr[4][8];
  float ssx = 0.f;
#pragma unroll
  for (int kk=0; kk<4; kk++){
    const float* rp = rowp + kk*32 + l4*8;
    float4 a = *(const float4*)rp;
    float4 bq = *(const float4*)(rp + 4);
    xr[kk][0]=a.x; xr[kk][1]=a.y; xr[kk][2]=a.z; xr[kk][3]=a.w;
    xr[kk][4]=bq.x; xr[kk][5]=bq.y; xr[kk][6]=bq.z; xr[kk][7]=bq.w;
#pragma unroll
    for (int e=0;e<8;e++) ssx = fmaf(xr[kk][e], xr[kk][e], ssx);
  }
  ssx += __shfl_xor(ssx,16,64);
  ssx += __shfl_xor(ssx,32,64);
  const float rsx = rsqrtf(ssx*(1.0f/128.0f) + 1e-6f);
#pragma unroll
  for (int kk=0; kk<4; kk++){
    const float* wp = normw + kk*32 + l4*8;
#pragma unroll
    for (int e=0;e<8;e++) bfr[kk][e] = (short)f2bf(xr[kk][e] * rsx * wp[e]);
  }
}

// ---------------- weight-transpose job table ----------------
struct WtJob { const float* src; const float* scale; u16* dst;
               int src_ld, row0, c0, k0, dlog, kslog, C; };
struct WtJobs { WtJob j[23]; };

// ---------------- mega-prologue: all input-only work in one launch ----------------
__global__ void prologue_kernel(WtJobs P,
                                const float* __restrict__ ang, u16* __restrict__ hat,
                                const float4* __restrict__ e, float4* __restrict__ oe,
                                const float* __restrict__ node, const float* __restrict__ nw,
                                const float* __restrict__ Ba, float* __restrict__ Ca,
                                const float* __restrict__ Bb, float* __restrict__ Cb,
                                const float* __restrict__ edge_in,
                                const float* __restrict__ la_ne, u16* __restrict__ enca){
  int bid = blockIdx.x;
  const int t = threadIdx.x;
  if (bid < 4608){
    const int row = bid*16 + (t >> 4);   // 73728 rows total
    const int l = t & 15;
    float4 v = *(const float4*)(ang + (size_t)row*64 + l*4);
    float ss = v.x*v.x + v.y*v.y + v.z*v.z + v.w*v.w;
#pragma unroll
    for (int off=8; off; off>>=1) ss += __shfl_xor(ss, off, 64);
    const float rs = rsqrtf(ss*(1.0f/64.0f) + 1e-6f);
    u16x4 pk;
    pk[0]=f2bf(v.x*rs); pk[1]=f2bf(v.y*rs); pk[2]=f2bf(v.z*rs); pk[3]=f2bf(v.w*rs);
    *(u16x4*)(hat + (size_t)row*64 + l*4) = pk;
  } else if (bid < 5632){
    int idx = (bid - 4608)*256 + t;      // 262144 float4 = out_edge init
    oe[idx] = e[idx];
  } else if (bid < 7680){
    __shared__ float ar[128];
    __shared__ float sred[2];
    const int c2 = bid - 5632;               // 0..2047
    const int row = c2 >> 4;                 // 0..127
    const int c = c2 & 15;                   // chunk
    float x = 0.f;
    if (t < 128) x = node[row*128 + t];
    float s = waveSum(x*x);
    if (t < 128 && (t & 63) == 0) sred[t>>6] = s;
    __syncthreads();
    float rs = rsqrtf((sred[0]+sred[1])*(1.0f/128.0f) + 1e-6f);
    if (t < 128) ar[t] = x * rs * nw[t];
    __syncthreads();
    if (t < 128){
      const float* B = (c < 8) ? Ba : Bb;
      float* C = (c < 8) ? Ca : Cb;
      const int cc = c & 7, half = cc >> 2, sub = cc & 3;
      const int brow = 128 + half*128;
      const int col = sub*128 + t;
      float acc = 0.f;
      for (int k=0;k<128;k++) acc = fmaf(ar[k], B[(size_t)(brow+k)*512 + col], acc);
      C[(size_t)row*1024 + half*512 + col] = acc;
    }
  } else if (bid < 8448){
    // blk1 enc_aug: rmsnorm(edge_in) + node append -> enca[3072][256]
    int row = (bid - 7680)*4 + (t >> 6);   // 0..3071
    int lane = t & 63;
    int loc = row/24;
    int src = loc*64 + (row - loc*24);
    float2 v = *(const float2*)(edge_in + (size_t)src*128 + lane*2);
    float ss = waveSum(v.x*v.x + v.y*v.y);
    float rs = rsqrtf(ss*(1.0f/128.0f) + 1e-6f);
    float2 wv = *(const float2*)(la_ne + lane*2);
    u32 pk = (u32)f2bf(v.x*rs*wv.x) | ((u32)f2bf(v.y*rs*wv.y) << 16);
    *(u32*)(enca + (size_t)row*256 + lane*2) = pk;
    float2 nv = *(const float2*)(node + loc*128 + lane*2);
    u32 pn = (u32)f2bf(nv.x) | ((u32)f2bf(nv.y) << 16);
    *(u32*)(enca + (size_t)row*256 + 128 + lane*2) = pn;
  } else {
    // weight-transpose jobs
    const int jb = bid - 8448;               // 0..1471
    const WtJob J = P.j[jb >> 6];
    const int inner = jb & 63;
    const int ks = 1 << J.kslog;
    const int total = J.C << J.kslog;
    for (int idx = inner*256 + t; idx < total; idx += 64*256){
      int c = idx >> J.kslog, k = idx & (ks-1);
      float s = J.scale ? J.scale[k] : 1.0f;
      J.dst[((size_t)(J.c0 + c) << J.dlog) + J.k0 + k] =
          f2bf(J.src[(size_t)(J.row0 + k)*J.src_ld + c] * s);
    }
  }
}

// fused blk2 node-add + blk4 npr table + blk3 enca node-half
__global__ __launch_bounds__(128) void node_add_gemm2_kernel(
    const float* __restrict__ node_in, const float* __restrict__ partial,
    float* __restrict__ node_out, const float* __restrict__ nw,
    const float* __restrict__ B, float* __restrict__ C,
    u16* __restrict__ enca){
  __shared__ float ar[128];
  __shared__ float sred[2];
  const int row = blockIdx.x, t = threadIdx.x;
  float x = node_in[row*128 + t]
          + (partial[(4*row)*128+t] + partial[(4*row+1)*128+t]
           + partial[(4*row+2)*128+t] + partial[(4*row+3)*128+t]);
  if (blockIdx.y == 0){
    node_out[row*128 + t] = x;
    u16 xb = f2bf(x);
    u16* er = enca + (size_t)(row*24)*256 + 128 + t;
#pragma unroll 4
    for (int j=0;j<24;j++) er[(size_t)j*256] = xb;
  }
  float s = waveSum(x*x);
  if ((t & 63) == 0) sred[t>>6] = s;
  __syncthreads();
  float rs = rsqrtf((sred[0]+sred[1])*(1.0f/128.0f) + 1e-6f);
  ar[t] = x * rs * nw[t];
  __syncthreads();
  const int c = blockIdx.y;
  const int half = c >> 2, sub = c & 3;
  const int brow = 128 + half*128;
  const int col = sub*128 + t;
  float acc = 0.f;
  for (int k=0;k<128;k++) acc = fmaf(ar[k], B[(size_t)(brow+k)*512 + col], acc);
  C[(size_t)row*1024 + half*512 + col] = acc;
}

// ---------------- dual MFMA GEMM ----------------
__global__ __launch_bounds__(256) void gemm2_bf16_kernel(
    const u16* __restrict__ A, int lda,
    const u16* __restrict__ Bt0, u16* __restrict__ C0, int N0, int K0, int ny0,
    const u16* __restrict__ Bt1, u16* __restrict__ C1, int N1, int K1){
  __shared__ float cl[32*128];
  const int lane = threadIdx.x & 63, wave = threadIdx.x >> 6;
  const int job1 = ((int)blockIdx.y >= ny0);
  const u16* Bt = job1 ? Bt1 : Bt0;
  u16* C = job1 ? C1 : C0;
  const int N = job1 ? N1 : N0;
  const int K = job1 ? K1 : K0;
  const int by = job1 ? ((int)blockIdx.y - ny0) : (int)blockIdx.y;
  const size_t arow = (size_t)blockIdx.x*32;
  const size_t bcol = (size_t)by*128 + wave*32;
  f32x4 acc00={0,0,0,0}, acc01={0,0,0,0}, acc10={0,0,0,0}, acc11={0,0,0,0};
  for (int k=0; k<K; k+=32){
    int ko = k + (lane>>4)*8;
    bf16x8 a0 = *(const bf16x8*)(A + (arow + (lane&15))*lda + ko);
    bf16x8 a1 = *(const bf16x8*)(A + (arow + 16 + (lane&15))*lda + ko);
    bf16x8 b0 = *(const bf16x8*)(Bt + (bcol + (lane&15))*K + ko);
    bf16x8 b1 = *(const bf16x8*)(Bt + (bcol + 16 + (lane&15))*K + ko);
    acc00 = __builtin_amdgcn_mfma_f32_16x16x32_bf16(a0, b0, acc00, 0,0,0);
    acc01 = __builtin_amdgcn_mfma_f32_16x16x32_bf16(a0, b1, acc01, 0,0,0);
    acc10 = __builtin_amdgcn_mfma_f32_16x16x32_bf16(a1, b0, acc10, 0,0,0);
    acc11 = __builtin_amdgcn_mfma_f32_16x16x32_bf16(a1, b1, acc11, 0,0,0);
  }
  const int cr = (lane>>4)*4, cc = wave*32 + (lane&15);
#pragma unroll
  for (int q=0;q<4;q++){
    cl[(cr+q)*128 + cc]      = acc00[q];
    cl[(cr+q)*128 + cc+16]   = acc01[q];
    cl[(16+cr+q)*128 + cc]    = acc10[q];
    cl[(16+cr+q)*128 + cc+16] = acc11[q];
  }
  __syncthreads();
  const int t = threadIdx.x;
#pragma unroll
  for (int i=0;i<16;i++){
    int idx = i*256 + t; int r = idx>>7, c = idx&127;
    int gcol = by*128 + c;
    C[(arow + r)*(size_t)N + cperm<1>(gcol)] = f2bf(cl[idx]);
  }
}

// ---------------- fused angle kernel v11 (proven, linear vgn) ----------------
template<bool IS_BLK1>
__global__ __launch_bounds__(512, 4) void angle11_kernel(
    const u16* __restrict__ hat, const u16* __restrict__ preE, const u16* __restrict__ preK,
    const u16* __restrict__ wangT, const u16* __restrict__ woT,
    const float* __restrict__ angle,
    const float* __restrict__ rbf, const float* __restrict__ envW,
    const float* __restrict__ a_sw,
    const u16* __restrict__ aprojTb, const float* __restrict__ eproj,
    float* __restrict__ edge_out, float* __restrict__ angle_out)
{
  constexpr int HW = IS_BLK1 ? 640 : 512;
  constexpr int VGN_B  = 48*264*2;
  constexpr int GATE_O = VGN_B;
  constexpr int SS_O   = GATE_O + (IS_BLK1 ? 48*132*2 : 0);
  constexpr int RS_O   = SS_O + 8*48*4;
  constexpr int SEG_O  = RS_O + 192;
  constexpr int RBF_O  = SEG_O + (IS_BLK1 ? 0 : 1024);
  constexpr int LDS_B  = RBF_O + (IS_BLK1 ? 0 : 1152);
  __shared__ __align__(16) char ldsRaw[LDS_B];
  u16*   vgn    = (u16*)ldsRaw;
  u16*   gateLb = (u16*)(ldsRaw + GATE_O);
  float* ssL    = (float*)(ldsRaw + SS_O);
  float* rsL    = (float*)(ldsRaw + RS_O);
  float* segL   = (float*)(ldsRaw + SEG_O);
  float* rbfL   = (float*)(ldsRaw + RBF_O);
  float* msgL   = (float*)ldsRaw;

  const int t = threadIdx.x, lane = t & 63, w = t >> 6;
  const int l15 = lane & 15, l4 = lane >> 4;
  const int b = blockIdx.x;
  const int xcd = b & 7, idx = b >> 3;
  const int loc = xcd*16 + idx/12;
  const int j0 = (idx - (idx/12)*12)*2;
  const int s0 = loc*24 + j0;
  const int hbase = s0*24;
  const int oc = 16*w + l15;

  if constexpr (!IS_BLK1){
    if (t < 288) rbfL[t] = rbf[(size_t)(loc*64)*12 + t];
  }

  u16x8 pk[3][2], pe[3][2];
  u16x4 pkg[3], peg[3];
#pragma unroll
  for (int nt=0; nt<3; nt++){
    const int r = nt*16 + l15;
    const int hi = (r >= 24);
    const int rr = r - 24*hi;
    const u16* pK = preK + (size_t)(loc*24 + rr)*HW;
    const u16* pE = preE + (size_t)(s0 + hi)*HW;
#pragma unroll
    for (int i=0;i<2;i++){
      const int a = (2*w + i)*4 + l4;
      pk[nt][i] = *(const u16x8*)(pK + a*8);
      pe[nt][i] = *(const u16x8*)(pE + a*8);
    }
    if constexpr (IS_BLK1){
      const int cg = 512 + w*16 + l4*4;
      pkg[nt] = *(const u16x4*)(pK + cg);
      peg[nt] = *(const u16x4*)(pE + cg);
    }
  }

  f32x4 accv[3][2], accg[3][2], accgate[3];
#pragma unroll
  for (int nt=0;nt<3;nt++){
    accv[nt][0]=(f32x4){0,0,0,0}; accv[nt][1]=(f32x4){0,0,0,0};
    accg[nt][0]=(f32x4){0,0,0,0}; accg[nt][1]=(f32x4){0,0,0,0};
    accgate[nt]=(f32x4){0,0,0,0};
  }
#pragma unroll
  for (int kk=0; kk<2; kk++){
    const int ko = kk*32 + l4*8;
    bf16x8 bb[3];
#pragma unroll
    for (int nt=0;nt<3;nt++)
      bb[nt] = *(const bf16x8*)(hat + (size_t)(hbase + nt*16 + l15)*64 + ko);
#pragma unroll
    for (int i=0;i<2;i++){
      const int chv = (2*w + i)*16 + l15;
      bf16x8 av = *(const bf16x8*)(wangT + (size_t)chv*64 + ko);
      bf16x8 ag = *(const bf16x8*)(wangT + (size_t)(256 + chv)*64 + ko);
#pragma unroll
      for (int nt=0;nt<3;nt++){
        accv[nt][i] = __builtin_amdgcn_mfma_f32_16x16x32_bf16(av, bb[nt], accv[nt][i], 0,0,0);
        accg[nt][i] = __builtin_amdgcn_mfma_f32_16x16x32_bf16(ag, bb[nt], accg[nt][i], 0,0,0);
      }
    }
    if constexpr (IS_BLK1){
      bf16x8 aga = *(const bf16x8*)(wangT + (size_t)(512 + w*16 + l15)*64 + ko);
#pragma unroll
      for (int nt=0;nt<3;nt++)
        accgate[nt] = __builtin_amdgcn_mfma_f32_16x16x32_bf16(aga, bb[nt], accgate[nt], 0,0,0);
    }
  }

  float ssr[3] = {0.f, 0.f, 0.f};
#pragma unroll
  for (int nt=0; nt<3; nt++){
    const int r = nt*16 + l15;
#pragma unroll
    for (int i=0;i<2;i++){
      const int cb = (2*w + i)*16 + l4*4;
      u16x4 xs;
#pragma unroll
      for (int q=0;q<4;q++){
        float v = accv[nt][i][q] + bf2f(pk[nt][i][q])   + bf2f(pe[nt][i][q]);
        float g = accg[nt][i][q] + bf2f(pk[nt][i][4+q]) + bf2f(pe[nt][i][4+q]);
        float x = v * silu(g);
        ssr[nt] += x*x;
        xs[q] = f2bf(x);
      }
      *(u16x4*)&vgn[r*264 + cb] = xs;
    }
    if constexpr (IS_BLK1){
      u16x4 gs;
#pragma unroll
      for (int q=0;q<4;q++)
        gs[q] = f2bf((accgate[nt][q] + bf2f(pkg[nt][q]) + bf2f(peg[nt][q])) * A_SCALE_C);
      *(u16x4*)&gateLb[r*132 + w*16 + l4*4] = gs;
    }
  }
#pragma unroll
  for (int nt=0;nt<3;nt++){
    float s = ssr[nt];
    s += __shfl_xor(s,16,64); s += __shfl_xor(s,32,64);
    if (l4 == 0) ssL[w*48 + nt*16 + l15] = s;
  }
  bf16x8 bwp[8];
#pragma unroll
  for (int kk=0; kk<8; kk++)
    bwp[kk] = *(const bf16x8*)(woT + (size_t)oc*256 + kk*32 + l4*8);
  __syncthreads();                    // sync1
  if (t < 48){
    float s_ = 0.f;
#pragma unroll
    for (int k=0;k<8;k++) s_ += ssL[k*48 + t];
    rsL[t] = rsqrtf(s_*(1.0f/256.0f) + 1e-6f);
  }

  f32x4 mac[3];
#pragma unroll
  for (int m=0;m<3;m++) mac[m] = (f32x4){0,0,0,0};
#pragma unroll
  for (int kk=0; kk<8; kk++){
#pragma unroll
    for (int m=0;m<3;m++){
      bf16x8 aw = *(const bf16x8*)&vgn[(m*16 + l15)*264 + kk*32 + l4*8];
      mac[m] = __builtin_amdgcn_mfma_f32_16x16x32_bf16(aw, bwp[kk], mac[m], 0,0,0);
    }
  }
  __syncthreads();                    // sync2
  float rsv[3][4];
#pragma unroll
  for (int m=0;m<3;m++)
#pragma unroll
    for (int q=0;q<4;q++) rsv[m][q] = rsL[m*16 + l4*4 + q];
#pragma unroll
  for (int m=0;m<3;m++)
#pragma unroll
    for (int q=0;q<4;q++)
      msgL[(m*16 + l4*4 + q)*132 + 16*w + l15] = mac[m][q] * rsv[m][q];
  __syncthreads();                    // sync3

  if constexpr (IS_BLK1){
    if (t < 256){
      int s = t>>7, c = t&127;
      float ex[24]; float mx = -1e30f;
#pragma unroll
      for (int k=0;k<24;k++){ ex[k] = bf2f(gateLb[(s*24+k)*132 + c]); mx = fmaxf(mx, ex[k]); }
      float S = 0.f;
#pragma unroll
      for (int k=0;k<24;k++){ ex[k] = __expf(ex[k] - mx); S += ex[k]; }
      float inv = 1.f/(S + 1e-12f);
      float delta = 0.f;
#pragma unroll
      for (int k=0;k<24;k++) delta += msgL[(s*24+k)*132 + c] * ex[k];
      edge_out[(size_t)(loc*64 + j0 + s)*128 + c] += delta * inv;
    }
  } else {
    if (t < 256){
      int s = t>>7, c = t&127;
      float envR[12];
#pragma unroll
      for (int j=0;j<12;j++) envR[j] = envW[j*128 + c];
      float sg_ = 0.f;
#pragma unroll
      for (int k=0;k<24;k++){
        float envC = 0.f;
#pragma unroll
        for (int j=0;j<12;j++) envC = fmaf(rbfL[k*12 + j], envR[j], envC);
        sg_ += msgL[(s*24+k)*132 + c] * envC * a_sw[(size_t)(s0+s)*24 + k];
      }
      segL[s*128 + c] = sg_;
    }
    for (int p = w; p < 12; p += 8){
      const int mt = p >> 2, ntc = p & 3;
      f32x4 am = (f32x4){0,0,0,0};
#pragma unroll
      for (int kk=0; kk<4; kk++){
        const float* mrow = &msgL[(mt*16 + l15)*132 + kk*32 + l4*8];
        bf16x8 a;
#pragma unroll
        for (int e=0;e<8;e++) a[e] = (short)f2bf(mrow[e]);
        bf16x8 bb = *(const bf16x8*)(aprojTb + (size_t)(ntc*16 + l15)*128 + kk*32 + l4*8);
        am = __builtin_amdgcn_mfma_f32_16x16x32_bf16(a, bb, am, 0,0,0);
      }
#pragma unroll
      for (int q=0;q<4;q++){
        int row = mt*16 + l4*4 + q;
        size_t a_ = (size_t)hbase + row;
        int col = ntc*16 + l15;
        angle_out[a_*64 + col] = angle[a_*64 + col] + am[q] * a_sw[a_];
      }
    }
    __syncthreads();
    if (t < 256){
      int s = t>>7, c = t&127;
      float acc2 = 0.f;
      for (int dd=0; dd<128; dd++) acc2 = fmaf(segL[s*128 + dd], eproj[dd*128 + c], acc2);
      edge_out[(size_t)(loc*64 + j0 + s)*128 + c] += acc2 * A_SCALE_C;
    }
  }
}

// ---------------- scores v4: inline rmsnorm + MFMA gate + 2-way parallel softmax ----------------
__global__ __launch_bounds__(256) void scores3_kernel(const float* __restrict__ edge_src,
                                                      const float* __restrict__ norm_e,
                                                      const u16* __restrict__ gateT,
                                                      float* __restrict__ scores){
  __shared__ float s[64*132];
  __shared__ float red[2][128];
  const int t = threadIdx.x, lane = t & 63, w = t >> 6;
  const int l15 = lane & 15, l4 = lane >> 4;
  const int n = blockIdx.x;
  const int row = n*64 + w*16 + l15;
  bf16x8 bfr[4];
  row_rms_frag(edge_src + (size_t)row*128, norm_e, l4, bfr);
  f32x4 acc[8];
#pragma unroll
  for (int j=0;j<8;j++) acc[j] = (f32x4){0,0,0,0};
#pragma unroll
  for (int kk=0; kk<4; kk++){
    const int ko = kk*32 + l4*8;
#pragma unroll
    for (int j=0;j<8;j++){
      bf16x8 b = *(const bf16x8*)(gateT + (size_t)(j*16 + l15)*128 + ko);
      acc[j] = __builtin_amdgcn_mfma_f32_16x16x32_bf16(bfr[kk], b, acc[j], 0,0,0);
    }
  }
#pragma unroll
  for (int j=0;j<8;j++)
#pragma unroll
    for (int q=0;q<4;q++)
      s[(w*16 + l4*4 + q)*132 + j*16 + l15] = acc[j][q] * E_SCALE_C;
  __syncthreads();
  {
    const int c = t & 127, h = t >> 7;
    const int r0 = h*32;
    float m = -1e30f;
    for (int r=r0; r<r0+32; r++) m = fmaxf(m, s[r*132 + c]);
    red[h][c] = m;
    __syncthreads();
    m = fmaxf(red[0][c], red[1][c]);
    __syncthreads();
    float S = 0.f;
    for (int r=r0; r<r0+32; r++) S += __expf(s[r*132 + c] - m);
    red[h][c] = S;
    __syncthreads();
    S = red[0][c] + red[1][c];
    float inv = 1.f/(S + 1e-12f);
    for (int r=r0; r<r0+32; r++)
      scores[(size_t)(n*64 + r)*128 + c] = __expf(s[r*132 + c] - m) * inv;
  }
}

// ---------------- combined blk2 edge kernel (inline rmsnorm + blk3 enca e-half) ----------------
__global__ __launch_bounds__(256) void edge_fused01_kernel(
    const float* __restrict__ edge_src,
    const float* __restrict__ norm_e,
    const float* __restrict__ NPa, const float* __restrict__ NPe,
    const int* __restrict__ next2e,
    const u16* __restrict__ aaWT, const u16* __restrict__ aeWT,
    const u16* __restrict__ woaaT, const u16* __restrict__ woaeT,
    const float* __restrict__ scores,
    float* __restrict__ edge_out, float* __restrict__ partial,
    const float* __restrict__ lr_norm_e, u16* __restrict__ enca){
  __shared__ __align__(16) char lds[13184];
  u16*   vgn  = (u16*)lds;
  float* msgF = (float*)lds;
  float* ssP  = (float*)(lds + 12800);
  float* rsL  = (float*)(lds + 13056);
  const int t = threadIdx.x, lane = t & 63, w = t >> 6;
  const int l15 = lane & 15, l4 = lane >> 4;
  const int g = blockIdx.x, e0 = g*16, n = e0 >> 6;
  const int nx = next2e[e0 + l15];

  bf16x8 bfr[4];
  row_rms_frag(edge_src + (size_t)(e0 + l15)*128, norm_e, l4, bfr);

#pragma unroll
  for (int path=0; path<2; path++){
    const u16* wT  = path ? aeWT : aaWT;
    const u16* woT = path ? woaeT : woaaT;
    const float* NPt = path ? NPe : NPa;

    f32x4 av4[4], ag4[4];
#pragma unroll
    for (int i=0;i<4;i++){ av4[i]=(f32x4){0,0,0,0}; ag4[i]=(f32x4){0,0,0,0}; }
#pragma unroll
    for (int kk=0; kk<4; kk++){
      const int ko = kk*32 + l4*8;
#pragma unroll
      for (int i=0;i<4;i++){
        const int chr = w*64 + i*16 + l15;
        bf16x8 wv = *(const bf16x8*)(wT + (size_t)chr*128 + ko);
        bf16x8 wg = *(const bf16x8*)(wT + (size_t)(256 + chr)*128 + ko);
        av4[i] = __builtin_amdgcn_mfma_f32_16x16x32_bf16(wv, bfr[kk], av4[i], 0,0,0);
        ag4[i] = __builtin_amdgcn_mfma_f32_16x16x32_bf16(wg, bfr[kk], ag4[i], 0,0,0);
      }
    }

    float ssr = 0.f;
#pragma unroll
    for (int i=0;i<4;i++){
      const int cb = w*64 + i*16 + l4*4;
      float4 sv = *(const float4*)(NPt + n*1024 + cb);
      float4 sg = *(const float4*)(NPt + n*1024 + 256 + cb);
      float4 nv = *(const float4*)(NPt + (size_t)nx*1024 + 512 + cb);
      float4 ng = *(const float4*)(NPt + (size_t)nx*1024 + 768 + cb);
      u16x4 xs;
#pragma unroll
      for (int q=0;q<4;q++){
        float v  = av4[i][q] + ((const float*)&sv)[q] + ((const float*)&nv)[q];
        float gg = ag4[i][q] + ((const float*)&sg)[q] + ((const float*)&ng)[q];
        float x = v * silu(gg);
        ssr += x*x;
        xs[q] = f2bf(x);
      }
      *(u16x4*)&vgn[l15*264 + cb] = xs;
    }
    {
      float s = ssr;
      s += __shfl_xor(s,16,64); s += __shfl_xor(s,32,64);
      if (l4 == 0) ssP[l15*4 + w] = s;
    }
    __syncthreads();
    if (t < 16)
      rsL[t] = rsqrtf((ssP[t*4]+ssP[t*4+1]+ssP[t*4+2]+ssP[t*4+3])*(1.0f/256.0f) + 1e-6f);
    __syncthreads();
    f32x4 mac[2] = {(f32x4){0,0,0,0}, (f32x4){0,0,0,0}};
#pragma unroll
    for (int kk=0; kk<8; kk++){
      bf16x8 a = *(const bf16x8*)&vgn[l15*264 + kk*32 + l4*8];
#pragma unroll
      for (int nt=0; nt<2; nt++){
        bf16x8 bw = *(const bf16x8*)(woT + (size_t)(32*w + nt*16 + l15)*256 + kk*32 + l4*8);
        mac[nt] = __builtin_amdgcn_mfma_f32_16x16x32_bf16(a, bw, mac[nt], 0,0,0);
      }
    }
    float rsv[4];
#pragma unroll
    for (int q=0;q<4;q++) rsv[q] = rsL[l4*4 + q];
    __syncthreads();
#pragma unroll
    for (int nt=0; nt<2; nt++)
#pragma unroll
      for (int q=0;q<4;q++)
        msgF[(l4*4 + q)*132 + 32*w + nt*16 + l15] = mac[nt][q] * rsv[q];
    __syncthreads();

    if (path == 0){
      if (t < 128){
        float p = 0.f;
#pragma unroll
        for (int r=0;r<16;r++) p += msgF[r*132 + t] * scores[(size_t)(e0+r)*128 + t];
        partial[g*128 + t] = p;
      }
    } else {
      const int d = t & 127, rg = (t >> 7) * 8;
#pragma unroll
      for (int i=0;i<8;i++){
        float fin = edge_out[(size_t)(e0+rg+i)*128 + d] + msgF[(rg+i)*132 + d];
        edge_out[(size_t)(e0+rg+i)*128 + d] = fin;
        msgF[(rg+i)*132 + d] = fin;   // keep final fp32 for blk3 rmsnorm
      }
    }
    __syncthreads();
  }

  // ---- blk3 enca e-half: rmsnorm(final edge rows) for j<24 of this loc ----
  if ((e0 & 63) < 24){
    const int jrow = (e0 & 63) + l15;
    float xr2[4][8]; float ss2 = 0.f;
#pragma unroll
    for (int kk=0; kk<4; kk++)
#pragma unroll
      for (int e=0;e<8;e++){
        float v = msgF[l15*132 + kk*32 + l4*8 + e];
        xr2[kk][e] = v; ss2 = fmaf(v, v, ss2);
      }
    ss2 += __shfl_xor(ss2,16,64);
    ss2 += __shfl_xor(ss2,32,64);
    const float rs2 = rsqrtf(ss2*(1.0f/128.0f) + 1e-6f);
    if (jrow < 24 && w == (l15 & 3)){
#pragma unroll
      for (int kk=0; kk<4; kk++){
        const float* wp = lr_norm_e + kk*32 + l4*8;
        u16x8 ob;
#pragma unroll
        for (int e=0;e<8;e++) ob[e] = f2bf(xr2[kk][e] * rs2 * wp[e]);
        *(u16x8*)(enca + (size_t)(n*24 + jrow)*256 + kk*32 + l4*8) = ob;
      }
    }
  }
}

// ---------------- blk4 edge kernel: MODE2 + fused rmsnorm + fused node projection ----------------
__global__ __launch_bounds__(256) void edge_fused2m2_kernel(
    const float* __restrict__ edge_src,
    const float* __restrict__ norm_e,
    const float* __restrict__ NPt,
    const int* __restrict__ next2e,
    const u16* __restrict__ wT,
    const u16* __restrict__ woT,
    const float* __restrict__ rbf, const float* __restrict__ envW,
    const float* __restrict__ sw, const u16* __restrict__ eprojT,
    const float* __restrict__ nproj,
    float* __restrict__ edge_out, float* __restrict__ node_out){
  __shared__ __align__(16) char lds[20608];
  u16*   vgn  = (u16*)lds;
  float* msgF = (float*)lds;
  u16*   msgB = (u16*)(lds + 8448);
  float* ssP  = (float*)(lds + 12800);
  float* rsL  = (float*)(lds + 13056);
  float* envWL= (float*)(lds + 13184);
  float* rbfL = (float*)(lds + 19328);
  float* segN = (float*)(lds + 20096);
  const int t = threadIdx.x, lane = t & 63, w = t >> 6;
  const int l15 = lane & 15, l4 = lane >> 4;
  const int g = blockIdx.x, e0 = g*16, n = e0 >> 6;
  const int nx = next2e[e0 + l15];
  for (int i=t; i<12*128; i+=256) envWL[i] = envW[i];
  if (t < 192) rbfL[t] = rbf[(size_t)e0*12 + t];

  bf16x8 bfr[4];
  row_rms_frag(edge_src + (size_t)(e0 + l15)*128, norm_e, l4, bfr);

  float4 sv[4], sg[4], nv[4], ng[4];
#pragma unroll
  for (int i=0;i<4;i++){
    const int cb = w*64 + i*16 + l4*4;
    sv[i] = *(const float4*)(NPt + n*1024 + cb);
    sg[i] = *(const float4*)(NPt + n*1024 + 256 + cb);
    nv[i] = *(const float4*)(NPt + (size_t)nx*1024 + 512 + cb);
    ng[i] = *(const float4*)(NPt + (size_t)nx*1024 + 768 + cb);
  }

  f32x4 av4[4], ag4[4];
#pragma unroll
  for (int i=0;i<4;i++){ av4[i]=(f32x4){0,0,0,0}; ag4[i]=(f32x4){0,0,0,0}; }
#pragma unroll
  for (int kk=0; kk<4; kk++){
    const int ko = kk*32 + l4*8;
#pragma unroll
    for (int i=0;i<4;i++){
      const int chr = w*64 + i*16 + l15;
      bf16x8 wv = *(const bf16x8*)(wT + (size_t)chr*128 + ko);
      bf16x8 wg = *(const bf16x8*)(wT + (size_t)(256 + chr)*128 + ko);
      av4[i] = __builtin_amdgcn_mfma_f32_16x16x32_bf16(wv, bfr[kk], av4[i], 0,0,0);
      ag4[i] = __builtin_amdgcn_mfma_f32_16x16x32_bf16(wg, bfr[kk], ag4[i], 0,0,0);
    }
  }

  float ssr = 0.f;
#pragma unroll
  for (int i=0;i<4;i++){
    const int cb = w*64 + i*16 + l4*4;
    u16x4 xs;
#pragma unroll
    for (int q=0;q<4;q++){
      float v = av4[i][q] + ((const float*)&sv[i])[q] + ((const float*)&nv[i])[q];
      float gg = ag4[i][q] + ((const float*)&sg[i])[q] + ((const float*)&ng[i])[q];
      float x = v * silu(gg);
      ssr += x*x;
      xs[q] = f2bf(x);
    }
    *(u16x4*)&vgn[l15*264 + cb] = xs;
  }
  {
    float s = ssr;
    s += __shfl_xor(s,16,64); s += __shfl_xor(s,32,64);
    if (l4 == 0) ssP[l15*4 + w] = s;
  }
  __syncthreads();
  if (t < 16)
    rsL[t] = rsqrtf((ssP[t*4]+ssP[t*4+1]+ssP[t*4+2]+ssP[t*4+3])*(1.0f/256.0f) + 1e-6f);
  __syncthreads();
  f32x4 mac[2] = {(f32x4){0,0,0,0}, (f32x4){0,0,0,0}};
#pragma unroll
  for (int kk=0; kk<8; kk++){
    bf16x8 a = *(const bf16x8*)&vgn[l15*264 + kk*32 + l4*8];
#pragma unroll
    for (int nt=0; nt<2; nt++){
      bf16x8 bw = *(const bf16x8*)(woT + (size_t)(32*w + nt*16 + l15)*256 + kk*32 + l4*8);
      mac[nt] = __builtin_amdgcn_mfma_f32_16x16x32_bf16(a, bw, mac[nt], 0,0,0);
    }
  }
  float rsv[4];
#pragma unroll
  for (int q=0;q<4;q++) rsv[q] = rsL[l4*4 + q];
  __syncthreads();
#pragma unroll
  for (int nt=0; nt<2; nt++)
#pragma unroll
    for (int q=0;q<4;q++){
      float val = mac[nt][q] * rsv[q];
      int row = l4*4 + q, col = 32*w + nt*16 + l15;
      msgF[row*132 + col] = val;
      msgB[row*136 + col] = f2bf(val);
    }
  __syncthreads();

  f32x4 em[2] = {(f32x4){0,0,0,0}, (f32x4){0,0,0,0}};
#pragma unroll
  for (int kk=0; kk<4; kk++){
    bf16x8 a = *(const bf16x8*)&msgB[l15*136 + kk*32 + l4*8];
#pragma unroll
    for (int nt=0; nt<2; nt++){
      bf16x8 bw = *(const bf16x8*)(eprojT + (size_t)(32*w + nt*16 + l15)*128 + kk*32 + l4*8);
      em[nt] = __builtin_amdgcn_mfma_f32_16x16x32_bf16(a, bw, em[nt], 0,0,0);
    }
  }
#pragma unroll
  for (int nt=0; nt<2; nt++)
#pragma unroll
    for (int q=0;q<4;q++)
      edge_out[(size_t)(e0 + l4*4 + q)*128 + 32*w + nt*16 + l15] += em[nt][q];

  // ---- fused node projection: p = env-gated partial; node_out += (p . nproj) * E_SCALE ----
  float p = 0.f;
  if (t < 128){
#pragma unroll
    for (int r=0;r<16;r++){
      float envC = 0.f;
#pragma unroll
      for (int j=0;j<12;j++) envC = fmaf(rbfL[r*12 + j], envWL[j*128 + t], envC);
      p += msgF[r*132 + t] * envC * sw[e0 + r];
    }
  }
  __syncthreads();
  if (t < 128) segN[t] = p;
  __syncthreads();
  if (t < 128){
    float acc = 0.f;
    for (int dd=0; dd<128; dd++) acc = fmaf(segN[dd], nproj[dd*128 + t], acc);
    atomicAdd(node_out + (size_t)n*128 + t, acc * E_SCALE_C);
  }
}

// ---------------- launch ----------------
extern "C" void kernel_launch(void* const* d_in, const int* in_sizes, int n_in,
                              void* d_out, int out_size, void* d_ws, size_t ws_size,
                              hipStream_t stream){
  const float* node_in  = (const float*)d_in[0];
  const float* edge_in  = (const float*)d_in[1];
  const float* angle_in = (const float*)d_in[2];
  const float* sw       = (const float*)d_in[3];
  const float* a_sw     = (const float*)d_in[4];
  const float* rbf      = (const float*)d_in[5];
  const int*   edge_index = (const int*)d_in[6];
  const float* la_norm_e = (const float*)d_in[8];
  const float* la_norm_a = (const float*)d_in[9];
  const float* la_win    = (const float*)d_in[10];
  const float* la_nw     = (const float*)d_in[11];
  const float* la_wout   = (const float*)d_in[12];
  const float* la_gate   = (const float*)d_in[13];
  const float* aa_norm_n = (const float*)d_in[14];
  const float* aa_norm_e = (const float*)d_in[15];
  const float* aa_win    = (const float*)d_in[16];
  const float* aa_nw     = (const float*)d_in[17];
  const float* aa_wout   = (const float*)d_in[18];
  const float* aa_src_gate = (const float*)d_in[19];
  const float* ae_win    = (const float*)d_in[20];
  const float* ae_nw     = (const float*)d_in[21];
  const float* ae_wout   = (const float*)d_in[22];
  const float* lr_norm_e = (const float*)d_in[23];
  const float* lr_norm_a = (const float*)d_in[24];
  const float* lr_win    = (const float*)d_in[25];
  const float* lr_nw     = (const float*)d_in[26];
  const float* lr_wout   = (const float*)d_in[27];
  const float* lr_env    = (const float*)d_in[28];
  const float* lr_eproj  = (const float*)d_in[29];
  const float* lr_aproj  = (const float*)d_in[30];
  const float* ar_norm_n = (const float*)d_in[31];
  const float* ar_norm_e = (const float*)d_in[32];
  const float* ar_win    = (const float*)d_in[33];
  const float* ar_nw     = (const float*)d_in[34];
  const float* ar_wout   = (const float*)d_in[35];
  const float* ar_env    = (const float*)d_in[36];
  const float* ar_nproj  = (const float*)d_in[37];
  const float* ar_eproj  = (const float*)d_in[38];

  float* out_node  = (float*)d_out;
  float* out_edge  = out_node + 128*128;
  float* out_angle = out_edge + (size_t)8192*128;

  float* p = (float*)d_ws;
  float* hat_f   = p; p += 2359296;
  float* enca_f  = p; p += 393216;
  float* preE_f  = p; p += 983040;
  float* preK_f  = p; p += 983040;
  float* wang1_f = p; p += 20480;
  float* wang3_f = p; p += 16384;
  float* wij1_f  = p; p += 40960;
  float* wij3_f  = p; p += 32768;
  float* wik1_f  = p; p += 81920;
  float* wik3_f  = p; p += 65536;
  float* wo1T_f  = p; p += 16384;
  float* wo3T_f  = p; p += 16384;
  float* whe2_f  = p; p += 73728;
  float* whe4_f  = p; p += 32768;
  float* woaaT_f = p; p += 16384;
  float* woaeT_f = p; p += 16384;
  float* woarT_f = p; p += 16384;
  float* eprjT_f = p; p += 8192;
  float* aprjT_f = p; p += 4096;
  float* npa     = p; p += 131072;
  float* npe     = p; p += 131072;
  float* npr     = p; p += 131072;
  float* scores2 = p; p += 1048576;
  float* partial = p; p += 65536;

  u16* hat  = (u16*)hat_f;
  u16* enca = (u16*)enca_f;
  u16* preE = (u16*)preE_f;
  u16* preK = (u16*)preK_f;
  u16* wang1= (u16*)wang1_f;
  u16* wang3= (u16*)wang3_f;
  u16* wij1 = (u16*)wij1_f;
  u16* wij3 = (u16*)wij3_f;
  u16* wik1 = (u16*)wik1_f;
  u16* wik3 = (u16*)wik3_f;
  u16* wo1T = (u16*)wo1T_f;
  u16* wo3T = (u16*)wo3T_f;
  u16* whe2 = (u16*)whe2_f;
  u16* whe4 = (u16*)whe4_f;
  u16* woaaT= (u16*)woaaT_f;
  u16* woaeT= (u16*)woaeT_f;
  u16* woarT= (u16*)woarT_f;
  u16* eprjT= (u16*)eprjT_f;
  u16* aprjT= (u16*)aprjT_f;
  u16* aaWT = whe2;
  u16* aeWT = whe2 + 512*128;
  u16* gateT= whe2 + 1024*128;
  u16* arWT = whe4;

  dim3 b512(512), b256(256), b128(128);
  const int* next2e = edge_index + 8192;

  WtJobs jobs;
  int nj = 0;
  auto add = [&](const float* src, const float* scale, u16* dst,
                 int ld, int row0, int c0, int k0, int dlog, int kslog, int C){
    jobs.j[nj++] = WtJob{src, scale, dst, ld, row0, c0, k0, dlog, kslog, C};
  };
  add(la_win, la_norm_a, wang1, 512, 0,   0,   0,   6, 6, 512);
  add(la_gate,la_norm_a, wang1, 128, 0,   512, 0,   6, 6, 128);
  add(la_win, nullptr,   wij1,  512, 192, 0,   0,   7, 7, 512);
  add(la_gate,nullptr,   wij1,  128, 192, 512, 0,   7, 7, 128);
  add(la_win, nullptr,   wik1,  512, 320, 0,   0,   8, 7, 512);
  add(la_gate,nullptr,   wik1,  128, 320, 512, 0,   8, 7, 128);
  add(la_win, nullptr,   wik1,  512, 64,  0,   128, 8, 7, 512);
  add(la_gate,nullptr,   wik1,  128, 64,  512, 128, 8, 7, 128);
  add(la_wout,la_nw,     wo1T,  128, 0,   0,   0,   8, 8, 128);
  add(lr_win, lr_norm_a, wang3, 512, 0,   0,   0,   6, 6, 512);
  add(lr_win, nullptr,   wij3,  512, 192, 0,   0,   7, 7, 512);
  add(lr_win, nullptr,   wik3,  512, 320, 0,   0,   8, 7, 512);
  add(lr_win, nullptr,   wik3,  512, 64,  0,   128, 8, 7, 512);
  add(lr_wout,lr_nw,     wo3T,  128, 0,   0,   0,   8, 8, 128);
  add(aa_win, nullptr,   whe2,  512, 0,   0,   0,   7, 7, 512);
  add(ae_win, nullptr,   whe2,  512, 0,   512, 0,   7, 7, 512);
  add(aa_src_gate,nullptr,whe2, 128, 0,   1024,0,   7, 7, 128);
  add(ar_win, nullptr,   whe4,  512, 0,   0,   0,   7, 7, 512);
  add(aa_wout, aa_nw,    woaaT, 128, 0,   0,   0,   8, 8, 128);
  add(ae_wout, ae_nw,    woaeT, 128, 0,   0,   0,   8, 8, 128);
  add(ar_wout, ar_nw,    woarT, 128, 0,   0,   0,   8, 8, 128);
  add(ar_eproj,nullptr,  eprjT, 128, 0,   0,   0,   7, 7, 128);
  add(lr_aproj,nullptr,  aprjT, 64,  0,   0,   0,   7, 7, 64);

  // mega-prologue: all input-only work (hat, edge copy, npa/npe, blk1 enc_aug, wt jobs)
  prologue_kernel<<<4608 + 1024 + 2048 + 768 + 64*23, b256, 0, stream>>>(jobs,
      angle_in, hat, (const float4*)edge_in, (float4*)out_edge,
      node_in, aa_norm_n, aa_win, npa, ae_win, npe,
      edge_in, la_norm_e, enca);

  // ---- block 1 ----
  gemm2_bf16_kernel<<<dim3(96,10), b256, 0, stream>>>(enca, 256,
      wij1, preE, 640, 128, 5, wik1, preK, 640, 256);
  angle11_kernel<true><<<1536, b512, 0, stream>>>(hat, preE, preK, wang1, wo1T,
      angle_in, nullptr, nullptr, nullptr, nullptr, nullptr, out_edge, nullptr);

  // ---- block 2 (edge rmsnorm fused; writes blk3 enca e-half; node add fused with npr) ----
  scores3_kernel<<<128, b256, 0, stream>>>(out_edge, aa_norm_e, gateT, scores2);
  edge_fused01_kernel<<<512, b256, 0, stream>>>(out_edge, aa_norm_e, npa, npe, next2e,
      aaWT, aeWT, woaaT, woaeT, scores2, out_edge, partial, lr_norm_e, enca);
  node_add_gemm2_kernel<<<dim3(128,8), b128, 0, stream>>>(node_in, partial,
      out_node, ar_norm_n, ar_win, npr, enca);

  // ---- block 3 (enca fully built by blk2 kernels) ----
  gemm2_bf16_kernel<<<dim3(96,8), b256, 0, stream>>>(enca, 256,
      wij3, preE, 512, 128, 4, wik3, preK, 512, 256);
  angle11_kernel<false><<<1536, b512, 0, stream>>>(hat, preE, preK, wang3, wo3T,
      angle_in, rbf, lr_env, a_sw, aprjT, lr_eproj, out_edge, out_angle);

  // ---- block 4 (npr precomputed at blk2; node projection fused via atomics) ----
  edge_fused2m2_kernel<<<512, b256, 0, stream>>>(out_edge, ar_norm_e, npr, next2e,
      arWT, woarT, rbf, ar_env, sw, eprjT, ar_nproj, out_edge, out_node);

  (void)in_sizes; (void)n_in; (void)out_size; (void)ws_size;
}